// Round 5
// baseline (686.860 us; speedup 1.0000x reference)
//
#include <hip/hip_runtime.h>
#include <math.h>

// Problem dims
#define NB   64      // batch B
#define NN   256     // tokens N
#define HSS  768     // H_S
#define HTT  1024    // H_T
#define ROWS (NB*NN) // 16384
#define C2LOG 14.426950408889634f  // 10 * log2(e)

typedef unsigned short u16;
typedef __attribute__((ext_vector_type(8))) short bf16x8;
typedef __attribute__((ext_vector_type(4))) float f32x4;

// swizzled LDS index for K[r][c] (256 cols): chunk rotation, 8-u16 granularity
#define LIDX(r,c) (((r)<<8) + (((((c)>>3) + (r)) & 31)<<3) + ((c)&7))
// swizzled LDS index for E[r][c] (128 cols, 16 chunks of 8)
#define EIDX(r,c) (((r)<<7) + (((((c)>>3) + (r)) & 15)<<3) + ((c)&7))

// async global->LDS, 16B per lane (gfx950)
__device__ __forceinline__ void gl16(const u16* g, u16* l){
  __builtin_amdgcn_global_load_lds(
      (const __attribute__((address_space(1))) unsigned int*)g,
      (__attribute__((address_space(3))) unsigned int*)l,
      16, 0, 0);
}

// ---------------- workspace layout (float offsets) ----------------
static const size_t OFF_ACC   = 0;                          // 16 floats
static const size_t OFF_SQ128 = 16;
static const size_t OFF_SP128 = OFF_SQ128 + 64*128;
static const size_t OFF_TQ128 = OFF_SP128 + 64*128;
static const size_t OFF_TP128 = OFF_TQ128 + 64*128;
static const size_t OFF_SQ768 = OFF_TP128 + 64*128;
static const size_t OFF_SP768 = OFF_SQ768 + 64*768;
static const size_t OFF_DS    = OFF_SP768 + 64*768;         // 128*128
static const size_t OFF_DT    = OFF_DS + 128*128;
static const size_t OFF_CS    = OFF_DT + 128*128;           // 2*B*N*N f32
static const size_t OFF_MBF   = OFF_CS  + (size_t)2*NB*NN*NN;     // 2*B*N*N bf16
static const size_t OFF_ZS_BF = OFF_MBF + (size_t)NB*NN*NN;       // 16384x768 bf16
static const size_t OFF_ZT_BF = OFF_ZS_BF + (size_t)ROWS*HSS/2;   // 16384x1024 bf16
static const size_t OFF_WT_BF = OFF_ZT_BF + (size_t)ROWS*HTT/2;   // 1024x768 bf16
static const size_t OFF_ZSP_BF= OFF_WT_BF + (size_t)HTT*HSS/2;    // 16384x1024 bf16
static const size_t OFF_GN_BF = OFF_ZSP_BF+ (size_t)ROWS*HTT/2;   // 2*B*N*N bf16
static const size_t OFF_CT_BF = OFF_GN_BF + (size_t)NB*NN*NN;     // 2*B*N*N bf16
static const size_t OFF_T_BF  = OFF_ZS_BF;                  // ALIAS: ZS dead after cost GEMMs
static const size_t OFF_NS    = OFF_CT_BF + (size_t)NB*NN*NN;
static const size_t OFF_NT    = OFF_NS + ROWS;
static const size_t OFF_NSP   = OFF_NT + ROWS;
static const size_t OFF_MU    = OFF_NSP + ROWS;             // 2*ROWS (linear)
static const size_t OFF_NU    = OFF_MU + 2*ROWS;            // 2*ROWS (linear)

// acc: 0=contrastive 1=ds_sum 2=dt_sum 3=dist_huber 4=angle_huber 5=feat 6=struct

// ---------------- helpers ----------------
__device__ __forceinline__ float wred_sum(float v){
  #pragma unroll
  for(int o=32;o>0;o>>=1) v += __shfl_xor(v,o,64);
  return v;
}
__device__ __forceinline__ float wred_max(float v){
  #pragma unroll
  for(int o=32;o>0;o>>=1) v = fmaxf(v, __shfl_xor(v,o,64));
  return v;
}
__device__ __forceinline__ u16 f2bf(float f){
  unsigned u = __float_as_uint(f);
  unsigned r = (u + 0x7fffu + ((u>>16)&1u)) >> 16;
  return (u16)r;
}
__device__ __forceinline__ float bf2f(u16 h){
  return __uint_as_float(((unsigned)h)<<16);
}

// ---------------- Part A kernels ----------------
// fused 6-way l2norm: blocks 0..255 -> 128-dim slices of {sq,sp,tq,tp};
// blocks 256..383 -> 768-dim of {sq,sp}
__global__ __launch_bounds__(256) void k_l2norm_all(
    const float* __restrict__ sq, const float* __restrict__ sp,
    const float* __restrict__ tq, const float* __restrict__ tp,
    float* __restrict__ ws){
  int bid = blockIdx.x;
  int r = bid & 63;
  const float* in; float* out; int kuse;
  if(bid < 64)       { in = sq; out = ws + OFF_SQ128; kuse = 128; }
  else if(bid < 128) { in = sp; out = ws + OFF_SP128; kuse = 128; }
  else if(bid < 192) { in = tq; out = ws + OFF_TQ128; kuse = 128; }
  else if(bid < 256) { in = tp; out = ws + OFF_TP128; kuse = 128; }
  else if(bid < 320) { in = sq; out = ws + OFF_SQ768; kuse = 768; }
  else               { in = sp; out = ws + OFF_SP768; kuse = 768; }
  const float* row = in + (size_t)r*768;
  float ss = 0.f;
  for(int d=threadIdx.x; d<kuse; d+=256){ float x=row[d]; ss += x*x; }
  ss = wred_sum(ss);
  __shared__ float sm[4];
  if((threadIdx.x&63)==0) sm[threadIdx.x>>6]=ss;
  __syncthreads();
  float tot = sm[0]+sm[1]+sm[2]+sm[3];
  float inv = 1.f / fmaxf(sqrtf(tot), 1e-12f);
  for(int d=threadIdx.x; d<kuse; d+=256) out[(size_t)r*kuse + d] = row[d]*inv;
}

// fused contrastive (both matryoshka dims): blocks 0..63 dim=128 w=1, 64..127 dim=768 w=2
__global__ __launch_bounds__(512) void k_contrastive2(const float* __restrict__ ws,
    float* __restrict__ acc){
  int bid = blockIdx.x;
  int i = bid & 63;
  int big = bid >> 6;
  const float* q = ws + (big ? OFF_SQ768 : OFF_SQ128);
  const float* p = ws + (big ? OFF_SP768 : OFF_SP128);
  int dim = big ? 768 : 128;
  float weight = big ? 2.f : 1.f;
  int j = threadIdx.x & 63;
  int part = threadIdx.x >> 6;           // 0..7
  const float* qi = q + (size_t)i*dim;
  const float* pj = p + (size_t)j*dim;
  int seg = dim >> 3;
  int d0 = part*seg;
  float dot = 0.f;
  for(int d=d0; d<d0+seg; d+=4){
    float4 a = *(const float4*)(qi+d);
    float4 b = *(const float4*)(pj+d);
    dot = fmaf(a.x,b.x,dot);
    dot = fmaf(a.y,b.y,dot);
    dot = fmaf(a.z,b.z,dot);
    dot = fmaf(a.w,b.w,dot);
  }
  __shared__ float sm[8][64];
  sm[part][j] = dot;
  __syncthreads();
  if(part==0){
    float s = 0.f;
    #pragma unroll
    for(int k=0;k<8;k++) s += sm[k][j];
    s = s / 0.07f;
    float mx = wred_max(s);
    float e = expf(s - mx);
    float Z = wred_sum(e);
    float logZ = mx + logf(Z);
    float diag = __shfl(s, i, 64);
    if(j==0) atomicAdd(acc+0, weight*(logZ - diag)*(1.f/64.f));
  }
}

__global__ __launch_bounds__(128) void k_gram_ds(const float* __restrict__ sb,
    const float* __restrict__ tb, float* __restrict__ ds, float* __restrict__ dt,
    float* __restrict__ acc){
  int r = blockIdx.x, c = threadIdx.x;
  const float* sr = sb + r*128; const float* sc = sb + c*128;
  const float* tr = tb + r*128; const float* tc = tb + c*128;
  float dot_s=0,ssr=0,ssc=0,dot_t=0,tsr=0,tsc=0;
  for(int d=0; d<128; d++){
    float a=sr[d], b=sc[d]; dot_s += a*b; ssr += a*a; ssc += b*b;
    float at=tr[d], bt=tc[d]; dot_t += at*bt; tsr += at*at; tsc += bt*bt;
  }
  float dv = ssr + ssc - 2.f*dot_s;
  float tv = tsr + tsc - 2.f*dot_t;
  ds[r*128+c] = dv; dt[r*128+c] = tv;
  float ms = (c>r)? dv : 0.f;
  float mt = (c>r)? tv : 0.f;
  ms = wred_sum(ms); mt = wred_sum(mt);
  __shared__ float sm[2][2];
  if((threadIdx.x&63)==0){ sm[0][threadIdx.x>>6]=ms; sm[1][threadIdx.x>>6]=mt; }
  __syncthreads();
  if(threadIdx.x==0){ atomicAdd(acc+1, sm[0][0]+sm[0][1]); atomicAdd(acc+2, sm[1][0]+sm[1][1]); }
}

__global__ __launch_bounds__(128) void k_rkd_dist(const float* __restrict__ ds,
    const float* __restrict__ dt, float* __restrict__ acc){
  int r=blockIdx.x, c=threadIdx.x;
  float mean_s = acc[1]*(1.f/8128.f) + 1e-8f;
  float mean_t = acc[2]*(1.f/8128.f) + 1e-8f;
  float h=0.f;
  if(c>r){
    float diff = ds[r*128+c]/mean_s - dt[r*128+c]/mean_t;
    float a = fabsf(diff);
    h = (a<1.f)? 0.5f*a*a : a-0.5f;
  }
  h = wred_sum(h);
  __shared__ float sm[2];
  if((threadIdx.x&63)==0) sm[threadIdx.x>>6]=h;
  __syncthreads();
  if(threadIdx.x==0) atomicAdd(acc+3, sm[0]+sm[1]);
}

// ---- RKD angle via MFMA: psi = E E^T, E in bf16 LDS, huber fused ----
#define RKD_LDS 65536
__global__ __launch_bounds__(256, 1) void k_rkd_angle_mfma(
    const float* __restrict__ sb, const float* __restrict__ tb,
    float* __restrict__ accp)
{
  extern __shared__ u16 eSh[];
  u16* Es = eSh;
  u16* Et = eSh + 128*128;
  const int j    = blockIdx.x >> 1;
  const int half = blockIdx.x & 1;
  const int tid = threadIdx.x;
  {
    const int i = tid >> 1, h = tid & 1;
    #pragma unroll
    for(int which=0; which<2; which++){
      const float* xb = which ? tb : sb;
      u16* E = which ? Et : Es;
      const float* xj = xb + j*128 + h*64;
      const float* xi = xb + i*128 + h*64;
      float ss = 0.f;
      #pragma unroll
      for(int d4=0; d4<16; d4++){
        float4 a = *(const float4*)(xj + d4*4);
        float4 b = *(const float4*)(xi + d4*4);
        float d0=a.x-b.x, d1=a.y-b.y, d2=a.z-b.z, d3=a.w-b.w;
        ss += d0*d0+d1*d1+d2*d2+d3*d3;
      }
      ss += __shfl_xor(ss, 1, 64);
      float inv = (i==j) ? 0.f : 1.f/(sqrtf(ss)+1e-8f);
      #pragma unroll
      for(int d4=0; d4<16; d4++){
        float4 a = *(const float4*)(xj + d4*4);
        float4 b = *(const float4*)(xi + d4*4);
        int c = h*64 + d4*4;
        E[EIDX(i,c+0)] = f2bf((a.x-b.x)*inv);
        E[EIDX(i,c+1)] = f2bf((a.y-b.y)*inv);
        E[EIDX(i,c+2)] = f2bf((a.z-b.z)*inv);
        E[EIDX(i,c+3)] = f2bf((a.w-b.w)*inv);
      }
    }
  }
  __syncthreads();
  const int w = tid >> 6, lane = tid & 63;
  const int q = lane >> 4, loc = lane & 15;
  float hsum = 0.f;
  #pragma unroll
  for(int ni=0; ni<4; ni++){
    const int cb = half*64 + ni*16;
    #pragma unroll
    for(int mi=0; mi<2; mi++){
      const int rb = w*32 + mi*16;
      f32x4 as_ = {0.f,0.f,0.f,0.f}, at_ = {0.f,0.f,0.f,0.f};
      #pragma unroll
      for(int k0=0; k0<128; k0+=32){
        int ra = rb + loc, rbn = cb + loc;
        int ca = k0 + q*8;
        bf16x8 aS = *(const bf16x8*)(Es + EIDX(ra, ca));
        bf16x8 bS = *(const bf16x8*)(Es + EIDX(rbn, ca));
        bf16x8 aT = *(const bf16x8*)(Et + EIDX(ra, ca));
        bf16x8 bT = *(const bf16x8*)(Et + EIDX(rbn, ca));
        as_ = __builtin_amdgcn_mfma_f32_16x16x32_bf16(aS, bS, as_, 0,0,0);
        at_ = __builtin_amdgcn_mfma_f32_16x16x32_bf16(aT, bT, at_, 0,0,0);
      }
      #pragma unroll
      for(int jj=0; jj<4; jj++){
        int row = rb + q*4 + jj, col = cb + loc;
        if(row != col){
          float d = as_[jj] - at_[jj];
          float a = fabsf(d);
          hsum += (a < 1.f) ? 0.5f*a*a : a - 0.5f;
        }
      }
    }
  }
  hsum = wred_sum(hsum);
  __syncthreads();
  float* red = (float*)eSh;
  if(lane==0) red[w] = hsum;
  __syncthreads();
  if(tid==0) atomicAdd(accp+4, red[0]+red[1]+red[2]+red[3]);
}

// ---------------- Part B: convert+norm / saliency ----------------
// wave-per-row: grid ROWS/4 x 256 thr. float4 loads, no LDS, no block sync.
__global__ __launch_bounds__(256) void k_cvt_norm(const float* __restrict__ in,
    u16* __restrict__ out, float* __restrict__ nrm, int K){
  int w = threadIdx.x >> 6, l = threadIdx.x & 63;
  int r = blockIdx.x*4 + w;
  const float* row = in + (size_t)r*K;
  u16* orow = out + (size_t)r*K;
  float ss = 0.f;
  int nv = K >> 8;                      // float4 per lane: 3 (K=768) or 4 (K=1024)
  for(int i=0;i<nv;i++){
    int d = l*4 + i*256;
    float4 x = *(const float4*)(row + d);
    ushort4 o; o.x=f2bf(x.x); o.y=f2bf(x.y); o.z=f2bf(x.z); o.w=f2bf(x.w);
    *(ushort4*)(orow + d) = o;
    ss += x.x*x.x + x.y*x.y + x.z*x.z + x.w*x.w;
  }
  ss = wred_sum(ss);
  if(l==0) nrm[r] = sqrtf(ss);
}

// wave-per-row bf16 row norms (K multiple of 512): uint4 = 8 bf16 per load
__global__ __launch_bounds__(256) void k_row_norm_bf16(const u16* __restrict__ z,
    float* __restrict__ nrm, int K){
  int w = threadIdx.x >> 6, l = threadIdx.x & 63;
  int r = blockIdx.x*4 + w;
  const u16* row = z + (size_t)r*K;
  float ss = 0.f;
  int nv = K >> 9;                      // uint4 per lane: 2 (K=1024)
  for(int i=0;i<nv;i++){
    int d = l*8 + i*512;
    uint4 v = *(const uint4*)(row + d);
    float a0=__uint_as_float(v.x<<16), a1=__uint_as_float(v.x&0xffff0000u);
    float a2=__uint_as_float(v.y<<16), a3=__uint_as_float(v.y&0xffff0000u);
    float a4=__uint_as_float(v.z<<16), a5=__uint_as_float(v.z&0xffff0000u);
    float a6=__uint_as_float(v.w<<16), a7=__uint_as_float(v.w&0xffff0000u);
    ss += a0*a0+a1*a1+a2*a2+a3*a3+a4*a4+a5*a5+a6*a6+a7*a7;
  }
  ss = wred_sum(ss);
  if(l==0) nrm[r] = sqrtf(ss);
}

// W (HSS x HTT) f32 -> Wt (HTT x HSS) bf16
__global__ void k_wt(const float* __restrict__ W, u16* __restrict__ Wt){
  __shared__ float t[32][33];
  int k0 = blockIdx.y*32, n0 = blockIdx.x*32;
  int tx = threadIdx.x, ty = threadIdx.y;
  for(int r=0;r<32;r+=8) t[ty+r][tx] = W[(size_t)(k0+ty+r)*HTT + n0+tx];
  __syncthreads();
  for(int r=0;r<32;r+=8) Wt[(size_t)(n0+ty+r)*HSS + k0+tx] = f2bf(t[tx][ty+r]);
}

// fused saliency: blocks 0..63 -> (ns -> mu), 64..127 -> (nt -> nu)
__global__ __launch_bounds__(256) void k_saliency2(const float* __restrict__ ns,
    const float* __restrict__ nt, float* __restrict__ omu, float* __restrict__ onu){
  int b0 = blockIdx.x, n = threadIdx.x;
  const float* nrm = (b0 < NB) ? ns : nt;
  float* out = (b0 < NB) ? omu : onu;
  int b = b0 & 63;
  float x = nrm[b*NN+n];
  float mx = wred_max(x);
  __shared__ float sm[4], sm2[4];
  if((n&63)==0) sm[n>>6]=mx;
  __syncthreads();
  mx = fmaxf(fmaxf(sm[0],sm[1]),fmaxf(sm[2],sm[3]));
  float e = expf(x-mx);
  float s = wred_sum(e);
  if((n&63)==0) sm2[n>>6]=s;
  __syncthreads();
  s = sm2[0]+sm2[1]+sm2[2]+sm2[3];
  out[b*NN+n] = e/s;
}

// ---------------- MFMA GEMM (NT form) ----------------
enum { MODE_PROJ=0, MODE_COST=1, MODE_PLAIN=2, MODE_STRUCT=3 };

template<int MODE>
__global__ __launch_bounds__(256) void k_mfma(
    const u16* __restrict__ A, int lda, long bA,
    const u16* __restrict__ B, int ldb, long bB,
    int K,
    float* __restrict__ outF, u16* __restrict__ outB, int ldo, long bO,
    const float* __restrict__ nx, const float* __restrict__ ny,
    const float* __restrict__ bias,
    const float* __restrict__ Cs, const float* __restrict__ mu,
    float* __restrict__ accp)
{
  __shared__ u16 As[128*32];
  __shared__ u16 Bs[128*32];
  __shared__ float red[4];

  // XCD-aware bijective block swizzle (all grids have nwg % 8 == 0)
  int gx = gridDim.x, gy = gridDim.y;
  int flat = blockIdx.x + gx*(blockIdx.y + gy*blockIdx.z);
  int nwg  = gx*gy*gridDim.z;
  int cpx  = nwg >> 3;
  int lg   = (flat & 7)*cpx + (flat >> 3);
  int bx   = lg % gx;
  int rest = lg / gx;
  int by   = rest % gy;
  int b    = rest / gy;

  const u16* Ab = A + (size_t)b*bA;
  const u16* Bb = B + (size_t)b*bB;
  int tid = threadIdx.x;
  int lane = tid & 63, w = tid >> 6;
  int m0 = by*128, n0 = bx*128;
  int row_off = (w>>1)*64, col_off = (w&1)*64;
  int q = lane>>4, loc = lane&15;
  f32x4 acc[4][4] = {};

  const int srow = (lane >> 2);
  const int sslot = lane & 3;

  for(int k0=0;k0<K;k0+=32){
    #pragma unroll
    for(int h=0;h<2;h++){
      int row = h*64 + w*16 + srow;
      int ca  = (sslot ^ ((row>>1)&3))*8;            // inverse of read-side XOR
      u16* ldst = As + h*2048 + w*512 + lane*8;      // linear: row*32 + slot*8
      u16* ldstB= Bs + h*2048 + w*512 + lane*8;
      gl16(Ab + (size_t)(m0+row)*lda + k0 + ca, ldst);
      gl16(Bb + (size_t)(n0+row)*ldb + k0 + ca, ldstB);
    }
    __syncthreads();
    bf16x8 af[4], bfr[4];
    #pragma unroll
    for(int mi=0;mi<4;mi++){
      int r = row_off + mi*16 + loc;
      int slot = q ^ ((r>>1)&3);
      af[mi] = *(const bf16x8*)(As + r*32 + slot*8);
    }
    #pragma unroll
    for(int ni=0;ni<4;ni++){
      int r = col_off + ni*16 + loc;
      int slot = q ^ ((r>>1)&3);
      bfr[ni] = *(const bf16x8*)(Bs + r*32 + slot*8);
    }
    #pragma unroll
    for(int mi=0;mi<4;mi++)
      #pragma unroll
      for(int ni=0;ni<4;ni++)
        acc[mi][ni] = __builtin_amdgcn_mfma_f32_16x16x32_bf16(af[mi], bfr[ni], acc[mi][ni], 0,0,0);
    __syncthreads();
  }

  float* outFb = outF ? outF + (size_t)b*bO : nullptr;
  u16*   outBb = outB ? outB + (size_t)b*bO : nullptr;
  const float* nxb = nx ? nx + (size_t)b*NN : nullptr;
  const float* nyb = ny ? ny + (size_t)b*NN : nullptr;
  const float* Cb  = (MODE==MODE_STRUCT) ? Cs + (size_t)b*bO : nullptr;
  const float* mb  = (MODE==MODE_STRUCT) ? mu + (size_t)b*NN : nullptr;
  float lsum = 0.f;
  #pragma unroll
  for(int mi=0;mi<4;mi++){
    #pragma unroll
    for(int j=0;j<4;j++){
      int row = m0 + row_off + mi*16 + q*4 + j;
      float ir = 0.f, mr = 0.f;
      if(MODE==MODE_COST)   ir = 1.f/fmaxf(nxb[row],1e-12f);
      if(MODE==MODE_STRUCT) mr = mb[row];
      #pragma unroll
      for(int ni=0;ni<4;ni++){
        int col = n0 + col_off + ni*16 + loc;
        float v = acc[mi][ni][j];
        if(MODE==MODE_PROJ){
          v += bias[col];
          outBb[(size_t)row*ldo + col] = f2bf(v);
        } else if(MODE==MODE_COST){
          float ic = 1.f/fmaxf(nyb[col],1e-12f);
          v = 1.f - v*ir*ic;
          if(outFb) outFb[(size_t)row*ldo + col] = v;
          if(outBb) outBb[(size_t)row*ldo + col] = f2bf(v);
        } else if(MODE==MODE_PLAIN){
          outBb[(size_t)row*ldo + col] = f2bf(v);
        } else {
          float d = Cb[(size_t)row*ldo + col] - v;
          lsum += d*d*mr*mb[col];
        }
      }
    }
  }
  if(MODE==MODE_STRUCT){
    lsum = wred_sum(lsum);
    if(lane==0) red[w] = lsum;
    __syncthreads();
    if(tid==0) atomicAdd(accp+6, red[0]+red[1]+red[2]+red[3]);
  }
}

// ---------------- fused Sinkhorn: 3 phases/iter, in-wave u, no register K ----------------
// Phase A: wave w owns rows w*16..+16. Lane l: row w*16+(l&15), col quarter l>>4.
//   Quarter-dot (4 indep accumulators) -> shfl_xor(16,32) completes S_r in-wave ->
//   u_r = mu_r/S_r written by 16 lanes. (eliminates the separate u-phase+barrier)
// Phase B: strip col matvec (wave w rows w*16..+16, lane l cols l*4..+4) -> partB.
// Phase C: all 1024 threads: col t>>2, group t&3 reduces 4 partials + shfl_xor(1,2) -> v.
// Epilogue: 21st phase A stores sinv = 1/(u*S_new+eps); output phase reads su/sinv/sv from LDS.
#define SINK_DYN_LDS 131072
__global__ __launch_bounds__(1024, 1) void k_sinkhorn_fused(
    const u16* __restrict__ Mbf, const float* __restrict__ muL,
    const float* __restrict__ nuL, u16* __restrict__ Gn, float* __restrict__ accp)
{
  extern __shared__ u16 Ks[];                        // 256x256 bf16, swizzled
  __shared__ __align__(16) float partB[4096];        // col strip partials (16 x 256)
  __shared__ __align__(16) float su[256], sv[256], smu_s[256], snu_s[256], sinv[256];
  __shared__ float red[16];

  const int b = blockIdx.x;
  const int t = threadIdx.x;
  const u16* Mb = Mbf + (size_t)b*NN*NN;

  #pragma unroll
  for(int i=0;i<16;i++){
    int e = (i*1024 + t)*4;
    int r = e>>8, c = e&255;
    ushort4 mv = *(const ushort4*)(Mb + e);
    ushort4 o;
    o.x = f2bf(exp2f(-C2LOG*bf2f(mv.x)));
    o.y = f2bf(exp2f(-C2LOG*bf2f(mv.y)));
    o.z = f2bf(exp2f(-C2LOG*bf2f(mv.z)));
    o.w = f2bf(exp2f(-C2LOG*bf2f(mv.w)));
    *(ushort4*)(Ks + LIDX(r,c)) = o;
  }
  if(t < NN){
    smu_s[t] = muL[(size_t)b*NN+t] + 1e-8f;
    snu_s[t] = nuL[(size_t)b*NN+t] + 1e-8f;
    sv[t] = 1.f;
  }
  __syncthreads();

  const int w = t>>6, l = t&63;
  const int ra = (w<<4) + (l&15);          // phase-A row
  const int qa = l>>4;                     // phase-A col quarter

  #pragma unroll 1
  for(int it=0; it<=20; ++it){
    // ---- phase A: S_r = sum_c K[r,c]*v[c]; u inline via in-wave reduce ----
    float s0=0.f, s1=0.f, s2=0.f, s3=0.f;
    #pragma unroll
    for(int jj=0;jj<8;jj++){
      int c0 = (qa<<6) + (jj<<3);
      uint4 kv = *(const uint4*)(Ks + LIDX(ra, c0));
      float4 va = *(const float4*)(sv + c0);
      float4 vb = *(const float4*)(sv + c0 + 4);
      s0 = fmaf(__uint_as_float(kv.x<<16),           va.x, s0);
      s1 = fmaf(__uint_as_float(kv.x & 0xffff0000u), va.y, s1);
      s2 = fmaf(__uint_as_float(kv.y<<16),           va.z, s2);
      s3 = fmaf(__uint_as_float(kv.y & 0xffff0000u), va.w, s3);
      s0 = fmaf(__uint_as_float(kv.z<<16),           vb.x, s0);
      s1 = fmaf(__uint_as_float(kv.z & 0xffff0000u), vb.y, s1);
      s2 = fmaf(__uint_as_float(kv.w<<16),           vb.z, s2);
      s3 = fmaf(__uint_as_float(kv.w & 0xffff0000u), vb.w, s3);
    }
    float S = (s0+s1)+(s2+s3);
    S += __shfl_xor(S, 16, 64);
    S += __shfl_xor(S, 32, 64);
    if(qa==0){
      if(it<20) su[ra]   = smu_s[ra] / S;
      else      sinv[ra] = 1.f / (su[ra]*S + 1e-8f);
    }
    __syncthreads();
    if(it==20) break;

    // ---- phase B: strip col matvec -> partB ----
    float cs0=0.f,cs1=0.f,cs2=0.f,cs3=0.f;
    #pragma unroll
    for(int rr=0; rr<16; rr++){
      int r = (w<<4) + rr;
      ushort4 kv = *(const ushort4*)(Ks + LIDX(r, l<<2));
      float ur = su[r];
      cs0 = fmaf(bf2f(kv.x), ur, cs0);
      cs1 = fmaf(bf2f(kv.y), ur, cs1);
      cs2 = fmaf(bf2f(kv.z), ur, cs2);
      cs3 = fmaf(bf2f(kv.w), ur, cs3);
    }
    float4 o; o.x=cs0; o.y=cs1; o.z=cs2; o.w=cs3;
    *(float4*)(partB + (w<<8) + (l<<2)) = o;
    __syncthreads();

    // ---- phase C: v update (all threads, 4 partials + in-wave 4-lane reduce) ----
    {
      int c = t>>2, g = t&3;
      float T = partB[((g*4+0)<<8)+c] + partB[((g*4+1)<<8)+c]
              + partB[((g*4+2)<<8)+c] + partB[((g*4+3)<<8)+c];
      T += __shfl_xor(T, 1, 64);
      T += __shfl_xor(T, 2, 64);
      if(g==0) sv[c] = snu_s[c] / T;
    }
    __syncthreads();
  }

  // ---- output phase (strip-shaped): Gamma, Gn, feat loss ----
  u16* Gb = Gn + (size_t)b*NN*NN;
  const float IC = -1.f/C2LOG;
  float4 v4 = *(const float4*)(sv + (l<<2));
  float fl = 0.f;
  #pragma unroll
  for(int rr=0; rr<16; rr++){
    int r = (w<<4) + rr;
    float ur  = su[r];
    float inv = sinv[r];
    ushort4 kv = *(const ushort4*)(Ks + LIDX(r, l<<2));
    float k0=bf2f(kv.x), k1=bf2f(kv.y), k2=bf2f(kv.z), k3=bf2f(kv.w);
    float g0=ur*k0*v4.x, g1=ur*k1*v4.y, g2=ur*k2*v4.z, g3=ur*k3*v4.w;
    fl += g0*(__log2f(k0)*IC) + g1*(__log2f(k1)*IC)
        + g2*(__log2f(k2)*IC) + g3*(__log2f(k3)*IC);
    ushort4 o;
    o.x=f2bf(g0*inv); o.y=f2bf(g1*inv); o.z=f2bf(g2*inv); o.w=f2bf(g3*inv);
    *(ushort4*)(Gb + (size_t)r*NN + (l<<2)) = o;
  }
  fl = wred_sum(fl);
  if(l==0) red[w] = fl;
  __syncthreads();
  if(t==0){
    float s=0.f;
    #pragma unroll
    for(int i=0;i<16;i++) s+=red[i];
    atomicAdd(accp+5, s);
  }
}

__global__ void k_final(const float* __restrict__ acc, float* __restrict__ out){
  out[0] = acc[0]
         + 20.f*acc[3]*(1.f/8128.f)
         + 40.f*acc[4]*(1.f/2048256.f)
         + 0.25f*(acc[5]+acc[6])*(1.f/64.f);
}

// ---------------- host ----------------
extern "C" void kernel_launch(void* const* d_in, const int* in_sizes, int n_in,
                              void* d_out, int out_size, void* d_ws, size_t ws_size,
                              hipStream_t stream) {
  const float* s_q_reps   = (const float*)d_in[0];
  const float* s_p_reps   = (const float*)d_in[1];
  const float* t_q_reps   = (const float*)d_in[2];
  const float* t_p_reps   = (const float*)d_in[3];
  const float* s_q_states = (const float*)d_in[4];
  const float* s_p_states = (const float*)d_in[5];
  const float* t_q_states = (const float*)d_in[6];
  const float* t_p_states = (const float*)d_in[7];
  const float* proj_w     = (const float*)d_in[8];
  const float* proj_b     = (const float*)d_in[9];
  float* ws = (float*)d_ws;
  float* acc = ws + OFF_ACC;
  u16* M_BF   = (u16*)(ws + OFF_MBF);
  u16* ZS_BF  = (u16*)(ws + OFF_ZS_BF);
  u16* ZT_BF  = (u16*)(ws + OFF_ZT_BF);
  u16* WT_BF  = (u16*)(ws + OFF_WT_BF);
  u16* ZSP_BF = (u16*)(ws + OFF_ZSP_BF);
  u16* GN_BF  = (u16*)(ws + OFF_GN_BF);
  u16* CT_BF  = (u16*)(ws + OFF_CT_BF);
  u16* T_BF   = (u16*)(ws + OFF_T_BF);

  hipFuncSetAttribute(reinterpret_cast<const void*>(k_sinkhorn_fused),
                      hipFuncAttributeMaxDynamicSharedMemorySize, SINK_DYN_LDS);
  hipFuncSetAttribute(reinterpret_cast<const void*>(k_rkd_angle_mfma),
                      hipFuncAttributeMaxDynamicSharedMemorySize, RKD_LDS);

  hipMemsetAsync(acc, 0, 16*sizeof(float), stream);

  // ---- Part A ----
  k_l2norm_all<<<384,256,0,stream>>>(s_q_reps, s_p_reps, t_q_reps, t_p_reps, ws);
  k_contrastive2<<<128,512,0,stream>>>(ws, acc);
  k_gram_ds<<<128,128,0,stream>>>(ws+OFF_SQ128, ws+OFF_TQ128, ws+OFF_DS, ws+OFF_DT, acc);
  k_rkd_dist<<<128,128,0,stream>>>(ws+OFF_DS, ws+OFF_DT, acc);
  k_rkd_angle_mfma<<<256,256,RKD_LDS,stream>>>(ws+OFF_SQ128, ws+OFF_TQ128, acc);

  k_wt<<<dim3(HTT/32, HSS/32),dim3(32,8),0,stream>>>(proj_w, WT_BF);

  // ---- Part B phase 1: per-pass GEMMs into doubled buffers ----
  for(int pass=0; pass<2; pass++){
    const float* zs = pass ? s_p_states : s_q_states;
    const float* zt = pass ? t_p_states : t_q_states;
    size_t po  = (size_t)pass*NB*NN*NN;
    size_t pr  = (size_t)pass*ROWS;
    k_cvt_norm<<<ROWS/4,256,0,stream>>>(zs, ZS_BF, ws+OFF_NS, HSS);
    k_cvt_norm<<<ROWS/4,256,0,stream>>>(zt, ZT_BF, ws+OFF_NT, HTT);
    k_saliency2<<<128,256,0,stream>>>(ws+OFF_NS, ws+OFF_NT, ws+OFF_MU+pr, ws+OFF_NU+pr);
    k_mfma<MODE_PROJ><<<dim3(HTT/128, ROWS/128, 1),256,0,stream>>>(
        ZS_BF, HSS, 0, WT_BF, HSS, 0, HSS,
        nullptr, ZSP_BF, HTT, 0,
        nullptr, nullptr, proj_b, nullptr, nullptr, nullptr);
    k_row_norm_bf16<<<ROWS/4,256,0,stream>>>(ZSP_BF, ws+OFF_NSP, HTT);
    // C_s (f32)
    k_mfma<MODE_COST><<<dim3(2,2,NB),256,0,stream>>>(
        ZS_BF, HSS, (long)NN*HSS, ZS_BF, HSS, (long)NN*HSS, HSS,
        ws+OFF_CS+po, nullptr, NN, (long)NN*NN,
        ws+OFF_NS, ws+OFF_NS, nullptr, nullptr, nullptr, nullptr);
    // C_t (bf16)
    k_mfma<MODE_COST><<<dim3(2,2,NB),256,0,stream>>>(
        ZT_BF, HTT, (long)NN*HTT, ZT_BF, HTT, (long)NN*HTT, HTT,
        nullptr, CT_BF+po, NN, (long)NN*NN,
        ws+OFF_NT, ws+OFF_NT, nullptr, nullptr, nullptr, nullptr);
    // M (bf16)
    k_mfma<MODE_COST><<<dim3(2,2,NB),256,0,stream>>>(
        ZSP_BF, HTT, (long)NN*HTT, ZT_BF, HTT, (long)NN*HTT, HTT,
        nullptr, M_BF+po, NN, (long)NN*NN,
        ws+OFF_NSP, ws+OFF_NT, nullptr, nullptr, nullptr, nullptr);
  }

  // ---- Part B phase 2: Sinkhorn (both passes, multiplicative, K in LDS) ----
  k_sinkhorn_fused<<<2*NB,1024,SINK_DYN_LDS,stream>>>(
      M_BF, ws+OFF_MU, ws+OFF_NU, GN_BF, acc);

  // ---- Part B phase 3: T = Gn@Ct, struct loss (batched over both passes) ----
  k_mfma<MODE_PLAIN><<<dim3(2,2,2*NB),256,0,stream>>>(
      GN_BF, NN, (long)NN*NN, CT_BF, NN, (long)NN*NN, NN,
      nullptr, T_BF, NN, (long)NN*NN,
      nullptr, nullptr, nullptr, nullptr, nullptr, nullptr);
  k_mfma<MODE_STRUCT><<<dim3(2,2,2*NB),256,0,stream>>>(
      T_BF, NN, (long)NN*NN, GN_BF, NN, (long)NN*NN, NN,
      nullptr, nullptr, NN, (long)NN*NN,
      nullptr, nullptr, nullptr, ws+OFF_CS, ws+OFF_MU, acc);

  k_final<<<1,1,0,stream>>>(acc, (float*)d_out);
}

// Round 6
// 671.509 us; speedup vs baseline: 1.0229x; 1.0229x over previous
//
#include <hip/hip_runtime.h>
#include <math.h>

// Problem dims
#define NB   64      // batch B
#define NN   256     // tokens N
#define HSS  768     // H_S
#define HTT  1024    // H_T
#define ROWS (NB*NN) // 16384
#define C2LOG 14.426950408889634f  // 10 * log2(e)

typedef unsigned short u16;
typedef __attribute__((ext_vector_type(8))) short bf16x8;
typedef __attribute__((ext_vector_type(4))) float f32x4;

// swizzled LDS index for K[r][c] (256 cols): chunk rotation, 8-u16 granularity
#define LIDX(r,c) (((r)<<8) + (((((c)>>3) + (r)) & 31)<<3) + ((c)&7))
// swizzled LDS index for E[r][c] (128 cols, 16 chunks of 8)
#define EIDX(r,c) (((r)<<7) + (((((c)>>3) + (r)) & 15)<<3) + ((c)&7))

// async global->LDS, 16B per lane (gfx950)
__device__ __forceinline__ void gl16(const u16* g, u16* l){
  __builtin_amdgcn_global_load_lds(
      (const __attribute__((address_space(1))) unsigned int*)g,
      (__attribute__((address_space(3))) unsigned int*)l,
      16, 0, 0);
}

// ---------------- workspace layout (float offsets) ----------------
static const size_t OFF_ACC   = 0;                          // 16 floats
static const size_t OFF_SQ128 = 16;
static const size_t OFF_SP128 = OFF_SQ128 + 64*128;
static const size_t OFF_TQ128 = OFF_SP128 + 64*128;
static const size_t OFF_TP128 = OFF_TQ128 + 64*128;
static const size_t OFF_SQ768 = OFF_TP128 + 64*128;
static const size_t OFF_SP768 = OFF_SQ768 + 64*768;
static const size_t OFF_DS    = OFF_SP768 + 64*768;         // 128*128
static const size_t OFF_DT    = OFF_DS + 128*128;
static const size_t OFF_CS    = OFF_DT + 128*128;           // 2*B*N*N f32
static const size_t OFF_MBF   = OFF_CS  + (size_t)2*NB*NN*NN;     // 2*B*N*N bf16
static const size_t OFF_ZS_BF = OFF_MBF + (size_t)NB*NN*NN;       // 16384x768 bf16
static const size_t OFF_ZT_BF = OFF_ZS_BF + (size_t)ROWS*HSS/2;   // 16384x1024 bf16
static const size_t OFF_WT_BF = OFF_ZT_BF + (size_t)ROWS*HTT/2;   // 1024x768 bf16
static const size_t OFF_ZSP_BF= OFF_WT_BF + (size_t)HTT*HSS/2;    // 16384x1024 bf16
static const size_t OFF_GN_BF = OFF_ZSP_BF+ (size_t)ROWS*HTT/2;   // 2*B*N*N bf16
static const size_t OFF_CT_BF = OFF_GN_BF + (size_t)NB*NN*NN;     // 2*B*N*N bf16
static const size_t OFF_T_BF  = OFF_ZS_BF;                  // ALIAS: ZS dead after cost GEMMs
static const size_t OFF_NS    = OFF_CT_BF + (size_t)NB*NN*NN;
static const size_t OFF_NT    = OFF_NS + ROWS;
static const size_t OFF_NSP   = OFF_NT + ROWS;
static const size_t OFF_MU    = OFF_NSP + ROWS;             // 2*ROWS (linear)
static const size_t OFF_NU    = OFF_MU + 2*ROWS;            // 2*ROWS (linear)

// acc: 0=contrastive 1=ds_sum 2=dt_sum 3=dist_huber 4=angle_huber 5=feat 6=struct

// ---------------- helpers ----------------
__device__ __forceinline__ float wred_sum(float v){
  #pragma unroll
  for(int o=32;o>0;o>>=1) v += __shfl_xor(v,o,64);
  return v;
}
__device__ __forceinline__ float wred_max(float v){
  #pragma unroll
  for(int o=32;o>0;o>>=1) v = fmaxf(v, __shfl_xor(v,o,64));
  return v;
}
__device__ __forceinline__ u16 f2bf(float f){
  unsigned u = __float_as_uint(f);
  unsigned r = (u + 0x7fffu + ((u>>16)&1u)) >> 16;
  return (u16)r;
}
__device__ __forceinline__ float bf2f(u16 h){
  return __uint_as_float(((unsigned)h)<<16);
}

// ---------------- Part A kernels ----------------
// fused 6-way l2norm: blocks 0..255 -> 128-dim slices of {sq,sp,tq,tp};
// blocks 256..383 -> 768-dim of {sq,sp}
__global__ __launch_bounds__(256) void k_l2norm_all(
    const float* __restrict__ sq, const float* __restrict__ sp,
    const float* __restrict__ tq, const float* __restrict__ tp,
    float* __restrict__ ws){
  int bid = blockIdx.x;
  int r = bid & 63;
  const float* in; float* out; int kuse;
  if(bid < 64)       { in = sq; out = ws + OFF_SQ128; kuse = 128; }
  else if(bid < 128) { in = sp; out = ws + OFF_SP128; kuse = 128; }
  else if(bid < 192) { in = tq; out = ws + OFF_TQ128; kuse = 128; }
  else if(bid < 256) { in = tp; out = ws + OFF_TP128; kuse = 128; }
  else if(bid < 320) { in = sq; out = ws + OFF_SQ768; kuse = 768; }
  else               { in = sp; out = ws + OFF_SP768; kuse = 768; }
  const float* row = in + (size_t)r*768;
  float ss = 0.f;
  for(int d=threadIdx.x; d<kuse; d+=256){ float x=row[d]; ss += x*x; }
  ss = wred_sum(ss);
  __shared__ float sm[4];
  if((threadIdx.x&63)==0) sm[threadIdx.x>>6]=ss;
  __syncthreads();
  float tot = sm[0]+sm[1]+sm[2]+sm[3];
  float inv = 1.f / fmaxf(sqrtf(tot), 1e-12f);
  for(int d=threadIdx.x; d<kuse; d+=256) out[(size_t)r*kuse + d] = row[d]*inv;
}

// fused contrastive (both matryoshka dims): blocks 0..63 dim=128 w=1, 64..127 dim=768 w=2
__global__ __launch_bounds__(512) void k_contrastive2(const float* __restrict__ ws,
    float* __restrict__ acc){
  int bid = blockIdx.x;
  int i = bid & 63;
  int big = bid >> 6;
  const float* q = ws + (big ? OFF_SQ768 : OFF_SQ128);
  const float* p = ws + (big ? OFF_SP768 : OFF_SP128);
  int dim = big ? 768 : 128;
  float weight = big ? 2.f : 1.f;
  int j = threadIdx.x & 63;
  int part = threadIdx.x >> 6;           // 0..7
  const float* qi = q + (size_t)i*dim;
  const float* pj = p + (size_t)j*dim;
  int seg = dim >> 3;
  int d0 = part*seg;
  float dot = 0.f;
  for(int d=d0; d<d0+seg; d+=4){
    float4 a = *(const float4*)(qi+d);
    float4 b = *(const float4*)(pj+d);
    dot = fmaf(a.x,b.x,dot);
    dot = fmaf(a.y,b.y,dot);
    dot = fmaf(a.z,b.z,dot);
    dot = fmaf(a.w,b.w,dot);
  }
  __shared__ float sm[8][64];
  sm[part][j] = dot;
  __syncthreads();
  if(part==0){
    float s = 0.f;
    #pragma unroll
    for(int k=0;k<8;k++) s += sm[k][j];
    s = s / 0.07f;
    float mx = wred_max(s);
    float e = expf(s - mx);
    float Z = wred_sum(e);
    float logZ = mx + logf(Z);
    float diag = __shfl(s, i, 64);
    if(j==0) atomicAdd(acc+0, weight*(logZ - diag)*(1.f/64.f));
  }
}

__global__ __launch_bounds__(128) void k_gram_ds(const float* __restrict__ sb,
    const float* __restrict__ tb, float* __restrict__ ds, float* __restrict__ dt,
    float* __restrict__ acc){
  int r = blockIdx.x, c = threadIdx.x;
  const float* sr = sb + r*128; const float* sc = sb + c*128;
  const float* tr = tb + r*128; const float* tc = tb + c*128;
  float dot_s=0,ssr=0,ssc=0,dot_t=0,tsr=0,tsc=0;
  for(int d=0; d<128; d++){
    float a=sr[d], b=sc[d]; dot_s += a*b; ssr += a*a; ssc += b*b;
    float at=tr[d], bt=tc[d]; dot_t += at*bt; tsr += at*at; tsc += bt*bt;
  }
  float dv = ssr + ssc - 2.f*dot_s;
  float tv = tsr + tsc - 2.f*dot_t;
  ds[r*128+c] = dv; dt[r*128+c] = tv;
  float ms = (c>r)? dv : 0.f;
  float mt = (c>r)? tv : 0.f;
  ms = wred_sum(ms); mt = wred_sum(mt);
  __shared__ float sm[2][2];
  if((threadIdx.x&63)==0){ sm[0][threadIdx.x>>6]=ms; sm[1][threadIdx.x>>6]=mt; }
  __syncthreads();
  if(threadIdx.x==0){ atomicAdd(acc+1, sm[0][0]+sm[0][1]); atomicAdd(acc+2, sm[1][0]+sm[1][1]); }
}

__global__ __launch_bounds__(128) void k_rkd_dist(const float* __restrict__ ds,
    const float* __restrict__ dt, float* __restrict__ acc){
  int r=blockIdx.x, c=threadIdx.x;
  float mean_s = acc[1]*(1.f/8128.f) + 1e-8f;
  float mean_t = acc[2]*(1.f/8128.f) + 1e-8f;
  float h=0.f;
  if(c>r){
    float diff = ds[r*128+c]/mean_s - dt[r*128+c]/mean_t;
    float a = fabsf(diff);
    h = (a<1.f)? 0.5f*a*a : a-0.5f;
  }
  h = wred_sum(h);
  __shared__ float sm[2];
  if((threadIdx.x&63)==0) sm[threadIdx.x>>6]=h;
  __syncthreads();
  if(threadIdx.x==0) atomicAdd(acc+3, sm[0]+sm[1]);
}

// ---- RKD angle via MFMA: psi = E E^T, E in bf16 LDS, huber fused ----
#define RKD_LDS 65536
__global__ __launch_bounds__(256, 1) void k_rkd_angle_mfma(
    const float* __restrict__ sb, const float* __restrict__ tb,
    float* __restrict__ accp)
{
  extern __shared__ u16 eSh[];
  u16* Es = eSh;
  u16* Et = eSh + 128*128;
  const int j    = blockIdx.x >> 1;
  const int half = blockIdx.x & 1;
  const int tid = threadIdx.x;
  {
    const int i = tid >> 1, h = tid & 1;
    #pragma unroll
    for(int which=0; which<2; which++){
      const float* xb = which ? tb : sb;
      u16* E = which ? Et : Es;
      const float* xj = xb + j*128 + h*64;
      const float* xi = xb + i*128 + h*64;
      float ss = 0.f;
      #pragma unroll
      for(int d4=0; d4<16; d4++){
        float4 a = *(const float4*)(xj + d4*4);
        float4 b = *(const float4*)(xi + d4*4);
        float d0=a.x-b.x, d1=a.y-b.y, d2=a.z-b.z, d3=a.w-b.w;
        ss += d0*d0+d1*d1+d2*d2+d3*d3;
      }
      ss += __shfl_xor(ss, 1, 64);
      float inv = (i==j) ? 0.f : 1.f/(sqrtf(ss)+1e-8f);
      #pragma unroll
      for(int d4=0; d4<16; d4++){
        float4 a = *(const float4*)(xj + d4*4);
        float4 b = *(const float4*)(xi + d4*4);
        int c = h*64 + d4*4;
        E[EIDX(i,c+0)] = f2bf((a.x-b.x)*inv);
        E[EIDX(i,c+1)] = f2bf((a.y-b.y)*inv);
        E[EIDX(i,c+2)] = f2bf((a.z-b.z)*inv);
        E[EIDX(i,c+3)] = f2bf((a.w-b.w)*inv);
      }
    }
  }
  __syncthreads();
  const int w = tid >> 6, lane = tid & 63;
  const int q = lane >> 4, loc = lane & 15;
  float hsum = 0.f;
  #pragma unroll
  for(int ni=0; ni<4; ni++){
    const int cb = half*64 + ni*16;
    #pragma unroll
    for(int mi=0; mi<2; mi++){
      const int rb = w*32 + mi*16;
      f32x4 as_ = {0.f,0.f,0.f,0.f}, at_ = {0.f,0.f,0.f,0.f};
      #pragma unroll
      for(int k0=0; k0<128; k0+=32){
        int ra = rb + loc, rbn = cb + loc;
        int ca = k0 + q*8;
        bf16x8 aS = *(const bf16x8*)(Es + EIDX(ra, ca));
        bf16x8 bS = *(const bf16x8*)(Es + EIDX(rbn, ca));
        bf16x8 aT = *(const bf16x8*)(Et + EIDX(ra, ca));
        bf16x8 bT = *(const bf16x8*)(Et + EIDX(rbn, ca));
        as_ = __builtin_amdgcn_mfma_f32_16x16x32_bf16(aS, bS, as_, 0,0,0);
        at_ = __builtin_amdgcn_mfma_f32_16x16x32_bf16(aT, bT, at_, 0,0,0);
      }
      #pragma unroll
      for(int jj=0; jj<4; jj++){
        int row = rb + q*4 + jj, col = cb + loc;
        if(row != col){
          float d = as_[jj] - at_[jj];
          float a = fabsf(d);
          hsum += (a < 1.f) ? 0.5f*a*a : a - 0.5f;
        }
      }
    }
  }
  hsum = wred_sum(hsum);
  __syncthreads();
  float* red = (float*)eSh;
  if(lane==0) red[w] = hsum;
  __syncthreads();
  if(tid==0) atomicAdd(accp+4, red[0]+red[1]+red[2]+red[3]);
}

// ---------------- Part B: convert+norm / saliency ----------------
// wave-per-row: grid ROWS/4 x 256 thr. float4 loads, no LDS, no block sync.
__global__ __launch_bounds__(256) void k_cvt_norm(const float* __restrict__ in,
    u16* __restrict__ out, float* __restrict__ nrm, int K){
  int w = threadIdx.x >> 6, l = threadIdx.x & 63;
  int r = blockIdx.x*4 + w;
  const float* row = in + (size_t)r*K;
  u16* orow = out + (size_t)r*K;
  float ss = 0.f;
  int nv = K >> 8;                      // float4 per lane: 3 (K=768) or 4 (K=1024)
  for(int i=0;i<nv;i++){
    int d = l*4 + i*256;
    float4 x = *(const float4*)(row + d);
    ushort4 o; o.x=f2bf(x.x); o.y=f2bf(x.y); o.z=f2bf(x.z); o.w=f2bf(x.w);
    *(ushort4*)(orow + d) = o;
    ss += x.x*x.x + x.y*x.y + x.z*x.z + x.w*x.w;
  }
  ss = wred_sum(ss);
  if(l==0) nrm[r] = sqrtf(ss);
}

// wave-per-row bf16 row norms (K multiple of 512): uint4 = 8 bf16 per load
__global__ __launch_bounds__(256) void k_row_norm_bf16(const u16* __restrict__ z,
    float* __restrict__ nrm, int K){
  int w = threadIdx.x >> 6, l = threadIdx.x & 63;
  int r = blockIdx.x*4 + w;
  const u16* row = z + (size_t)r*K;
  float ss = 0.f;
  int nv = K >> 9;                      // uint4 per lane: 2 (K=1024)
  for(int i=0;i<nv;i++){
    int d = l*8 + i*512;
    uint4 v = *(const uint4*)(row + d);
    float a0=__uint_as_float(v.x<<16), a1=__uint_as_float(v.x&0xffff0000u);
    float a2=__uint_as_float(v.y<<16), a3=__uint_as_float(v.y&0xffff0000u);
    float a4=__uint_as_float(v.z<<16), a5=__uint_as_float(v.z&0xffff0000u);
    float a6=__uint_as_float(v.w<<16), a7=__uint_as_float(v.w&0xffff0000u);
    ss += a0*a0+a1*a1+a2*a2+a3*a3+a4*a4+a5*a5+a6*a6+a7*a7;
  }
  ss = wred_sum(ss);
  if(l==0) nrm[r] = sqrtf(ss);
}

// W (HSS x HTT) f32 -> Wt (HTT x HSS) bf16
__global__ void k_wt(const float* __restrict__ W, u16* __restrict__ Wt){
  __shared__ float t[32][33];
  int k0 = blockIdx.y*32, n0 = blockIdx.x*32;
  int tx = threadIdx.x, ty = threadIdx.y;
  for(int r=0;r<32;r+=8) t[ty+r][tx] = W[(size_t)(k0+ty+r)*HTT + n0+tx];
  __syncthreads();
  for(int r=0;r<32;r+=8) Wt[(size_t)(n0+ty+r)*HSS + k0+tx] = f2bf(t[tx][ty+r]);
}

// fused saliency: blocks 0..63 -> (ns -> mu), 64..127 -> (nt -> nu)
__global__ __launch_bounds__(256) void k_saliency2(const float* __restrict__ ns,
    const float* __restrict__ nt, float* __restrict__ omu, float* __restrict__ onu){
  int b0 = blockIdx.x, n = threadIdx.x;
  const float* nrm = (b0 < NB) ? ns : nt;
  float* out = (b0 < NB) ? omu : onu;
  int b = b0 & 63;
  float x = nrm[b*NN+n];
  float mx = wred_max(x);
  __shared__ float sm[4], sm2[4];
  if((n&63)==0) sm[n>>6]=mx;
  __syncthreads();
  mx = fmaxf(fmaxf(sm[0],sm[1]),fmaxf(sm[2],sm[3]));
  float e = expf(x-mx);
  float s = wred_sum(e);
  if((n&63)==0) sm2[n>>6]=s;
  __syncthreads();
  s = sm2[0]+sm2[1]+sm2[2]+sm2[3];
  out[b*NN+n] = e/s;
}

// ---------------- MFMA GEMM (NT form) ----------------
enum { MODE_PROJ=0, MODE_COST=1, MODE_PLAIN=2, MODE_STRUCT=3 };

template<int MODE>
__global__ __launch_bounds__(256) void k_mfma(
    const u16* __restrict__ A, int lda, long bA,
    const u16* __restrict__ B, int ldb, long bB,
    int K,
    float* __restrict__ outF, u16* __restrict__ outB, int ldo, long bO,
    const float* __restrict__ nx, const float* __restrict__ ny,
    const float* __restrict__ bias,
    const float* __restrict__ Cs, const float* __restrict__ mu,
    float* __restrict__ accp)
{
  __shared__ u16 As[128*32];
  __shared__ u16 Bs[128*32];
  __shared__ float red[4];

  // XCD-aware bijective block swizzle (all grids have nwg % 8 == 0)
  int gx = gridDim.x, gy = gridDim.y;
  int flat = blockIdx.x + gx*(blockIdx.y + gy*blockIdx.z);
  int nwg  = gx*gy*gridDim.z;
  int cpx  = nwg >> 3;
  int lg   = (flat & 7)*cpx + (flat >> 3);
  int bx   = lg % gx;
  int rest = lg / gx;
  int by   = rest % gy;
  int b    = rest / gy;

  const u16* Ab = A + (size_t)b*bA;
  const u16* Bb = B + (size_t)b*bB;
  int tid = threadIdx.x;
  int lane = tid & 63, w = tid >> 6;
  int m0 = by*128, n0 = bx*128;
  int row_off = (w>>1)*64, col_off = (w&1)*64;
  int q = lane>>4, loc = lane&15;
  f32x4 acc[4][4] = {};

  const int srow = (lane >> 2);
  const int sslot = lane & 3;

  for(int k0=0;k0<K;k0+=32){
    #pragma unroll
    for(int h=0;h<2;h++){
      int row = h*64 + w*16 + srow;
      int ca  = (sslot ^ ((row>>1)&3))*8;            // inverse of read-side XOR
      u16* ldst = As + h*2048 + w*512 + lane*8;      // linear: row*32 + slot*8
      u16* ldstB= Bs + h*2048 + w*512 + lane*8;
      gl16(Ab + (size_t)(m0+row)*lda + k0 + ca, ldst);
      gl16(Bb + (size_t)(n0+row)*ldb + k0 + ca, ldstB);
    }
    __syncthreads();
    bf16x8 af[4], bfr[4];
    #pragma unroll
    for(int mi=0;mi<4;mi++){
      int r = row_off + mi*16 + loc;
      int slot = q ^ ((r>>1)&3);
      af[mi] = *(const bf16x8*)(As + r*32 + slot*8);
    }
    #pragma unroll
    for(int ni=0;ni<4;ni++){
      int r = col_off + ni*16 + loc;
      int slot = q ^ ((r>>1)&3);
      bfr[ni] = *(const bf16x8*)(Bs + r*32 + slot*8);
    }
    #pragma unroll
    for(int mi=0;mi<4;mi++)
      #pragma unroll
      for(int ni=0;ni<4;ni++)
        acc[mi][ni] = __builtin_amdgcn_mfma_f32_16x16x32_bf16(af[mi], bfr[ni], acc[mi][ni], 0,0,0);
    __syncthreads();
  }

  float* outFb = outF ? outF + (size_t)b*bO : nullptr;
  u16*   outBb = outB ? outB + (size_t)b*bO : nullptr;
  const float* nxb = nx ? nx + (size_t)b*NN : nullptr;
  const float* nyb = ny ? ny + (size_t)b*NN : nullptr;
  const float* Cb  = (MODE==MODE_STRUCT) ? Cs + (size_t)b*bO : nullptr;
  const float* mb  = (MODE==MODE_STRUCT) ? mu + (size_t)b*NN : nullptr;
  float lsum = 0.f;
  #pragma unroll
  for(int mi=0;mi<4;mi++){
    #pragma unroll
    for(int j=0;j<4;j++){
      int row = m0 + row_off + mi*16 + q*4 + j;
      float ir = 0.f, mr = 0.f;
      if(MODE==MODE_COST)   ir = 1.f/fmaxf(nxb[row],1e-12f);
      if(MODE==MODE_STRUCT) mr = mb[row];
      #pragma unroll
      for(int ni=0;ni<4;ni++){
        int col = n0 + col_off + ni*16 + loc;
        float v = acc[mi][ni][j];
        if(MODE==MODE_PROJ){
          v += bias[col];
          outBb[(size_t)row*ldo + col] = f2bf(v);
        } else if(MODE==MODE_COST){
          float ic = 1.f/fmaxf(nyb[col],1e-12f);
          v = 1.f - v*ir*ic;
          if(outFb) outFb[(size_t)row*ldo + col] = v;
          if(outBb) outBb[(size_t)row*ldo + col] = f2bf(v);
        } else if(MODE==MODE_PLAIN){
          outBb[(size_t)row*ldo + col] = f2bf(v);
        } else {
          float d = Cb[(size_t)row*ldo + col] - v;
          lsum += d*d*mr*mb[col];
        }
      }
    }
  }
  if(MODE==MODE_STRUCT){
    lsum = wred_sum(lsum);
    if(lane==0) red[w] = lsum;
    __syncthreads();
    if(tid==0) atomicAdd(accp+6, red[0]+red[1]+red[2]+red[3]);
  }
}

// ---------------- fused Sinkhorn: multiplicative domain, K in LDS ----------------
// REVERTED to the measured-best 4-phase structure (R2: 60 µs, 0 bank conflicts).
// Only change vs R2: row-phase dot uses 4 independent accumulators (identical
// addresses/operands, re-associated chain) to cut dependency latency.
#define SINK_DYN_LDS 131072
__global__ __launch_bounds__(1024, 1) void k_sinkhorn_fused(
    const u16* __restrict__ Mbf, const float* __restrict__ muL,
    const float* __restrict__ nuL, u16* __restrict__ Gn, float* __restrict__ accp)
{
  extern __shared__ u16 Ks[];                      // 256x256 bf16, swizzled
  __shared__ __align__(16) float part[4096];       // reduction scratch
  __shared__ __align__(16) float su[NN], sv[NN], smu[NN], snu[NN];
  __shared__ float red[16];

  const int b = blockIdx.x;
  const int t = threadIdx.x;
  const u16* Mb = Mbf + (size_t)b*NN*NN;

  #pragma unroll
  for(int i=0;i<16;i++){
    int e = (i*1024 + t)*4;
    int r = e>>8, c = e&255;
    ushort4 mv = *(const ushort4*)(Mb + e);
    ushort4 o;
    o.x = f2bf(exp2f(-C2LOG*bf2f(mv.x)));
    o.y = f2bf(exp2f(-C2LOG*bf2f(mv.y)));
    o.z = f2bf(exp2f(-C2LOG*bf2f(mv.z)));
    o.w = f2bf(exp2f(-C2LOG*bf2f(mv.w)));
    *(ushort4*)(Ks + LIDX(r,c)) = o;
  }
  if(t < NN){
    smu[t] = muL[(size_t)b*NN+t] + 1e-8f;
    snu[t] = nuL[(size_t)b*NN+t] + 1e-8f;
    sv[t] = 1.f;
  }
  __syncthreads();

  const int r_ = t & 255, p_ = t >> 8;
  const int w = t>>6, l = t&63;

  for(int it=0; it<20; it++){
    {
      float s0=0.f, s1=0.f, s2=0.f, s3=0.f;
      #pragma unroll
      for(int jj=0;jj<8;jj++){
        int c0 = p_*64 + jj*8;
        uint4 kv = *(const uint4*)(Ks + LIDX(r_, c0));
        float4 va = *(const float4*)(sv + c0);
        float4 vb = *(const float4*)(sv + c0 + 4);
        s0 = fmaf(__uint_as_float(kv.x<<16),           va.x, s0);
        s1 = fmaf(__uint_as_float(kv.x & 0xffff0000u), va.y, s1);
        s2 = fmaf(__uint_as_float(kv.y<<16),           va.z, s2);
        s3 = fmaf(__uint_as_float(kv.y & 0xffff0000u), va.w, s3);
        s0 = fmaf(__uint_as_float(kv.z<<16),           vb.x, s0);
        s1 = fmaf(__uint_as_float(kv.z & 0xffff0000u), vb.y, s1);
        s2 = fmaf(__uint_as_float(kv.w<<16),           vb.z, s2);
        s3 = fmaf(__uint_as_float(kv.w & 0xffff0000u), vb.w, s3);
      }
      part[t] = (s0+s1)+(s2+s3);
    }
    __syncthreads();
    if(t < NN){
      float S = part[t] + part[256+t] + part[512+t] + part[768+t];
      su[t] = smu[t] / S;
    }
    __syncthreads();
    {
      float cs0=0.f,cs1=0.f,cs2=0.f,cs3=0.f;
      #pragma unroll
      for(int rr=0;rr<16;rr++){
        int r = w*16 + rr;
        ushort4 kv = *(const ushort4*)(Ks + LIDX(r, l*4));
        float ur = su[r];
        cs0 = fmaf(bf2f(kv.x), ur, cs0);
        cs1 = fmaf(bf2f(kv.y), ur, cs1);
        cs2 = fmaf(bf2f(kv.z), ur, cs2);
        cs3 = fmaf(bf2f(kv.w), ur, cs3);
      }
      float4 o; o.x=cs0; o.y=cs1; o.z=cs2; o.w=cs3;
      *(float4*)(part + w*256 + l*4) = o;
    }
    __syncthreads();
    if(t < NN){
      float S = 0.f;
      #pragma unroll
      for(int ww=0;ww<16;ww++) S += part[ww*256 + t];
      sv[t] = snu[t] / S;
    }
    __syncthreads();
  }

  {
    float s0=0.f, s1=0.f, s2=0.f, s3=0.f;
    #pragma unroll
    for(int jj=0;jj<8;jj++){
      int c0 = p_*64 + jj*8;
      uint4 kv = *(const uint4*)(Ks + LIDX(r_, c0));
      float4 va = *(const float4*)(sv + c0);
      float4 vb = *(const float4*)(sv + c0 + 4);
      s0 = fmaf(__uint_as_float(kv.x<<16),           va.x, s0);
      s1 = fmaf(__uint_as_float(kv.x & 0xffff0000u), va.y, s1);
      s2 = fmaf(__uint_as_float(kv.y<<16),           va.z, s2);
      s3 = fmaf(__uint_as_float(kv.y & 0xffff0000u), va.w, s3);
      s0 = fmaf(__uint_as_float(kv.z<<16),           vb.x, s0);
      s1 = fmaf(__uint_as_float(kv.z & 0xffff0000u), vb.y, s1);
      s2 = fmaf(__uint_as_float(kv.w<<16),           vb.z, s2);
      s3 = fmaf(__uint_as_float(kv.w & 0xffff0000u), vb.w, s3);
    }
    part[t] = (s0+s1)+(s2+s3);
  }
  __syncthreads();
  if(t < NN){
    float S = part[t] + part[256+t] + part[512+t] + part[768+t];
    smu[t] = 1.f / (su[t]*S + 1e-8f);
  }
  __syncthreads();

  u16* Gb = Gn + (size_t)b*NN*NN;
  const float IC = -1.f/C2LOG;
  float v0 = sv[l*4+0], v1 = sv[l*4+1], v2 = sv[l*4+2], v3 = sv[l*4+3];
  float fl = 0.f;
  for(int rr=0;rr<16;rr++){
    int r = w*16 + rr;
    ushort4 kv = *(const ushort4*)(Ks + LIDX(r, l*4));
    float k0=bf2f(kv.x), k1=bf2f(kv.y), k2=bf2f(kv.z), k3=bf2f(kv.w);
    float ur = su[r], inv = smu[r];
    float g0=ur*k0*v0, g1=ur*k1*v1, g2=ur*k2*v2, g3=ur*k3*v3;
    fl += g0*(__log2f(k0)*IC) + g1*(__log2f(k1)*IC)
        + g2*(__log2f(k2)*IC) + g3*(__log2f(k3)*IC);
    ushort4 o;
    o.x=f2bf(g0*inv); o.y=f2bf(g1*inv); o.z=f2bf(g2*inv); o.w=f2bf(g3*inv);
    *(ushort4*)(Gb + (size_t)r*NN + l*4) = o;
  }
  fl = wred_sum(fl);
  if(l==0) red[w] = fl;
  __syncthreads();
  if(t==0){
    float s=0.f;
    #pragma unroll
    for(int i=0;i<16;i++) s+=red[i];
    atomicAdd(accp+5, s);
  }
}

__global__ void k_final(const float* __restrict__ acc, float* __restrict__ out){
  out[0] = acc[0]
         + 20.f*acc[3]*(1.f/8128.f)
         + 40.f*acc[4]*(1.f/2048256.f)
         + 0.25f*(acc[5]+acc[6])*(1.f/64.f);
}

// ---------------- host ----------------
extern "C" void kernel_launch(void* const* d_in, const int* in_sizes, int n_in,
                              void* d_out, int out_size, void* d_ws, size_t ws_size,
                              hipStream_t stream) {
  const float* s_q_reps   = (const float*)d_in[0];
  const float* s_p_reps   = (const float*)d_in[1];
  const float* t_q_reps   = (const float*)d_in[2];
  const float* t_p_reps   = (const float*)d_in[3];
  const float* s_q_states = (const float*)d_in[4];
  const float* s_p_states = (const float*)d_in[5];
  const float* t_q_states = (const float*)d_in[6];
  const float* t_p_states = (const float*)d_in[7];
  const float* proj_w     = (const float*)d_in[8];
  const float* proj_b     = (const float*)d_in[9];
  float* ws = (float*)d_ws;
  float* acc = ws + OFF_ACC;
  u16* M_BF   = (u16*)(ws + OFF_MBF);
  u16* ZS_BF  = (u16*)(ws + OFF_ZS_BF);
  u16* ZT_BF  = (u16*)(ws + OFF_ZT_BF);
  u16* WT_BF  = (u16*)(ws + OFF_WT_BF);
  u16* ZSP_BF = (u16*)(ws + OFF_ZSP_BF);
  u16* GN_BF  = (u16*)(ws + OFF_GN_BF);
  u16* CT_BF  = (u16*)(ws + OFF_CT_BF);
  u16* T_BF   = (u16*)(ws + OFF_T_BF);

  hipFuncSetAttribute(reinterpret_cast<const void*>(k_sinkhorn_fused),
                      hipFuncAttributeMaxDynamicSharedMemorySize, SINK_DYN_LDS);
  hipFuncSetAttribute(reinterpret_cast<const void*>(k_rkd_angle_mfma),
                      hipFuncAttributeMaxDynamicSharedMemorySize, RKD_LDS);

  hipMemsetAsync(acc, 0, 16*sizeof(float), stream);

  // ---- Part A ----
  k_l2norm_all<<<384,256,0,stream>>>(s_q_reps, s_p_reps, t_q_reps, t_p_reps, ws);
  k_contrastive2<<<128,512,0,stream>>>(ws, acc);
  k_gram_ds<<<128,128,0,stream>>>(ws+OFF_SQ128, ws+OFF_TQ128, ws+OFF_DS, ws+OFF_DT, acc);
  k_rkd_dist<<<128,128,0,stream>>>(ws+OFF_DS, ws+OFF_DT, acc);
  k_rkd_angle_mfma<<<256,256,RKD_LDS,stream>>>(ws+OFF_SQ128, ws+OFF_TQ128, acc);

  k_wt<<<dim3(HTT/32, HSS/32),dim3(32,8),0,stream>>>(proj_w, WT_BF);

  // ---- Part B phase 1: per-pass GEMMs into doubled buffers ----
  for(int pass=0; pass<2; pass++){
    const float* zs = pass ? s_p_states : s_q_states;
    const float* zt = pass ? t_p_states : t_q_states;
    size_t po  = (size_t)pass*NB*NN*NN;
    size_t pr  = (size_t)pass*ROWS;
    k_cvt_norm<<<ROWS/4,256,0,stream>>>(zs, ZS_BF, ws+OFF_NS, HSS);
    k_cvt_norm<<<ROWS/4,256,0,stream>>>(zt, ZT_BF, ws+OFF_NT, HTT);
    k_saliency2<<<128,256,0,stream>>>(ws+OFF_NS, ws+OFF_NT, ws+OFF_MU+pr, ws+OFF_NU+pr);
    k_mfma<MODE_PROJ><<<dim3(HTT/128, ROWS/128, 1),256,0,stream>>>(
        ZS_BF, HSS, 0, WT_BF, HSS, 0, HSS,
        nullptr, ZSP_BF, HTT, 0,
        nullptr, nullptr, proj_b, nullptr, nullptr, nullptr);
    k_row_norm_bf16<<<ROWS/4,256,0,stream>>>(ZSP_BF, ws+OFF_NSP, HTT);
    // C_s (f32)
    k_mfma<MODE_COST><<<dim3(2,2,NB),256,0,stream>>>(
        ZS_BF, HSS, (long)NN*HSS, ZS_BF, HSS, (long)NN*HSS, HSS,
        ws+OFF_CS+po, nullptr, NN, (long)NN*NN,
        ws+OFF_NS, ws+OFF_NS, nullptr, nullptr, nullptr, nullptr);
    // C_t (bf16)
    k_mfma<MODE_COST><<<dim3(2,2,NB),256,0,stream>>>(
        ZT_BF, HTT, (long)NN*HTT, ZT_BF, HTT, (long)NN*HTT, HTT,
        nullptr, CT_BF+po, NN, (long)NN*NN,
        ws+OFF_NT, ws+OFF_NT, nullptr, nullptr, nullptr, nullptr);
    // M (bf16)
    k_mfma<MODE_COST><<<dim3(2,2,NB),256,0,stream>>>(
        ZSP_BF, HTT, (long)NN*HTT, ZT_BF, HTT, (long)NN*HTT, HTT,
        nullptr, M_BF+po, NN, (long)NN*NN,
        ws+OFF_NSP, ws+OFF_NT, nullptr, nullptr, nullptr, nullptr);
  }

  // ---- Part B phase 2: Sinkhorn (both passes, multiplicative, K in LDS) ----
  k_sinkhorn_fused<<<2*NB,1024,SINK_DYN_LDS,stream>>>(
      M_BF, ws+OFF_MU, ws+OFF_NU, GN_BF, acc);

  // ---- Part B phase 3: T = Gn@Ct, struct loss (batched over both passes) ----
  k_mfma<MODE_PLAIN><<<dim3(2,2,2*NB),256,0,stream>>>(
      GN_BF, NN, (long)NN*NN, CT_BF, NN, (long)NN*NN, NN,
      nullptr, T_BF, NN, (long)NN*NN,
      nullptr, nullptr, nullptr, nullptr, nullptr, nullptr);
  k_mfma<MODE_STRUCT><<<dim3(2,2,2*NB),256,0,stream>>>(
      T_BF, NN, (long)NN*NN, GN_BF, NN, (long)NN*NN, NN,
      nullptr, nullptr, NN, (long)NN*NN,
      nullptr, nullptr, nullptr, ws+OFF_CS, ws+OFF_MU, acc);

  k_final<<<1,1,0,stream>>>(acc, (float*)d_out);
}

// Round 7
// 634.584 us; speedup vs baseline: 1.0824x; 1.0582x over previous
//
#include <hip/hip_runtime.h>
#include <math.h>

// Problem dims
#define NB   64      // batch B
#define NN   256     // tokens N
#define HSS  768     // H_S
#define HTT  1024    // H_T
#define ROWS (NB*NN) // 16384
#define C2LOG 14.426950408889634f  // 10 * log2(e)

typedef unsigned short u16;
typedef __attribute__((ext_vector_type(8))) short bf16x8;
typedef __attribute__((ext_vector_type(4))) float f32x4;

// swizzled LDS index for K[r][c] (256 cols): chunk rotation, 8-u16 granularity
#define LIDX(r,c) (((r)<<8) + (((((c)>>3) + (r)) & 31)<<3) + ((c)&7))
// swizzled LDS index for E[r][c] (128 cols, 16 chunks of 8)
#define EIDX(r,c) (((r)<<7) + (((((c)>>3) + (r)) & 15)<<3) + ((c)&7))

// async global->LDS, 16B per lane (gfx950)
__device__ __forceinline__ void gl16(const u16* g, u16* l){
  __builtin_amdgcn_global_load_lds(
      (const __attribute__((address_space(1))) unsigned int*)g,
      (__attribute__((address_space(3))) unsigned int*)l,
      16, 0, 0);
}

// ---------------- workspace layout (float offsets) ----------------
static const size_t OFF_ACC   = 0;                          // 16 floats
static const size_t OFF_SQ128 = 16;
static const size_t OFF_SP128 = OFF_SQ128 + 64*128;
static const size_t OFF_TQ128 = OFF_SP128 + 64*128;
static const size_t OFF_TP128 = OFF_TQ128 + 64*128;
static const size_t OFF_SQ768 = OFF_TP128 + 64*128;
static const size_t OFF_SP768 = OFF_SQ768 + 64*768;
static const size_t OFF_DS    = OFF_SP768 + 64*768;         // 128*128
static const size_t OFF_DT    = OFF_DS + 128*128;
static const size_t OFF_CS    = OFF_DT + 128*128;           // 2*B*N*N f32
static const size_t OFF_MBF   = OFF_CS  + (size_t)2*NB*NN*NN;     // 2*B*N*N bf16
static const size_t OFF_ZS_BF = OFF_MBF + (size_t)NB*NN*NN;       // 16384x768 bf16
static const size_t OFF_ZT_BF = OFF_ZS_BF + (size_t)ROWS*HSS/2;   // 16384x1024 bf16
static const size_t OFF_WT_BF = OFF_ZT_BF + (size_t)ROWS*HTT/2;   // 1024x768 bf16
static const size_t OFF_ZSP_BF= OFF_WT_BF + (size_t)HTT*HSS/2;    // 16384x1024 bf16
static const size_t OFF_GN_BF = OFF_ZSP_BF+ (size_t)ROWS*HTT/2;   // 2*B*N*N bf16
static const size_t OFF_CT_BF = OFF_GN_BF + (size_t)NB*NN*NN;     // 2*B*N*N bf16
static const size_t OFF_T_BF  = OFF_ZS_BF;                  // ALIAS: ZS dead after cost GEMMs
static const size_t OFF_NS    = OFF_CT_BF + (size_t)NB*NN*NN;
static const size_t OFF_NT    = OFF_NS + ROWS;
static const size_t OFF_NSP   = OFF_NT + ROWS;
static const size_t OFF_MU    = OFF_NSP + ROWS;             // 2*ROWS (linear)
static const size_t OFF_NU    = OFF_MU + 2*ROWS;            // 2*ROWS (linear)

// acc: 0=contrastive 1=ds_sum 2=dt_sum 3=dist_huber 4=angle_huber 5=feat 6=struct

// ---------------- helpers ----------------
__device__ __forceinline__ float wred_sum(float v){
  #pragma unroll
  for(int o=32;o>0;o>>=1) v += __shfl_xor(v,o,64);
  return v;
}
__device__ __forceinline__ float wred_max(float v){
  #pragma unroll
  for(int o=32;o>0;o>>=1) v = fmaxf(v, __shfl_xor(v,o,64));
  return v;
}
__device__ __forceinline__ u16 f2bf(float f){
  unsigned u = __float_as_uint(f);
  unsigned r = (u + 0x7fffu + ((u>>16)&1u)) >> 16;
  return (u16)r;
}
__device__ __forceinline__ float bf2f(u16 h){
  return __uint_as_float(((unsigned)h)<<16);
}

// ---------------- Part A kernels ----------------
// fused 6-way l2norm: blocks 0..255 -> 128-dim slices of {sq,sp,tq,tp};
// blocks 256..383 -> 768-dim of {sq,sp}
__global__ __launch_bounds__(256) void k_l2norm_all(
    const float* __restrict__ sq, const float* __restrict__ sp,
    const float* __restrict__ tq, const float* __restrict__ tp,
    float* __restrict__ ws){
  int bid = blockIdx.x;
  int r = bid & 63;
  const float* in; float* out; int kuse;
  if(bid < 64)       { in = sq; out = ws + OFF_SQ128; kuse = 128; }
  else if(bid < 128) { in = sp; out = ws + OFF_SP128; kuse = 128; }
  else if(bid < 192) { in = tq; out = ws + OFF_TQ128; kuse = 128; }
  else if(bid < 256) { in = tp; out = ws + OFF_TP128; kuse = 128; }
  else if(bid < 320) { in = sq; out = ws + OFF_SQ768; kuse = 768; }
  else               { in = sp; out = ws + OFF_SP768; kuse = 768; }
  const float* row = in + (size_t)r*768;
  float ss = 0.f;
  for(int d=threadIdx.x; d<kuse; d+=256){ float x=row[d]; ss += x*x; }
  ss = wred_sum(ss);
  __shared__ float sm[4];
  if((threadIdx.x&63)==0) sm[threadIdx.x>>6]=ss;
  __syncthreads();
  float tot = sm[0]+sm[1]+sm[2]+sm[3];
  float inv = 1.f / fmaxf(sqrtf(tot), 1e-12f);
  for(int d=threadIdx.x; d<kuse; d+=256) out[(size_t)r*kuse + d] = row[d]*inv;
}

// fused contrastive (both matryoshka dims): blocks 0..63 dim=128 w=1, 64..127 dim=768 w=2
__global__ __launch_bounds__(512) void k_contrastive2(const float* __restrict__ ws,
    float* __restrict__ acc){
  int bid = blockIdx.x;
  int i = bid & 63;
  int big = bid >> 6;
  const float* q = ws + (big ? OFF_SQ768 : OFF_SQ128);
  const float* p = ws + (big ? OFF_SP768 : OFF_SP128);
  int dim = big ? 768 : 128;
  float weight = big ? 2.f : 1.f;
  int j = threadIdx.x & 63;
  int part = threadIdx.x >> 6;           // 0..7
  const float* qi = q + (size_t)i*dim;
  const float* pj = p + (size_t)j*dim;
  int seg = dim >> 3;
  int d0 = part*seg;
  float dot = 0.f;
  for(int d=d0; d<d0+seg; d+=4){
    float4 a = *(const float4*)(qi+d);
    float4 b = *(const float4*)(pj+d);
    dot = fmaf(a.x,b.x,dot);
    dot = fmaf(a.y,b.y,dot);
    dot = fmaf(a.z,b.z,dot);
    dot = fmaf(a.w,b.w,dot);
  }
  __shared__ float sm[8][64];
  sm[part][j] = dot;
  __syncthreads();
  if(part==0){
    float s = 0.f;
    #pragma unroll
    for(int k=0;k<8;k++) s += sm[k][j];
    s = s / 0.07f;
    float mx = wred_max(s);
    float e = expf(s - mx);
    float Z = wred_sum(e);
    float logZ = mx + logf(Z);
    float diag = __shfl(s, i, 64);
    if(j==0) atomicAdd(acc+0, weight*(logZ - diag)*(1.f/64.f));
  }
}

// ---- packed cvt+gram: blocks [0,4096) cvt zs, [4096,8192) cvt zt,
// [8192,8320) gram_ds (pass-0 only; pass-1 launches with grid 8192).
__global__ __launch_bounds__(256) void k_pack_cvt(
    const float* __restrict__ zs, const float* __restrict__ zt,
    u16* __restrict__ zsb, u16* __restrict__ ztb,
    float* __restrict__ ns, float* __restrict__ nt,
    const float* __restrict__ sb128, const float* __restrict__ tb128,
    float* __restrict__ ds, float* __restrict__ dt, float* __restrict__ acc)
{
  __shared__ float sm[2][2];
  int bid = blockIdx.x;
  if(bid < 8192){
    const float* in; u16* out; float* nrm; int K; int cb;
    if(bid < 4096){ in=zs; out=zsb; nrm=ns; K=HSS; cb=bid; }
    else          { in=zt; out=ztb; nrm=nt; K=HTT; cb=bid-4096; }
    int w = threadIdx.x >> 6, l = threadIdx.x & 63;
    int r = cb*4 + w;
    const float* row = in + (size_t)r*K;
    u16* orow = out + (size_t)r*K;
    float ss = 0.f;
    int nv = K >> 8;
    for(int i=0;i<nv;i++){
      int d = l*4 + i*256;
      float4 x = *(const float4*)(row + d);
      ushort4 o; o.x=f2bf(x.x); o.y=f2bf(x.y); o.z=f2bf(x.z); o.w=f2bf(x.w);
      *(ushort4*)(orow + d) = o;
      ss += x.x*x.x + x.y*x.y + x.z*x.z + x.w*x.w;
    }
    ss = wred_sum(ss);
    if(l==0) nrm[r] = sqrtf(ss);
    return;
  }
  // gram_ds branch: r = bid-8192, active threads < 128 (waves 0,1)
  {
    int r = bid - 8192;
    int c = threadIdx.x;
    float ms = 0.f, mt = 0.f;
    if(c < 128){
      const float* sr = sb128 + r*128; const float* sc = sb128 + c*128;
      const float* tr = tb128 + r*128; const float* tc = tb128 + c*128;
      float dot_s=0,ssr=0,ssc=0,dot_t=0,tsr=0,tsc=0;
      for(int d=0; d<128; d++){
        float a=sr[d], bb=sc[d]; dot_s += a*bb; ssr += a*a; ssc += bb*bb;
        float at=tr[d], bt=tc[d]; dot_t += at*bt; tsr += at*at; tsc += bt*bt;
      }
      float dv = ssr + ssc - 2.f*dot_s;
      float tv = tsr + tsc - 2.f*dot_t;
      ds[r*128+c] = dv; dt[r*128+c] = tv;
      ms = (c>r)? dv : 0.f;
      mt = (c>r)? tv : 0.f;
      ms = wred_sum(ms); mt = wred_sum(mt);
      if((c&63)==0){ sm[0][c>>6]=ms; sm[1][c>>6]=mt; }
    }
    __syncthreads();
    if(threadIdx.x==0){
      atomicAdd(acc+1, sm[0][0]+sm[0][1]);
      atomicAdd(acc+2, sm[1][0]+sm[1][1]);
    }
  }
}

// packed small kernels (pass 0): blocks [0,128) rkd_dist, [128,256) saliency
__global__ __launch_bounds__(256) void k_small0(
    const float* __restrict__ ds, const float* __restrict__ dt,
    const float* __restrict__ ns, const float* __restrict__ nt,
    float* __restrict__ omu, float* __restrict__ onu, float* __restrict__ acc)
{
  __shared__ float sm[4], sm2[4];
  int bid = blockIdx.x;
  if(bid < 128){
    int r = bid, c = threadIdx.x;
    float mean_s = acc[1]*(1.f/8128.f) + 1e-8f;
    float mean_t = acc[2]*(1.f/8128.f) + 1e-8f;
    float h = 0.f;
    if(c < 128){
      if(c > r){
        float diff = ds[r*128+c]/mean_s - dt[r*128+c]/mean_t;
        float a = fabsf(diff);
        h = (a<1.f)? 0.5f*a*a : a-0.5f;
      }
      h = wred_sum(h);
      if((c&63)==0) sm[c>>6]=h;
    }
    __syncthreads();
    if(threadIdx.x==0) atomicAdd(acc+3, sm[0]+sm[1]);
    return;
  }
  // saliency branch
  {
    int b0 = bid - 128, n = threadIdx.x;
    const float* nrm = (b0 < NB) ? ns : nt;
    float* out = (b0 < NB) ? omu : onu;
    int b = b0 & 63;
    float x = nrm[b*NN+n];
    float mx = wred_max(x);
    if((n&63)==0) sm[n>>6]=mx;
    __syncthreads();
    mx = fmaxf(fmaxf(sm[0],sm[1]),fmaxf(sm[2],sm[3]));
    float e = expf(x-mx);
    float s = wred_sum(e);
    if((n&63)==0) sm2[n>>6]=s;
    __syncthreads();
    s = sm2[0]+sm2[1]+sm2[2]+sm2[3];
    out[b*NN+n] = e/s;
  }
}

// ---- RKD angle via MFMA: psi = E E^T, E in bf16 LDS, huber fused ----
#define RKD_LDS 65536
__global__ __launch_bounds__(256, 1) void k_rkd_angle_mfma(
    const float* __restrict__ sb, const float* __restrict__ tb,
    float* __restrict__ accp)
{
  extern __shared__ u16 eSh[];
  u16* Es = eSh;
  u16* Et = eSh + 128*128;
  const int j    = blockIdx.x >> 1;
  const int half = blockIdx.x & 1;
  const int tid = threadIdx.x;
  {
    const int i = tid >> 1, h = tid & 1;
    #pragma unroll
    for(int which=0; which<2; which++){
      const float* xb = which ? tb : sb;
      u16* E = which ? Et : Es;
      const float* xj = xb + j*128 + h*64;
      const float* xi = xb + i*128 + h*64;
      float ss = 0.f;
      #pragma unroll
      for(int d4=0; d4<16; d4++){
        float4 a = *(const float4*)(xj + d4*4);
        float4 b = *(const float4*)(xi + d4*4);
        float d0=a.x-b.x, d1=a.y-b.y, d2=a.z-b.z, d3=a.w-b.w;
        ss += d0*d0+d1*d1+d2*d2+d3*d3;
      }
      ss += __shfl_xor(ss, 1, 64);
      float inv = (i==j) ? 0.f : 1.f/(sqrtf(ss)+1e-8f);
      #pragma unroll
      for(int d4=0; d4<16; d4++){
        float4 a = *(const float4*)(xj + d4*4);
        float4 b = *(const float4*)(xi + d4*4);
        int c = h*64 + d4*4;
        E[EIDX(i,c+0)] = f2bf((a.x-b.x)*inv);
        E[EIDX(i,c+1)] = f2bf((a.y-b.y)*inv);
        E[EIDX(i,c+2)] = f2bf((a.z-b.z)*inv);
        E[EIDX(i,c+3)] = f2bf((a.w-b.w)*inv);
      }
    }
  }
  __syncthreads();
  const int w = tid >> 6, lane = tid & 63;
  const int q = lane >> 4, loc = lane & 15;
  float hsum = 0.f;
  #pragma unroll
  for(int ni=0; ni<4; ni++){
    const int cb = half*64 + ni*16;
    #pragma unroll
    for(int mi=0; mi<2; mi++){
      const int rb = w*32 + mi*16;
      f32x4 as_ = {0.f,0.f,0.f,0.f}, at_ = {0.f,0.f,0.f,0.f};
      #pragma unroll
      for(int k0=0; k0<128; k0+=32){
        int ra = rb + loc, rbn = cb + loc;
        int ca = k0 + q*8;
        bf16x8 aS = *(const bf16x8*)(Es + EIDX(ra, ca));
        bf16x8 bS = *(const bf16x8*)(Es + EIDX(rbn, ca));
        bf16x8 aT = *(const bf16x8*)(Et + EIDX(ra, ca));
        bf16x8 bT = *(const bf16x8*)(Et + EIDX(rbn, ca));
        as_ = __builtin_amdgcn_mfma_f32_16x16x32_bf16(aS, bS, as_, 0,0,0);
        at_ = __builtin_amdgcn_mfma_f32_16x16x32_bf16(aT, bT, at_, 0,0,0);
      }
      #pragma unroll
      for(int jj=0; jj<4; jj++){
        int row = rb + q*4 + jj, col = cb + loc;
        if(row != col){
          float d = as_[jj] - at_[jj];
          float a = fabsf(d);
          hsum += (a < 1.f) ? 0.5f*a*a : a - 0.5f;
        }
      }
    }
  }
  hsum = wred_sum(hsum);
  __syncthreads();
  float* red = (float*)eSh;
  if(lane==0) red[w] = hsum;
  __syncthreads();
  if(tid==0) atomicAdd(accp+4, red[0]+red[1]+red[2]+red[3]);
}

// wave-per-row bf16 row norms (K multiple of 512): uint4 = 8 bf16 per load
__global__ __launch_bounds__(256) void k_row_norm_bf16(const u16* __restrict__ z,
    float* __restrict__ nrm, int K){
  int w = threadIdx.x >> 6, l = threadIdx.x & 63;
  int r = blockIdx.x*4 + w;
  const u16* row = z + (size_t)r*K;
  float ss = 0.f;
  int nv = K >> 9;                      // uint4 per lane: 2 (K=1024)
  for(int i=0;i<nv;i++){
    int d = l*8 + i*512;
    uint4 v = *(const uint4*)(row + d);
    float a0=__uint_as_float(v.x<<16), a1=__uint_as_float(v.x&0xffff0000u);
    float a2=__uint_as_float(v.y<<16), a3=__uint_as_float(v.y&0xffff0000u);
    float a4=__uint_as_float(v.z<<16), a5=__uint_as_float(v.z&0xffff0000u);
    float a6=__uint_as_float(v.w<<16), a7=__uint_as_float(v.w&0xffff0000u);
    ss += a0*a0+a1*a1+a2*a2+a3*a3+a4*a4+a5*a5+a6*a6+a7*a7;
  }
  ss = wred_sum(ss);
  if(l==0) nrm[r] = sqrtf(ss);
}

// W (HSS x HTT) f32 -> Wt (HTT x HSS) bf16
__global__ void k_wt(const float* __restrict__ W, u16* __restrict__ Wt){
  __shared__ float t[32][33];
  int k0 = blockIdx.y*32, n0 = blockIdx.x*32;
  int tx = threadIdx.x, ty = threadIdx.y;
  for(int r=0;r<32;r+=8) t[ty+r][tx] = W[(size_t)(k0+ty+r)*HTT + n0+tx];
  __syncthreads();
  for(int r=0;r<32;r+=8) Wt[(size_t)(n0+ty+r)*HSS + k0+tx] = f2bf(t[tx][ty+r]);
}

// fused saliency: blocks 0..63 -> (ns -> mu), 64..127 -> (nt -> nu)
__global__ __launch_bounds__(256) void k_saliency2(const float* __restrict__ ns,
    const float* __restrict__ nt, float* __restrict__ omu, float* __restrict__ onu){
  int b0 = blockIdx.x, n = threadIdx.x;
  const float* nrm = (b0 < NB) ? ns : nt;
  float* out = (b0 < NB) ? omu : onu;
  int b = b0 & 63;
  float x = nrm[b*NN+n];
  float mx = wred_max(x);
  __shared__ float sm[4], sm2[4];
  if((n&63)==0) sm[n>>6]=mx;
  __syncthreads();
  mx = fmaxf(fmaxf(sm[0],sm[1]),fmaxf(sm[2],sm[3]));
  float e = expf(x-mx);
  float s = wred_sum(e);
  if((n&63)==0) sm2[n>>6]=s;
  __syncthreads();
  s = sm2[0]+sm2[1]+sm2[2]+sm2[3];
  out[b*NN+n] = e/s;
}

// ---------------- MFMA GEMM (NT form) ----------------
enum { MODE_PROJ=0, MODE_COST=1, MODE_PLAIN=2, MODE_STRUCT=3 };

// 128x128 tile (used for PROJ: grid 1024 blocks = 4 blocks/CU)
template<int MODE>
__global__ __launch_bounds__(256) void k_mfma(
    const u16* __restrict__ A, int lda, long bA,
    const u16* __restrict__ B, int ldb, long bB,
    int K,
    float* __restrict__ outF, u16* __restrict__ outB, int ldo, long bO,
    const float* __restrict__ nx, const float* __restrict__ ny,
    const float* __restrict__ bias,
    const float* __restrict__ Cs, const float* __restrict__ mu,
    float* __restrict__ accp)
{
  __shared__ u16 As[128*32];
  __shared__ u16 Bs[128*32];
  __shared__ float red[4];

  // XCD-aware bijective block swizzle (all grids have nwg % 8 == 0)
  int gx = gridDim.x, gy = gridDim.y;
  int flat = blockIdx.x + gx*(blockIdx.y + gy*blockIdx.z);
  int nwg  = gx*gy*gridDim.z;
  int cpx  = nwg >> 3;
  int lg   = (flat & 7)*cpx + (flat >> 3);
  int bx   = lg % gx;
  int rest = lg / gx;
  int by   = rest % gy;
  int b    = rest / gy;

  const u16* Ab = A + (size_t)b*bA;
  const u16* Bb = B + (size_t)b*bB;
  int tid = threadIdx.x;
  int lane = tid & 63, w = tid >> 6;
  int m0 = by*128, n0 = bx*128;
  int row_off = (w>>1)*64, col_off = (w&1)*64;
  int q = lane>>4, loc = lane&15;
  f32x4 acc[4][4] = {};

  const int srow = (lane >> 2);
  const int sslot = lane & 3;

  for(int k0=0;k0<K;k0+=32){
    #pragma unroll
    for(int h=0;h<2;h++){
      int row = h*64 + w*16 + srow;
      int ca  = (sslot ^ ((row>>1)&3))*8;            // inverse of read-side XOR
      u16* ldst = As + h*2048 + w*512 + lane*8;      // linear: row*32 + slot*8
      u16* ldstB= Bs + h*2048 + w*512 + lane*8;
      gl16(Ab + (size_t)(m0+row)*lda + k0 + ca, ldst);
      gl16(Bb + (size_t)(n0+row)*ldb + k0 + ca, ldstB);
    }
    __syncthreads();
    bf16x8 af[4], bfr[4];
    #pragma unroll
    for(int mi=0;mi<4;mi++){
      int r = row_off + mi*16 + loc;
      int slot = q ^ ((r>>1)&3);
      af[mi] = *(const bf16x8*)(As + r*32 + slot*8);
    }
    #pragma unroll
    for(int ni=0;ni<4;ni++){
      int r = col_off + ni*16 + loc;
      int slot = q ^ ((r>>1)&3);
      bfr[ni] = *(const bf16x8*)(Bs + r*32 + slot*8);
    }
    #pragma unroll
    for(int mi=0;mi<4;mi++)
      #pragma unroll
      for(int ni=0;ni<4;ni++)
        acc[mi][ni] = __builtin_amdgcn_mfma_f32_16x16x32_bf16(af[mi], bfr[ni], acc[mi][ni], 0,0,0);
    __syncthreads();
  }

  float* outFb = outF ? outF + (size_t)b*bO : nullptr;
  u16*   outBb = outB ? outB + (size_t)b*bO : nullptr;
  const float* nxb = nx ? nx + (size_t)b*NN : nullptr;
  const float* nyb = ny ? ny + (size_t)b*NN : nullptr;
  const float* Cb  = (MODE==MODE_STRUCT) ? Cs + (size_t)b*bO : nullptr;
  const float* mb  = (MODE==MODE_STRUCT) ? mu + (size_t)b*NN : nullptr;
  float lsum = 0.f;
  #pragma unroll
  for(int mi=0;mi<4;mi++){
    #pragma unroll
    for(int j=0;j<4;j++){
      int row = m0 + row_off + mi*16 + q*4 + j;
      float ir = 0.f, mr = 0.f;
      if(MODE==MODE_COST)   ir = 1.f/fmaxf(nxb[row],1e-12f);
      if(MODE==MODE_STRUCT) mr = mb[row];
      #pragma unroll
      for(int ni=0;ni<4;ni++){
        int col = n0 + col_off + ni*16 + loc;
        float v = acc[mi][ni][j];
        if(MODE==MODE_PROJ){
          v += bias[col];
          outBb[(size_t)row*ldo + col] = f2bf(v);
        } else if(MODE==MODE_COST){
          float ic = 1.f/fmaxf(nyb[col],1e-12f);
          v = 1.f - v*ir*ic;
          if(outFb) outFb[(size_t)row*ldo + col] = v;
          if(outBb) outBb[(size_t)row*ldo + col] = f2bf(v);
        } else if(MODE==MODE_PLAIN){
          outBb[(size_t)row*ldo + col] = f2bf(v);
        } else {
          float d = Cb[(size_t)row*ldo + col] - v;
          lsum += d*d*mr*mb[col];
        }
      }
    }
  }
  if(MODE==MODE_STRUCT){
    lsum = wred_sum(lsum);
    if(lane==0) red[w] = lsum;
    __syncthreads();
    if(tid==0) atomicAdd(accp+6, red[0]+red[1]+red[2]+red[3]);
  }
}

// 64x64 tile variant for the batched GEMMs (COST/PLAIN/STRUCT).
// Same staging/swizzle/fragment pattern as k_mfma; 4x the block count
// -> 4+ waves/SIMD instead of 1 (grids were exactly 1 block/CU).
// Per-output-element K accumulation order identical -> bit-same results.
template<int MODE>
__global__ __launch_bounds__(256) void k_mfma64(
    const u16* __restrict__ A, int lda, long bA,
    const u16* __restrict__ B, int ldb, long bB,
    int K,
    float* __restrict__ outF, u16* __restrict__ outB, int ldo, long bO,
    const float* __restrict__ nx, const float* __restrict__ ny,
    const float* __restrict__ bias,
    const float* __restrict__ Cs, const float* __restrict__ mu,
    float* __restrict__ accp)
{
  __shared__ u16 As[64*32];
  __shared__ u16 Bs[64*32];
  __shared__ float red[4];

  int gx = gridDim.x, gy = gridDim.y;
  int flat = blockIdx.x + gx*(blockIdx.y + gy*blockIdx.z);
  int nwg  = gx*gy*gridDim.z;
  int cpx  = nwg >> 3;
  int lg   = (flat & 7)*cpx + (flat >> 3);
  int bx   = lg % gx;
  int rest = lg / gx;
  int by   = rest % gy;
  int b    = rest / gy;

  const u16* Ab = A + (size_t)b*bA;
  const u16* Bb = B + (size_t)b*bB;
  int tid = threadIdx.x;
  int lane = tid & 63, w = tid >> 6;
  int m0 = by*64, n0 = bx*64;
  int row_off = (w>>1)*32, col_off = (w&1)*32;
  int q = lane>>4, loc = lane&15;
  f32x4 acc[2][2] = {};

  const int srow = tid >> 2;     // 0..63
  const int sslot = tid & 3;

  for(int k0=0;k0<K;k0+=32){
    {
      int row = srow;
      int ca  = (sslot ^ ((row>>1)&3))*8;
      u16* la = As + w*512 + lane*8;   // == row*32 + slot*8 (linear)
      u16* lb = Bs + w*512 + lane*8;
      gl16(Ab + (size_t)(m0+row)*lda + k0 + ca, la);
      gl16(Bb + (size_t)(n0+row)*ldb + k0 + ca, lb);
    }
    __syncthreads();
    bf16x8 af[2], bfr[2];
    #pragma unroll
    for(int mi=0;mi<2;mi++){
      int r = row_off + mi*16 + loc;
      int slot = q ^ ((r>>1)&3);
      af[mi] = *(const bf16x8*)(As + r*32 + slot*8);
    }
    #pragma unroll
    for(int ni=0;ni<2;ni++){
      int r = col_off + ni*16 + loc;
      int slot = q ^ ((r>>1)&3);
      bfr[ni] = *(const bf16x8*)(Bs + r*32 + slot*8);
    }
    #pragma unroll
    for(int mi=0;mi<2;mi++)
      #pragma unroll
      for(int ni=0;ni<2;ni++)
        acc[mi][ni] = __builtin_amdgcn_mfma_f32_16x16x32_bf16(af[mi], bfr[ni], acc[mi][ni], 0,0,0);
    __syncthreads();
  }

  float* outFb = outF ? outF + (size_t)b*bO : nullptr;
  u16*   outBb = outB ? outB + (size_t)b*bO : nullptr;
  const float* nxb = nx ? nx + (size_t)b*NN : nullptr;
  const float* nyb = ny ? ny + (size_t)b*NN : nullptr;
  const float* Cb  = (MODE==MODE_STRUCT) ? Cs + (size_t)b*bO : nullptr;
  const float* mb  = (MODE==MODE_STRUCT) ? mu + (size_t)b*NN : nullptr;
  float lsum = 0.f;
  #pragma unroll
  for(int mi=0;mi<2;mi++){
    #pragma unroll
    for(int j=0;j<4;j++){
      int row = m0 + row_off + mi*16 + q*4 + j;
      float ir = 0.f, mr = 0.f;
      if(MODE==MODE_COST)   ir = 1.f/fmaxf(nxb[row],1e-12f);
      if(MODE==MODE_STRUCT) mr = mb[row];
      #pragma unroll
      for(int ni=0;ni<2;ni++){
        int col = n0 + col_off + ni*16 + loc;
        float v = acc[mi][ni][j];
        if(MODE==MODE_PROJ){
          v += bias[col];
          outBb[(size_t)row*ldo + col] = f2bf(v);
        } else if(MODE==MODE_COST){
          float ic = 1.f/fmaxf(nyb[col],1e-12f);
          v = 1.f - v*ir*ic;
          if(outFb) outFb[(size_t)row*ldo + col] = v;
          if(outBb) outBb[(size_t)row*ldo + col] = f2bf(v);
        } else if(MODE==MODE_PLAIN){
          outBb[(size_t)row*ldo + col] = f2bf(v);
        } else {
          float d = Cb[(size_t)row*ldo + col] - v;
          lsum += d*d*mr*mb[col];
        }
      }
    }
  }
  if(MODE==MODE_STRUCT){
    lsum = wred_sum(lsum);
    if(lane==0) red[w] = lsum;
    __syncthreads();
    if(tid==0) atomicAdd(accp+6, red[0]+red[1]+red[2]+red[3]);
  }
}

// ---------------- fused Sinkhorn: multiplicative domain, K in LDS ----------------
// Measured-best 4-phase structure (R2/R5: ~60-64 us, 0 bank conflicts). DO NOT restructure:
// 2-phase(64), reg-K(90, spill), 3-phase(95, conflicts) all measured worse.
#define SINK_DYN_LDS 131072
__global__ __launch_bounds__(1024, 1) void k_sinkhorn_fused(
    const u16* __restrict__ Mbf, const float* __restrict__ muL,
    const float* __restrict__ nuL, u16* __restrict__ Gn, float* __restrict__ accp)
{
  extern __shared__ u16 Ks[];                      // 256x256 bf16, swizzled
  __shared__ __align__(16) float part[4096];       // reduction scratch
  __shared__ __align__(16) float su[NN], sv[NN], smu[NN], snu[NN];
  __shared__ float red[16];

  const int b = blockIdx.x;
  const int t = threadIdx.x;
  const u16* Mb = Mbf + (size_t)b*NN*NN;

  #pragma unroll
  for(int i=0;i<16;i++){
    int e = (i*1024 + t)*4;
    int r = e>>8, c = e&255;
    ushort4 mv = *(const ushort4*)(Mb + e);
    ushort4 o;
    o.x = f2bf(exp2f(-C2LOG*bf2f(mv.x)));
    o.y = f2bf(exp2f(-C2LOG*bf2f(mv.y)));
    o.z = f2bf(exp2f(-C2LOG*bf2f(mv.z)));
    o.w = f2bf(exp2f(-C2LOG*bf2f(mv.w)));
    *(ushort4*)(Ks + LIDX(r,c)) = o;
  }
  if(t < NN){
    smu[t] = muL[(size_t)b*NN+t] + 1e-8f;
    snu[t] = nuL[(size_t)b*NN+t] + 1e-8f;
    sv[t] = 1.f;
  }
  __syncthreads();

  const int r_ = t & 255, p_ = t >> 8;
  const int w = t>>6, l = t&63;

  for(int it=0; it<20; it++){
    {
      float s0=0.f, s1=0.f, s2=0.f, s3=0.f;
      #pragma unroll
      for(int jj=0;jj<8;jj++){
        int c0 = p_*64 + jj*8;
        uint4 kv = *(const uint4*)(Ks + LIDX(r_, c0));
        float4 va = *(const float4*)(sv + c0);
        float4 vb = *(const float4*)(sv + c0 + 4);
        s0 = fmaf(__uint_as_float(kv.x<<16),           va.x, s0);
        s1 = fmaf(__uint_as_float(kv.x & 0xffff0000u), va.y, s1);
        s2 = fmaf(__uint_as_float(kv.y<<16),           va.z, s2);
        s3 = fmaf(__uint_as_float(kv.y & 0xffff0000u), va.w, s3);
        s0 = fmaf(__uint_as_float(kv.z<<16),           vb.x, s0);
        s1 = fmaf(__uint_as_float(kv.z & 0xffff0000u), vb.y, s1);
        s2 = fmaf(__uint_as_float(kv.w<<16),           vb.z, s2);
        s3 = fmaf(__uint_as_float(kv.w & 0xffff0000u), vb.w, s3);
      }
      part[t] = (s0+s1)+(s2+s3);
    }
    __syncthreads();
    if(t < NN){
      float S = part[t] + part[256+t] + part[512+t] + part[768+t];
      su[t] = smu[t] / S;
    }
    __syncthreads();
    {
      float cs0=0.f,cs1=0.f,cs2=0.f,cs3=0.f;
      #pragma unroll
      for(int rr=0;rr<16;rr++){
        int r = w*16 + rr;
        ushort4 kv = *(const ushort4*)(Ks + LIDX(r, l*4));
        float ur = su[r];
        cs0 = fmaf(bf2f(kv.x), ur, cs0);
        cs1 = fmaf(bf2f(kv.y), ur, cs1);
        cs2 = fmaf(bf2f(kv.z), ur, cs2);
        cs3 = fmaf(bf2f(kv.w), ur, cs3);
      }
      float4 o; o.x=cs0; o.y=cs1; o.z=cs2; o.w=cs3;
      *(float4*)(part + w*256 + l*4) = o;
    }
    __syncthreads();
    if(t < NN){
      float S = 0.f;
      #pragma unroll
      for(int ww=0;ww<16;ww++) S += part[ww*256 + t];
      sv[t] = snu[t] / S;
    }
    __syncthreads();
  }

  {
    float s0=0.f, s1=0.f, s2=0.f, s3=0.f;
    #pragma unroll
    for(int jj=0;jj<8;jj++){
      int c0 = p_*64 + jj*8;
      uint4 kv = *(const uint4*)(Ks + LIDX(r_, c0));
      float4 va = *(const float4*)(sv + c0);
      float4 vb = *(const float4*)(sv + c0 + 4);
      s0 = fmaf(__uint_as_float(kv.x<<16),           va.x, s0);
      s1 = fmaf(__uint_as_float(kv.x & 0xffff0000u), va.y, s1);
      s2 = fmaf(__uint_as_float(kv.y<<16),           va.z, s2);
      s3 = fmaf(__uint_as_float(kv.y & 0xffff0000u), va.w, s3);
      s0 = fmaf(__uint_as_float(kv.z<<16),           vb.x, s0);
      s1 = fmaf(__uint_as_float(kv.z & 0xffff0000u), vb.y, s1);
      s2 = fmaf(__uint_as_float(kv.w<<16),           vb.z, s2);
      s3 = fmaf(__uint_as_float(kv.w & 0xffff0000u), vb.w, s3);
    }
    part[t] = (s0+s1)+(s2+s3);
  }
  __syncthreads();
  if(t < NN){
    float S = part[t] + part[256+t] + part[512+t] + part[768+t];
    smu[t] = 1.f / (su[t]*S + 1e-8f);
  }
  __syncthreads();

  u16* Gb = Gn + (size_t)b*NN*NN;
  const float IC = -1.f/C2LOG;
  float v0 = sv[l*4+0], v1 = sv[l*4+1], v2 = sv[l*4+2], v3 = sv[l*4+3];
  float fl = 0.f;
  for(int rr=0;rr<16;rr++){
    int r = w*16 + rr;
    ushort4 kv = *(const ushort4*)(Ks + LIDX(r, l*4));
    float k0=bf2f(kv.x), k1=bf2f(kv.y), k2=bf2f(kv.z), k3=bf2f(kv.w);
    float ur = su[r], inv = smu[r];
    float g0=ur*k0*v0, g1=ur*k1*v1, g2=ur*k2*v2, g3=ur*k3*v3;
    fl += g0*(__log2f(k0)*IC) + g1*(__log2f(k1)*IC)
        + g2*(__log2f(k2)*IC) + g3*(__log2f(k3)*IC);
    ushort4 o;
    o.x=f2bf(g0*inv); o.y=f2bf(g1*inv); o.z=f2bf(g2*inv); o.w=f2bf(g3*inv);
    *(ushort4*)(Gb + (size_t)r*NN + l*4) = o;
  }
  fl = wred_sum(fl);
  if(l==0) red[w] = fl;
  __syncthreads();
  if(t==0){
    float s=0.f;
    #pragma unroll
    for(int i=0;i<16;i++) s+=red[i];
    atomicAdd(accp+5, s);
  }
}

__global__ void k_final(const float* __restrict__ acc, float* __restrict__ out){
  out[0] = acc[0]
         + 20.f*acc[3]*(1.f/8128.f)
         + 40.f*acc[4]*(1.f/2048256.f)
         + 0.25f*(acc[5]+acc[6])*(1.f/64.f);
}

// ---------------- host ----------------
extern "C" void kernel_launch(void* const* d_in, const int* in_sizes, int n_in,
                              void* d_out, int out_size, void* d_ws, size_t ws_size,
                              hipStream_t stream) {
  const float* s_q_reps   = (const float*)d_in[0];
  const float* s_p_reps   = (const float*)d_in[1];
  const float* t_q_reps   = (const float*)d_in[2];
  const float* t_p_reps   = (const float*)d_in[3];
  const float* s_q_states = (const float*)d_in[4];
  const float* s_p_states = (const float*)d_in[5];
  const float* t_q_states = (const float*)d_in[6];
  const float* t_p_states = (const float*)d_in[7];
  const float* proj_w     = (const float*)d_in[8];
  const float* proj_b     = (const float*)d_in[9];
  float* ws = (float*)d_ws;
  float* acc = ws + OFF_ACC;
  u16* M_BF   = (u16*)(ws + OFF_MBF);
  u16* ZS_BF  = (u16*)(ws + OFF_ZS_BF);
  u16* ZT_BF  = (u16*)(ws + OFF_ZT_BF);
  u16* WT_BF  = (u16*)(ws + OFF_WT_BF);
  u16* ZSP_BF = (u16*)(ws + OFF_ZSP_BF);
  u16* GN_BF  = (u16*)(ws + OFF_GN_BF);
  u16* CT_BF  = (u16*)(ws + OFF_CT_BF);
  u16* T_BF   = (u16*)(ws + OFF_T_BF);

  hipFuncSetAttribute(reinterpret_cast<const void*>(k_sinkhorn_fused),
                      hipFuncAttributeMaxDynamicSharedMemorySize, SINK_DYN_LDS);
  hipFuncSetAttribute(reinterpret_cast<const void*>(k_rkd_angle_mfma),
                      hipFuncAttributeMaxDynamicSharedMemorySize, RKD_LDS);

  hipMemsetAsync(acc, 0, 16*sizeof(float), stream);

  // ---- Part A ----
  k_l2norm_all<<<384,256,0,stream>>>(s_q_reps, s_p_reps, t_q_reps, t_p_reps, ws);
  k_contrastive2<<<128,512,0,stream>>>(ws, acc);

  // pass-0 cvt (zs,zt) + gram packed into one launch
  k_pack_cvt<<<8320,256,0,stream>>>(s_q_states, t_q_states, ZS_BF, ZT_BF,
      ws+OFF_NS, ws+OFF_NT, ws+OFF_SQ128, ws+OFF_TQ128, ws+OFF_DS, ws+OFF_DT, acc);
  // rkd_dist + saliency(pass0) packed
  k_small0<<<256,256,0,stream>>>(ws+OFF_DS, ws+OFF_DT, ws+OFF_NS, ws+OFF_NT,
      ws+OFF_MU, ws+OFF_NU, acc);
  k_rkd_angle_mfma<<<256,256,RKD_LDS,stream>>>(ws+OFF_SQ128, ws+OFF_TQ128, acc);
  k_wt<<<dim3(HTT/32, HSS/32),dim3(32,8),0,stream>>>(proj_w, WT_BF);

  // ---- Part B phase 1 ----
  for(int pass=0; pass<2; pass++){
    size_t po  = (size_t)pass*NB*NN*NN;
    size_t pr  = (size_t)pass*ROWS;
    if(pass==1){
      k_pack_cvt<<<8192,256,0,stream>>>(s_p_states, t_p_states, ZS_BF, ZT_BF,
          ws+OFF_NS, ws+OFF_NT, ws+OFF_SQ128, ws+OFF_TQ128, ws+OFF_DS, ws+OFF_DT, acc);
      k_saliency2<<<128,256,0,stream>>>(ws+OFF_NS, ws+OFF_NT, ws+OFF_MU+pr, ws+OFF_NU+pr);
    }
    k_mfma<MODE_PROJ><<<dim3(HTT/128, ROWS/128, 1),256,0,stream>>>(
        ZS_BF, HSS, 0, WT_BF, HSS, 0, HSS,
        nullptr, ZSP_BF, HTT, 0,
        nullptr, nullptr, proj_b, nullptr, nullptr, nullptr);
    k_row_norm_bf16<<<ROWS/4,256,0,stream>>>(ZSP_BF, ws+OFF_NSP, HTT);
    // C_s (f32) — 64² tiles, 1024 blocks
    k_mfma64<MODE_COST><<<dim3(4,4,NB),256,0,stream>>>(
        ZS_BF, HSS, (long)NN*HSS, ZS_BF, HSS, (long)NN*HSS, HSS,
        ws+OFF_CS+po, nullptr, NN, (long)NN*NN,
        ws+OFF_NS, ws+OFF_NS, nullptr, nullptr, nullptr, nullptr);
    // C_t (bf16)
    k_mfma64<MODE_COST><<<dim3(4,4,NB),256,0,stream>>>(
        ZT_BF, HTT, (long)NN*HTT, ZT_BF, HTT, (long)NN*HTT, HTT,
        nullptr, CT_BF+po, NN, (long)NN*NN,
        ws+OFF_NT, ws+OFF_NT, nullptr, nullptr, nullptr, nullptr);
    // M (bf16)
    k_mfma64<MODE_COST><<<dim3(4,4,NB),256,0,stream>>>(
        ZSP_BF, HTT, (long)NN*HTT, ZT_BF, HTT, (long)NN*HTT, HTT,
        nullptr, M_BF+po, NN, (long)NN*NN,
        ws+OFF_NSP, ws+OFF_NT, nullptr, nullptr, nullptr, nullptr);
  }

  // ---- Part B phase 2: Sinkhorn (both passes, multiplicative, K in LDS) ----
  k_sinkhorn_fused<<<2*NB,1024,SINK_DYN_LDS,stream>>>(
      M_BF, ws+OFF_MU, ws+OFF_NU, GN_BF, acc);

  // ---- Part B phase 3: T = Gn@Ct, struct loss (batched, 64² tiles) ----
  k_mfma64<MODE_PLAIN><<<dim3(4,4,2*NB),256,0,stream>>>(
      GN_BF, NN, (long)NN*NN, CT_BF, NN, (long)NN*NN, NN,
      nullptr, T_BF, NN, (long)NN*NN,
      nullptr, nullptr, nullptr, nullptr, nullptr, nullptr);
  k_mfma64<MODE_STRUCT><<<dim3(4,4,2*NB),256,0,stream>>>(
      T_BF, NN, (long)NN*NN, GN_BF, NN, (long)NN*NN, NN,
      nullptr, nullptr, NN, (long)NN*NN,
      nullptr, nullptr, nullptr, ws+OFF_CS, ws+OFF_MU, acc);

  k_final<<<1,1,0,stream>>>(acc, (float*)d_out);
}

// Round 8
// 603.082 us; speedup vs baseline: 1.1389x; 1.0522x over previous
//
#include <hip/hip_runtime.h>
#include <math.h>

// Problem dims
#define NB   64      // batch B
#define NN   256     // tokens N
#define HSS  768     // H_S
#define HTT  1024    // H_T
#define ROWS (NB*NN) // 16384
#define C2LOG 14.426950408889634f  // 10 * log2(e)

typedef unsigned short u16;
typedef __attribute__((ext_vector_type(8))) short bf16x8;
typedef __attribute__((ext_vector_type(4))) float f32x4;

// swizzled LDS index for K[r][c] (256 cols): chunk rotation, 8-u16 granularity
#define LIDX(r,c) (((r)<<8) + (((((c)>>3) + (r)) & 31)<<3) + ((c)&7))
// swizzled LDS index for E[r][c] (128 cols, 16 chunks of 8)
#define EIDX(r,c) (((r)<<7) + (((((c)>>3) + (r)) & 15)<<3) + ((c)&7))

// async global->LDS, 16B per lane (gfx950)
__device__ __forceinline__ void gl16(const u16* g, u16* l){
  __builtin_amdgcn_global_load_lds(
      (const __attribute__((address_space(1))) unsigned int*)g,
      (__attribute__((address_space(3))) unsigned int*)l,
      16, 0, 0);
}

// ---------------- workspace layout (float offsets) ----------------
static const size_t OFF_ACC   = 0;                          // 16 floats
static const size_t OFF_SQ128 = 16;
static const size_t OFF_SP128 = OFF_SQ128 + 64*128;
static const size_t OFF_TQ128 = OFF_SP128 + 64*128;
static const size_t OFF_TP128 = OFF_TQ128 + 64*128;
static const size_t OFF_SQ768 = OFF_TP128 + 64*128;
static const size_t OFF_SP768 = OFF_SQ768 + 64*768;
static const size_t OFF_DS    = OFF_SP768 + 64*768;         // 128*128
static const size_t OFF_DT    = OFF_DS + 128*128;
static const size_t OFF_CS    = OFF_DT + 128*128;           // 2*B*N*N f32
static const size_t OFF_MBF   = OFF_CS  + (size_t)2*NB*NN*NN;     // 2*B*N*N bf16
static const size_t OFF_ZS_BF = OFF_MBF + (size_t)NB*NN*NN;       // 16384x768 bf16
static const size_t OFF_ZT_BF = OFF_ZS_BF + (size_t)ROWS*HSS/2;   // 16384x1024 bf16
static const size_t OFF_WT_BF = OFF_ZT_BF + (size_t)ROWS*HTT/2;   // 1024x768 bf16
static const size_t OFF_ZSP_BF= OFF_WT_BF + (size_t)HTT*HSS/2;    // 16384x1024 bf16
static const size_t OFF_GN_BF = OFF_ZSP_BF+ (size_t)ROWS*HTT/2;   // 2*B*N*N bf16
static const size_t OFF_CT_BF = OFF_GN_BF + (size_t)NB*NN*NN;     // 2*B*N*N bf16
static const size_t OFF_T_BF  = OFF_ZS_BF;                  // ALIAS: ZS dead after cost GEMMs
static const size_t OFF_NS    = OFF_CT_BF + (size_t)NB*NN*NN;
static const size_t OFF_NT    = OFF_NS + ROWS;
static const size_t OFF_NSP   = OFF_NT + ROWS;
static const size_t OFF_MU    = OFF_NSP + ROWS;             // 2*ROWS (linear)
static const size_t OFF_NU    = OFF_MU + 2*ROWS;            // 2*ROWS (linear)

// acc: 0=contrastive 1=ds_sum 2=dt_sum 3=dist_huber 4=angle_huber 5=feat 6=struct

// ---------------- helpers ----------------
__device__ __forceinline__ float wred_sum(float v){
  #pragma unroll
  for(int o=32;o>0;o>>=1) v += __shfl_xor(v,o,64);
  return v;
}
__device__ __forceinline__ float wred_max(float v){
  #pragma unroll
  for(int o=32;o>0;o>>=1) v = fmaxf(v, __shfl_xor(v,o,64));
  return v;
}
__device__ __forceinline__ u16 f2bf(float f){
  unsigned u = __float_as_uint(f);
  unsigned r = (u + 0x7fffu + ((u>>16)&1u)) >> 16;
  return (u16)r;
}
__device__ __forceinline__ float bf2f(u16 h){
  return __uint_as_float(((unsigned)h)<<16);
}

// ---------------- Part A kernels ----------------
// fused 6-way l2norm: blocks 0..255 -> 128-dim slices of {sq,sp,tq,tp};
// blocks 256..383 -> 768-dim of {sq,sp}
__global__ __launch_bounds__(256) void k_l2norm_all(
    const float* __restrict__ sq, const float* __restrict__ sp,
    const float* __restrict__ tq, const float* __restrict__ tp,
    float* __restrict__ ws){
  int bid = blockIdx.x;
  int r = bid & 63;
  const float* in; float* out; int kuse;
  if(bid < 64)       { in = sq; out = ws + OFF_SQ128; kuse = 128; }
  else if(bid < 128) { in = sp; out = ws + OFF_SP128; kuse = 128; }
  else if(bid < 192) { in = tq; out = ws + OFF_TQ128; kuse = 128; }
  else if(bid < 256) { in = tp; out = ws + OFF_TP128; kuse = 128; }
  else if(bid < 320) { in = sq; out = ws + OFF_SQ768; kuse = 768; }
  else               { in = sp; out = ws + OFF_SP768; kuse = 768; }
  const float* row = in + (size_t)r*768;
  float ss = 0.f;
  for(int d=threadIdx.x; d<kuse; d+=256){ float x=row[d]; ss += x*x; }
  ss = wred_sum(ss);
  __shared__ float sm[4];
  if((threadIdx.x&63)==0) sm[threadIdx.x>>6]=ss;
  __syncthreads();
  float tot = sm[0]+sm[1]+sm[2]+sm[3];
  float inv = 1.f / fmaxf(sqrtf(tot), 1e-12f);
  for(int d=threadIdx.x; d<kuse; d+=256) out[(size_t)r*kuse + d] = row[d]*inv;
}

// fused contrastive (both matryoshka dims): blocks 0..63 dim=128 w=1, 64..127 dim=768 w=2
__global__ __launch_bounds__(512) void k_contrastive2(const float* __restrict__ ws,
    float* __restrict__ acc){
  int bid = blockIdx.x;
  int i = bid & 63;
  int big = bid >> 6;
  const float* q = ws + (big ? OFF_SQ768 : OFF_SQ128);
  const float* p = ws + (big ? OFF_SP768 : OFF_SP128);
  int dim = big ? 768 : 128;
  float weight = big ? 2.f : 1.f;
  int j = threadIdx.x & 63;
  int part = threadIdx.x >> 6;           // 0..7
  const float* qi = q + (size_t)i*dim;
  const float* pj = p + (size_t)j*dim;
  int seg = dim >> 3;
  int d0 = part*seg;
  float dot = 0.f;
  for(int d=d0; d<d0+seg; d+=4){
    float4 a = *(const float4*)(qi+d);
    float4 b = *(const float4*)(pj+d);
    dot = fmaf(a.x,b.x,dot);
    dot = fmaf(a.y,b.y,dot);
    dot = fmaf(a.z,b.z,dot);
    dot = fmaf(a.w,b.w,dot);
  }
  __shared__ float sm[8][64];
  sm[part][j] = dot;
  __syncthreads();
  if(part==0){
    float s = 0.f;
    #pragma unroll
    for(int k=0;k<8;k++) s += sm[k][j];
    s = s / 0.07f;
    float mx = wred_max(s);
    float e = expf(s - mx);
    float Z = wred_sum(e);
    float logZ = mx + logf(Z);
    float diag = __shfl(s, i, 64);
    if(j==0) atomicAdd(acc+0, weight*(logZ - diag)*(1.f/64.f));
  }
}

// ---- packed cvt+gram: blocks [0,4096) cvt zs, [4096,8192) cvt zt,
// [8192,8320) gram_ds (pass-0 only; pass-1 launches with grid 8192).
__global__ __launch_bounds__(256) void k_pack_cvt(
    const float* __restrict__ zs, const float* __restrict__ zt,
    u16* __restrict__ zsb, u16* __restrict__ ztb,
    float* __restrict__ ns, float* __restrict__ nt,
    const float* __restrict__ sb128, const float* __restrict__ tb128,
    float* __restrict__ ds, float* __restrict__ dt, float* __restrict__ acc)
{
  __shared__ float sm[2][2];
  int bid = blockIdx.x;
  if(bid < 8192){
    const float* in; u16* out; float* nrm; int K; int cb;
    if(bid < 4096){ in=zs; out=zsb; nrm=ns; K=HSS; cb=bid; }
    else          { in=zt; out=ztb; nrm=nt; K=HTT; cb=bid-4096; }
    int w = threadIdx.x >> 6, l = threadIdx.x & 63;
    int r = cb*4 + w;
    const float* row = in + (size_t)r*K;
    u16* orow = out + (size_t)r*K;
    float ss = 0.f;
    int nv = K >> 8;
    for(int i=0;i<nv;i++){
      int d = l*4 + i*256;
      float4 x = *(const float4*)(row + d);
      ushort4 o; o.x=f2bf(x.x); o.y=f2bf(x.y); o.z=f2bf(x.z); o.w=f2bf(x.w);
      *(ushort4*)(orow + d) = o;
      ss += x.x*x.x + x.y*x.y + x.z*x.z + x.w*x.w;
    }
    ss = wred_sum(ss);
    if(l==0) nrm[r] = sqrtf(ss);
    return;
  }
  // gram_ds branch: r = bid-8192, active threads < 128 (waves 0,1)
  {
    int r = bid - 8192;
    int c = threadIdx.x;
    float ms = 0.f, mt = 0.f;
    if(c < 128){
      const float* sr = sb128 + r*128; const float* sc = sb128 + c*128;
      const float* tr = tb128 + r*128; const float* tc = tb128 + c*128;
      float dot_s=0,ssr=0,ssc=0,dot_t=0,tsr=0,tsc=0;
      for(int d=0; d<128; d++){
        float a=sr[d], bb=sc[d]; dot_s += a*bb; ssr += a*a; ssc += bb*bb;
        float at=tr[d], bt=tc[d]; dot_t += at*bt; tsr += at*at; tsc += bt*bt;
      }
      float dv = ssr + ssc - 2.f*dot_s;
      float tv = tsr + tsc - 2.f*dot_t;
      ds[r*128+c] = dv; dt[r*128+c] = tv;
      ms = (c>r)? dv : 0.f;
      mt = (c>r)? tv : 0.f;
      ms = wred_sum(ms); mt = wred_sum(mt);
      if((c&63)==0){ sm[0][c>>6]=ms; sm[1][c>>6]=mt; }
    }
    __syncthreads();
    if(threadIdx.x==0){
      atomicAdd(acc+1, sm[0][0]+sm[0][1]);
      atomicAdd(acc+2, sm[1][0]+sm[1][1]);
    }
  }
}

// packed small kernels (pass 0): blocks [0,128) rkd_dist, [128,256) saliency
__global__ __launch_bounds__(256) void k_small0(
    const float* __restrict__ ds, const float* __restrict__ dt,
    const float* __restrict__ ns, const float* __restrict__ nt,
    float* __restrict__ omu, float* __restrict__ onu, float* __restrict__ acc)
{
  __shared__ float sm[4], sm2[4];
  int bid = blockIdx.x;
  if(bid < 128){
    int r = bid, c = threadIdx.x;
    float mean_s = acc[1]*(1.f/8128.f) + 1e-8f;
    float mean_t = acc[2]*(1.f/8128.f) + 1e-8f;
    float h = 0.f;
    if(c < 128){
      if(c > r){
        float diff = ds[r*128+c]/mean_s - dt[r*128+c]/mean_t;
        float a = fabsf(diff);
        h = (a<1.f)? 0.5f*a*a : a-0.5f;
      }
      h = wred_sum(h);
      if((c&63)==0) sm[c>>6]=h;
    }
    __syncthreads();
    if(threadIdx.x==0) atomicAdd(acc+3, sm[0]+sm[1]);
    return;
  }
  // saliency branch
  {
    int b0 = bid - 128, n = threadIdx.x;
    const float* nrm = (b0 < NB) ? ns : nt;
    float* out = (b0 < NB) ? omu : onu;
    int b = b0 & 63;
    float x = nrm[b*NN+n];
    float mx = wred_max(x);
    if((n&63)==0) sm[n>>6]=mx;
    __syncthreads();
    mx = fmaxf(fmaxf(sm[0],sm[1]),fmaxf(sm[2],sm[3]));
    float e = expf(x-mx);
    float s = wred_sum(e);
    if((n&63)==0) sm2[n>>6]=s;
    __syncthreads();
    s = sm2[0]+sm2[1]+sm2[2]+sm2[3];
    out[b*NN+n] = e/s;
  }
}

// ---- RKD angle via MFMA: psi = E E^T, E in bf16 LDS, huber fused ----
#define RKD_LDS 65536
__global__ __launch_bounds__(256, 1) void k_rkd_angle_mfma(
    const float* __restrict__ sb, const float* __restrict__ tb,
    float* __restrict__ accp)
{
  extern __shared__ u16 eSh[];
  u16* Es = eSh;
  u16* Et = eSh + 128*128;
  const int j    = blockIdx.x >> 1;
  const int half = blockIdx.x & 1;
  const int tid = threadIdx.x;
  {
    const int i = tid >> 1, h = tid & 1;
    #pragma unroll
    for(int which=0; which<2; which++){
      const float* xb = which ? tb : sb;
      u16* E = which ? Et : Es;
      const float* xj = xb + j*128 + h*64;
      const float* xi = xb + i*128 + h*64;
      float ss = 0.f;
      #pragma unroll
      for(int d4=0; d4<16; d4++){
        float4 a = *(const float4*)(xj + d4*4);
        float4 b = *(const float4*)(xi + d4*4);
        float d0=a.x-b.x, d1=a.y-b.y, d2=a.z-b.z, d3=a.w-b.w;
        ss += d0*d0+d1*d1+d2*d2+d3*d3;
      }
      ss += __shfl_xor(ss, 1, 64);
      float inv = (i==j) ? 0.f : 1.f/(sqrtf(ss)+1e-8f);
      #pragma unroll
      for(int d4=0; d4<16; d4++){
        float4 a = *(const float4*)(xj + d4*4);
        float4 b = *(const float4*)(xi + d4*4);
        int c = h*64 + d4*4;
        E[EIDX(i,c+0)] = f2bf((a.x-b.x)*inv);
        E[EIDX(i,c+1)] = f2bf((a.y-b.y)*inv);
        E[EIDX(i,c+2)] = f2bf((a.z-b.z)*inv);
        E[EIDX(i,c+3)] = f2bf((a.w-b.w)*inv);
      }
    }
  }
  __syncthreads();
  const int w = tid >> 6, lane = tid & 63;
  const int q = lane >> 4, loc = lane & 15;
  float hsum = 0.f;
  #pragma unroll
  for(int ni=0; ni<4; ni++){
    const int cb = half*64 + ni*16;
    #pragma unroll
    for(int mi=0; mi<2; mi++){
      const int rb = w*32 + mi*16;
      f32x4 as_ = {0.f,0.f,0.f,0.f}, at_ = {0.f,0.f,0.f,0.f};
      #pragma unroll
      for(int k0=0; k0<128; k0+=32){
        int ra = rb + loc, rbn = cb + loc;
        int ca = k0 + q*8;
        bf16x8 aS = *(const bf16x8*)(Es + EIDX(ra, ca));
        bf16x8 bS = *(const bf16x8*)(Es + EIDX(rbn, ca));
        bf16x8 aT = *(const bf16x8*)(Et + EIDX(ra, ca));
        bf16x8 bT = *(const bf16x8*)(Et + EIDX(rbn, ca));
        as_ = __builtin_amdgcn_mfma_f32_16x16x32_bf16(aS, bS, as_, 0,0,0);
        at_ = __builtin_amdgcn_mfma_f32_16x16x32_bf16(aT, bT, at_, 0,0,0);
      }
      #pragma unroll
      for(int jj=0; jj<4; jj++){
        int row = rb + q*4 + jj, col = cb + loc;
        if(row != col){
          float d = as_[jj] - at_[jj];
          float a = fabsf(d);
          hsum += (a < 1.f) ? 0.5f*a*a : a - 0.5f;
        }
      }
    }
  }
  hsum = wred_sum(hsum);
  __syncthreads();
  float* red = (float*)eSh;
  if(lane==0) red[w] = hsum;
  __syncthreads();
  if(tid==0) atomicAdd(accp+4, red[0]+red[1]+red[2]+red[3]);
}

// wave-per-row bf16 row norms (K multiple of 512): uint4 = 8 bf16 per load
__global__ __launch_bounds__(256) void k_row_norm_bf16(const u16* __restrict__ z,
    float* __restrict__ nrm, int K){
  int w = threadIdx.x >> 6, l = threadIdx.x & 63;
  int r = blockIdx.x*4 + w;
  const u16* row = z + (size_t)r*K;
  float ss = 0.f;
  int nv = K >> 9;                      // uint4 per lane: 2 (K=1024)
  for(int i=0;i<nv;i++){
    int d = l*8 + i*512;
    uint4 v = *(const uint4*)(row + d);
    float a0=__uint_as_float(v.x<<16), a1=__uint_as_float(v.x&0xffff0000u);
    float a2=__uint_as_float(v.y<<16), a3=__uint_as_float(v.y&0xffff0000u);
    float a4=__uint_as_float(v.z<<16), a5=__uint_as_float(v.z&0xffff0000u);
    float a6=__uint_as_float(v.w<<16), a7=__uint_as_float(v.w&0xffff0000u);
    ss += a0*a0+a1*a1+a2*a2+a3*a3+a4*a4+a5*a5+a6*a6+a7*a7;
  }
  ss = wred_sum(ss);
  if(l==0) nrm[r] = sqrtf(ss);
}

// W (HSS x HTT) f32 -> Wt (HTT x HSS) bf16
__global__ void k_wt(const float* __restrict__ W, u16* __restrict__ Wt){
  __shared__ float t[32][33];
  int k0 = blockIdx.y*32, n0 = blockIdx.x*32;
  int tx = threadIdx.x, ty = threadIdx.y;
  for(int r=0;r<32;r+=8) t[ty+r][tx] = W[(size_t)(k0+ty+r)*HTT + n0+tx];
  __syncthreads();
  for(int r=0;r<32;r+=8) Wt[(size_t)(n0+ty+r)*HSS + k0+tx] = f2bf(t[tx][ty+r]);
}

// fused saliency: blocks 0..63 -> (ns -> mu), 64..127 -> (nt -> nu)
__global__ __launch_bounds__(256) void k_saliency2(const float* __restrict__ ns,
    const float* __restrict__ nt, float* __restrict__ omu, float* __restrict__ onu){
  int b0 = blockIdx.x, n = threadIdx.x;
  const float* nrm = (b0 < NB) ? ns : nt;
  float* out = (b0 < NB) ? omu : onu;
  int b = b0 & 63;
  float x = nrm[b*NN+n];
  float mx = wred_max(x);
  __shared__ float sm[4], sm2[4];
  if((n&63)==0) sm[n>>6]=mx;
  __syncthreads();
  mx = fmaxf(fmaxf(sm[0],sm[1]),fmaxf(sm[2],sm[3]));
  float e = expf(x-mx);
  float s = wred_sum(e);
  if((n&63)==0) sm2[n>>6]=s;
  __syncthreads();
  s = sm2[0]+sm2[1]+sm2[2]+sm2[3];
  out[b*NN+n] = e/s;
}

// ---------------- MFMA GEMM (NT form) ----------------
enum { MODE_PROJ=0, MODE_COST=1, MODE_PLAIN=2, MODE_STRUCT=3 };

// 128x128 tile (used for PROJ: grid 1024 blocks = 4 blocks/CU)
template<int MODE>
__global__ __launch_bounds__(256) void k_mfma(
    const u16* __restrict__ A, int lda, long bA,
    const u16* __restrict__ B, int ldb, long bB,
    int K,
    float* __restrict__ outF, u16* __restrict__ outB, int ldo, long bO,
    const float* __restrict__ nx, const float* __restrict__ ny,
    const float* __restrict__ bias,
    const float* __restrict__ Cs, const float* __restrict__ mu,
    float* __restrict__ accp)
{
  __shared__ u16 As[128*32];
  __shared__ u16 Bs[128*32];
  __shared__ float red[4];

  // XCD-aware bijective block swizzle (all grids have nwg % 8 == 0)
  int gx = gridDim.x, gy = gridDim.y;
  int flat = blockIdx.x + gx*(blockIdx.y + gy*blockIdx.z);
  int nwg  = gx*gy*gridDim.z;
  int cpx  = nwg >> 3;
  int lg   = (flat & 7)*cpx + (flat >> 3);
  int bx   = lg % gx;
  int rest = lg / gx;
  int by   = rest % gy;
  int b    = rest / gy;

  const u16* Ab = A + (size_t)b*bA;
  const u16* Bb = B + (size_t)b*bB;
  int tid = threadIdx.x;
  int lane = tid & 63, w = tid >> 6;
  int m0 = by*128, n0 = bx*128;
  int row_off = (w>>1)*64, col_off = (w&1)*64;
  int q = lane>>4, loc = lane&15;
  f32x4 acc[4][4] = {};

  const int srow = (lane >> 2);
  const int sslot = lane & 3;

  for(int k0=0;k0<K;k0+=32){
    #pragma unroll
    for(int h=0;h<2;h++){
      int row = h*64 + w*16 + srow;
      int ca  = (sslot ^ ((row>>1)&3))*8;            // inverse of read-side XOR
      u16* ldst = As + h*2048 + w*512 + lane*8;      // linear: row*32 + slot*8
      u16* ldstB= Bs + h*2048 + w*512 + lane*8;
      gl16(Ab + (size_t)(m0+row)*lda + k0 + ca, ldst);
      gl16(Bb + (size_t)(n0+row)*ldb + k0 + ca, ldstB);
    }
    __syncthreads();
    bf16x8 af[4], bfr[4];
    #pragma unroll
    for(int mi=0;mi<4;mi++){
      int r = row_off + mi*16 + loc;
      int slot = q ^ ((r>>1)&3);
      af[mi] = *(const bf16x8*)(As + r*32 + slot*8);
    }
    #pragma unroll
    for(int ni=0;ni<4;ni++){
      int r = col_off + ni*16 + loc;
      int slot = q ^ ((r>>1)&3);
      bfr[ni] = *(const bf16x8*)(Bs + r*32 + slot*8);
    }
    #pragma unroll
    for(int mi=0;mi<4;mi++)
      #pragma unroll
      for(int ni=0;ni<4;ni++)
        acc[mi][ni] = __builtin_amdgcn_mfma_f32_16x16x32_bf16(af[mi], bfr[ni], acc[mi][ni], 0,0,0);
    __syncthreads();
  }

  float* outFb = outF ? outF + (size_t)b*bO : nullptr;
  u16*   outBb = outB ? outB + (size_t)b*bO : nullptr;
  const float* nxb = nx ? nx + (size_t)b*NN : nullptr;
  const float* nyb = ny ? ny + (size_t)b*NN : nullptr;
  const float* Cb  = (MODE==MODE_STRUCT) ? Cs + (size_t)b*bO : nullptr;
  const float* mb  = (MODE==MODE_STRUCT) ? mu + (size_t)b*NN : nullptr;
  float lsum = 0.f;
  #pragma unroll
  for(int mi=0;mi<4;mi++){
    #pragma unroll
    for(int j=0;j<4;j++){
      int row = m0 + row_off + mi*16 + q*4 + j;
      float ir = 0.f, mr = 0.f;
      if(MODE==MODE_COST)   ir = 1.f/fmaxf(nxb[row],1e-12f);
      if(MODE==MODE_STRUCT) mr = mb[row];
      #pragma unroll
      for(int ni=0;ni<4;ni++){
        int col = n0 + col_off + ni*16 + loc;
        float v = acc[mi][ni][j];
        if(MODE==MODE_PROJ){
          v += bias[col];
          outBb[(size_t)row*ldo + col] = f2bf(v);
        } else if(MODE==MODE_COST){
          float ic = 1.f/fmaxf(nyb[col],1e-12f);
          v = 1.f - v*ir*ic;
          if(outFb) outFb[(size_t)row*ldo + col] = v;
          if(outBb) outBb[(size_t)row*ldo + col] = f2bf(v);
        } else if(MODE==MODE_PLAIN){
          outBb[(size_t)row*ldo + col] = f2bf(v);
        } else {
          float d = Cb[(size_t)row*ldo + col] - v;
          lsum += d*d*mr*mb[col];
        }
      }
    }
  }
  if(MODE==MODE_STRUCT){
    lsum = wred_sum(lsum);
    if(lane==0) red[w] = lsum;
    __syncthreads();
    if(tid==0) atomicAdd(accp+6, red[0]+red[1]+red[2]+red[3]);
  }
}

// 64x64 tile variant for the batched GEMMs (COST/PLAIN/STRUCT).
template<int MODE>
__global__ __launch_bounds__(256) void k_mfma64(
    const u16* __restrict__ A, int lda, long bA,
    const u16* __restrict__ B, int ldb, long bB,
    int K,
    float* __restrict__ outF, u16* __restrict__ outB, int ldo, long bO,
    const float* __restrict__ nx, const float* __restrict__ ny,
    const float* __restrict__ bias,
    const float* __restrict__ Cs, const float* __restrict__ mu,
    float* __restrict__ accp)
{
  __shared__ u16 As[64*32];
  __shared__ u16 Bs[64*32];
  __shared__ float red[4];

  int gx = gridDim.x, gy = gridDim.y;
  int flat = blockIdx.x + gx*(blockIdx.y + gy*blockIdx.z);
  int nwg  = gx*gy*gridDim.z;
  int cpx  = nwg >> 3;
  int lg   = (flat & 7)*cpx + (flat >> 3);
  int bx   = lg % gx;
  int rest = lg / gx;
  int by   = rest % gy;
  int b    = rest / gy;

  const u16* Ab = A + (size_t)b*bA;
  const u16* Bb = B + (size_t)b*bB;
  int tid = threadIdx.x;
  int lane = tid & 63, w = tid >> 6;
  int m0 = by*64, n0 = bx*64;
  int row_off = (w>>1)*32, col_off = (w&1)*32;
  int q = lane>>4, loc = lane&15;
  f32x4 acc[2][2] = {};

  const int srow = tid >> 2;     // 0..63
  const int sslot = tid & 3;

  for(int k0=0;k0<K;k0+=32){
    {
      int row = srow;
      int ca  = (sslot ^ ((row>>1)&3))*8;
      u16* la = As + w*512 + lane*8;   // == row*32 + slot*8 (linear)
      u16* lb = Bs + w*512 + lane*8;
      gl16(Ab + (size_t)(m0+row)*lda + k0 + ca, la);
      gl16(Bb + (size_t)(n0+row)*ldb + k0 + ca, lb);
    }
    __syncthreads();
    bf16x8 af[2], bfr[2];
    #pragma unroll
    for(int mi=0;mi<2;mi++){
      int r = row_off + mi*16 + loc;
      int slot = q ^ ((r>>1)&3);
      af[mi] = *(const bf16x8*)(As + r*32 + slot*8);
    }
    #pragma unroll
    for(int ni=0;ni<2;ni++){
      int r = col_off + ni*16 + loc;
      int slot = q ^ ((r>>1)&3);
      bfr[ni] = *(const bf16x8*)(Bs + r*32 + slot*8);
    }
    #pragma unroll
    for(int mi=0;mi<2;mi++)
      #pragma unroll
      for(int ni=0;ni<2;ni++)
        acc[mi][ni] = __builtin_amdgcn_mfma_f32_16x16x32_bf16(af[mi], bfr[ni], acc[mi][ni], 0,0,0);
    __syncthreads();
  }

  float* outFb = outF ? outF + (size_t)b*bO : nullptr;
  u16*   outBb = outB ? outB + (size_t)b*bO : nullptr;
  const float* nxb = nx ? nx + (size_t)b*NN : nullptr;
  const float* nyb = ny ? ny + (size_t)b*NN : nullptr;
  const float* Cb  = (MODE==MODE_STRUCT) ? Cs + (size_t)b*bO : nullptr;
  const float* mb  = (MODE==MODE_STRUCT) ? mu + (size_t)b*NN : nullptr;
  float lsum = 0.f;
  #pragma unroll
  for(int mi=0;mi<2;mi++){
    #pragma unroll
    for(int j=0;j<4;j++){
      int row = m0 + row_off + mi*16 + q*4 + j;
      float ir = 0.f, mr = 0.f;
      if(MODE==MODE_COST)   ir = 1.f/fmaxf(nxb[row],1e-12f);
      if(MODE==MODE_STRUCT) mr = mb[row];
      #pragma unroll
      for(int ni=0;ni<2;ni++){
        int col = n0 + col_off + ni*16 + loc;
        float v = acc[mi][ni][j];
        if(MODE==MODE_PROJ){
          v += bias[col];
          outBb[(size_t)row*ldo + col] = f2bf(v);
        } else if(MODE==MODE_COST){
          float ic = 1.f/fmaxf(nyb[col],1e-12f);
          v = 1.f - v*ir*ic;
          if(outFb) outFb[(size_t)row*ldo + col] = v;
          if(outBb) outBb[(size_t)row*ldo + col] = f2bf(v);
        } else if(MODE==MODE_PLAIN){
          outBb[(size_t)row*ldo + col] = f2bf(v);
        } else {
          float d = Cb[(size_t)row*ldo + col] - v;
          lsum += d*d*mr*mb[col];
        }
      }
    }
  }
  if(MODE==MODE_STRUCT){
    lsum = wred_sum(lsum);
    if(lane==0) red[w] = lsum;
    __syncthreads();
    if(tid==0) atomicAdd(accp+6, red[0]+red[1]+red[2]+red[3]);
  }
}

// Dual-output 64x64 COST GEMM: C_t (A1=ZT) and M (A2=ZSP) share B=ZT, K=1024.
// B staged once; 8 MFMA per barrier pair (2x the ratio of separate kernels).
// Per-output accumulation order identical to separate k_mfma64 -> bit-same.
__global__ __launch_bounds__(256) void k_mfma64_dual(
    const u16* __restrict__ A1, const u16* __restrict__ A2,
    const u16* __restrict__ B, int ld, long bStr,
    int K,
    u16* __restrict__ out1, u16* __restrict__ out2, long bO,
    const float* __restrict__ n1, const float* __restrict__ n2,
    const float* __restrict__ ny)
{
  __shared__ u16 A1s[64*32];
  __shared__ u16 A2s[64*32];
  __shared__ u16 Bs[64*32];

  int gx = gridDim.x, gy = gridDim.y;
  int flat = blockIdx.x + gx*(blockIdx.y + gy*blockIdx.z);
  int nwg  = gx*gy*gridDim.z;
  int cpx  = nwg >> 3;
  int lg   = (flat & 7)*cpx + (flat >> 3);
  int bx   = lg % gx;
  int rest = lg / gx;
  int by   = rest % gy;
  int b    = rest / gy;

  const u16* A1b = A1 + (size_t)b*bStr;
  const u16* A2b = A2 + (size_t)b*bStr;
  const u16* Bb  = B  + (size_t)b*bStr;
  int tid = threadIdx.x;
  int lane = tid & 63, w = tid >> 6;
  int m0 = by*64, n0 = bx*64;
  int row_off = (w>>1)*32, col_off = (w&1)*32;
  int q = lane>>4, loc = lane&15;
  f32x4 acc1[2][2] = {};
  f32x4 acc2[2][2] = {};

  const int srow = tid >> 2;     // 0..63
  const int sslot = tid & 3;

  for(int k0=0;k0<K;k0+=32){
    {
      int row = srow;
      int ca  = (sslot ^ ((row>>1)&3))*8;
      u16* l1 = A1s + w*512 + lane*8;
      u16* l2 = A2s + w*512 + lane*8;
      u16* lb = Bs  + w*512 + lane*8;
      gl16(A1b + (size_t)(m0+row)*ld + k0 + ca, l1);
      gl16(A2b + (size_t)(m0+row)*ld + k0 + ca, l2);
      gl16(Bb  + (size_t)(n0+row)*ld + k0 + ca, lb);
    }
    __syncthreads();
    bf16x8 a1f[2], a2f[2], bfr[2];
    #pragma unroll
    for(int mi=0;mi<2;mi++){
      int r = row_off + mi*16 + loc;
      int slot = q ^ ((r>>1)&3);
      a1f[mi] = *(const bf16x8*)(A1s + r*32 + slot*8);
      a2f[mi] = *(const bf16x8*)(A2s + r*32 + slot*8);
    }
    #pragma unroll
    for(int ni=0;ni<2;ni++){
      int r = col_off + ni*16 + loc;
      int slot = q ^ ((r>>1)&3);
      bfr[ni] = *(const bf16x8*)(Bs + r*32 + slot*8);
    }
    #pragma unroll
    for(int mi=0;mi<2;mi++)
      #pragma unroll
      for(int ni=0;ni<2;ni++){
        acc1[mi][ni] = __builtin_amdgcn_mfma_f32_16x16x32_bf16(a1f[mi], bfr[ni], acc1[mi][ni], 0,0,0);
        acc2[mi][ni] = __builtin_amdgcn_mfma_f32_16x16x32_bf16(a2f[mi], bfr[ni], acc2[mi][ni], 0,0,0);
      }
    __syncthreads();
  }

  u16* o1 = out1 + (size_t)b*bO;
  u16* o2 = out2 + (size_t)b*bO;
  const float* n1b = n1 + (size_t)b*NN;
  const float* n2b = n2 + (size_t)b*NN;
  const float* nyb = ny + (size_t)b*NN;
  #pragma unroll
  for(int mi=0;mi<2;mi++){
    #pragma unroll
    for(int j=0;j<4;j++){
      int row = m0 + row_off + mi*16 + q*4 + j;
      float ir1 = 1.f/fmaxf(n1b[row],1e-12f);
      float ir2 = 1.f/fmaxf(n2b[row],1e-12f);
      #pragma unroll
      for(int ni=0;ni<2;ni++){
        int col = n0 + col_off + ni*16 + loc;
        float ic = 1.f/fmaxf(nyb[col],1e-12f);
        float v1 = 1.f - acc1[mi][ni][j]*ir1*ic;
        float v2 = 1.f - acc2[mi][ni][j]*ir2*ic;
        o1[(size_t)row*NN + col] = f2bf(v1);
        o2[(size_t)row*NN + col] = f2bf(v2);
      }
    }
  }
}

// ---------------- fused Sinkhorn: multiplicative domain, K in LDS ----------------
// Measured-best 4-phase structure (R2/R5: ~60-64 us, 0 bank conflicts). DO NOT restructure:
// 2-phase(64), reg-K(90, spill), 3-phase(95, conflicts) all measured worse.
#define SINK_DYN_LDS 131072
__global__ __launch_bounds__(1024, 1) void k_sinkhorn_fused(
    const u16* __restrict__ Mbf, const float* __restrict__ muL,
    const float* __restrict__ nuL, u16* __restrict__ Gn, float* __restrict__ accp)
{
  extern __shared__ u16 Ks[];                      // 256x256 bf16, swizzled
  __shared__ __align__(16) float part[4096];       // reduction scratch
  __shared__ __align__(16) float su[NN], sv[NN], smu[NN], snu[NN];
  __shared__ float red[16];

  const int b = blockIdx.x;
  const int t = threadIdx.x;
  const u16* Mb = Mbf + (size_t)b*NN*NN;

  #pragma unroll
  for(int i=0;i<16;i++){
    int e = (i*1024 + t)*4;
    int r = e>>8, c = e&255;
    ushort4 mv = *(const ushort4*)(Mb + e);
    ushort4 o;
    o.x = f2bf(exp2f(-C2LOG*bf2f(mv.x)));
    o.y = f2bf(exp2f(-C2LOG*bf2f(mv.y)));
    o.z = f2bf(exp2f(-C2LOG*bf2f(mv.z)));
    o.w = f2bf(exp2f(-C2LOG*bf2f(mv.w)));
    *(ushort4*)(Ks + LIDX(r,c)) = o;
  }
  if(t < NN){
    smu[t] = muL[(size_t)b*NN+t] + 1e-8f;
    snu[t] = nuL[(size_t)b*NN+t] + 1e-8f;
    sv[t] = 1.f;
  }
  __syncthreads();

  const int r_ = t & 255, p_ = t >> 8;
  const int w = t>>6, l = t&63;

  for(int it=0; it<20; it++){
    {
      float s0=0.f, s1=0.f, s2=0.f, s3=0.f;
      #pragma unroll
      for(int jj=0;jj<8;jj++){
        int c0 = p_*64 + jj*8;
        uint4 kv = *(const uint4*)(Ks + LIDX(r_, c0));
        float4 va = *(const float4*)(sv + c0);
        float4 vb = *(const float4*)(sv + c0 + 4);
        s0 = fmaf(__uint_as_float(kv.x<<16),           va.x, s0);
        s1 = fmaf(__uint_as_float(kv.x & 0xffff0000u), va.y, s1);
        s2 = fmaf(__uint_as_float(kv.y<<16),           va.z, s2);
        s3 = fmaf(__uint_as_float(kv.y & 0xffff0000u), va.w, s3);
        s0 = fmaf(__uint_as_float(kv.z<<16),           vb.x, s0);
        s1 = fmaf(__uint_as_float(kv.z & 0xffff0000u), vb.y, s1);
        s2 = fmaf(__uint_as_float(kv.w<<16),           vb.z, s2);
        s3 = fmaf(__uint_as_float(kv.w & 0xffff0000u), vb.w, s3);
      }
      part[t] = (s0+s1)+(s2+s3);
    }
    __syncthreads();
    if(t < NN){
      float S = part[t] + part[256+t] + part[512+t] + part[768+t];
      su[t] = smu[t] / S;
    }
    __syncthreads();
    {
      float cs0=0.f,cs1=0.f,cs2=0.f,cs3=0.f;
      #pragma unroll
      for(int rr=0;rr<16;rr++){
        int r = w*16 + rr;
        ushort4 kv = *(const ushort4*)(Ks + LIDX(r, l*4));
        float ur = su[r];
        cs0 = fmaf(bf2f(kv.x), ur, cs0);
        cs1 = fmaf(bf2f(kv.y), ur, cs1);
        cs2 = fmaf(bf2f(kv.z), ur, cs2);
        cs3 = fmaf(bf2f(kv.w), ur, cs3);
      }
      float4 o; o.x=cs0; o.y=cs1; o.z=cs2; o.w=cs3;
      *(float4*)(part + w*256 + l*4) = o;
    }
    __syncthreads();
    if(t < NN){
      float S = 0.f;
      #pragma unroll
      for(int ww=0;ww<16;ww++) S += part[ww*256 + t];
      sv[t] = snu[t] / S;
    }
    __syncthreads();
  }

  {
    float s0=0.f, s1=0.f, s2=0.f, s3=0.f;
    #pragma unroll
    for(int jj=0;jj<8;jj++){
      int c0 = p_*64 + jj*8;
      uint4 kv = *(const uint4*)(Ks + LIDX(r_, c0));
      float4 va = *(const float4*)(sv + c0);
      float4 vb = *(const float4*)(sv + c0 + 4);
      s0 = fmaf(__uint_as_float(kv.x<<16),           va.x, s0);
      s1 = fmaf(__uint_as_float(kv.x & 0xffff0000u), va.y, s1);
      s2 = fmaf(__uint_as_float(kv.y<<16),           va.z, s2);
      s3 = fmaf(__uint_as_float(kv.y & 0xffff0000u), va.w, s3);
      s0 = fmaf(__uint_as_float(kv.z<<16),           vb.x, s0);
      s1 = fmaf(__uint_as_float(kv.z & 0xffff0000u), vb.y, s1);
      s2 = fmaf(__uint_as_float(kv.w<<16),           vb.z, s2);
      s3 = fmaf(__uint_as_float(kv.w & 0xffff0000u), vb.w, s3);
    }
    part[t] = (s0+s1)+(s2+s3);
  }
  __syncthreads();
  if(t < NN){
    float S = part[t] + part[256+t] + part[512+t] + part[768+t];
    smu[t] = 1.f / (su[t]*S + 1e-8f);
  }
  __syncthreads();

  u16* Gb = Gn + (size_t)b*NN*NN;
  const float IC = -1.f/C2LOG;
  float v0 = sv[l*4+0], v1 = sv[l*4+1], v2 = sv[l*4+2], v3 = sv[l*4+3];
  float fl = 0.f;
  for(int rr=0;rr<16;rr++){
    int r = w*16 + rr;
    ushort4 kv = *(const ushort4*)(Ks + LIDX(r, l*4));
    float k0=bf2f(kv.x), k1=bf2f(kv.y), k2=bf2f(kv.z), k3=bf2f(kv.w);
    float ur = su[r], inv = smu[r];
    float g0=ur*k0*v0, g1=ur*k1*v1, g2=ur*k2*v2, g3=ur*k3*v3;
    fl += g0*(__log2f(k0)*IC) + g1*(__log2f(k1)*IC)
        + g2*(__log2f(k2)*IC) + g3*(__log2f(k3)*IC);
    ushort4 o;
    o.x=f2bf(g0*inv); o.y=f2bf(g1*inv); o.z=f2bf(g2*inv); o.w=f2bf(g3*inv);
    *(ushort4*)(Gb + (size_t)r*NN + l*4) = o;
  }
  fl = wred_sum(fl);
  if(l==0) red[w] = fl;
  __syncthreads();
  if(t==0){
    float s=0.f;
    #pragma unroll
    for(int i=0;i<16;i++) s+=red[i];
    atomicAdd(accp+5, s);
  }
}

__global__ void k_final(const float* __restrict__ acc, float* __restrict__ out){
  out[0] = acc[0]
         + 20.f*acc[3]*(1.f/8128.f)
         + 40.f*acc[4]*(1.f/2048256.f)
         + 0.25f*(acc[5]+acc[6])*(1.f/64.f);
}

// ---------------- host ----------------
extern "C" void kernel_launch(void* const* d_in, const int* in_sizes, int n_in,
                              void* d_out, int out_size, void* d_ws, size_t ws_size,
                              hipStream_t stream) {
  const float* s_q_reps   = (const float*)d_in[0];
  const float* s_p_reps   = (const float*)d_in[1];
  const float* t_q_reps   = (const float*)d_in[2];
  const float* t_p_reps   = (const float*)d_in[3];
  const float* s_q_states = (const float*)d_in[4];
  const float* s_p_states = (const float*)d_in[5];
  const float* t_q_states = (const float*)d_in[6];
  const float* t_p_states = (const float*)d_in[7];
  const float* proj_w     = (const float*)d_in[8];
  const float* proj_b     = (const float*)d_in[9];
  float* ws = (float*)d_ws;
  float* acc = ws + OFF_ACC;
  u16* M_BF   = (u16*)(ws + OFF_MBF);
  u16* ZS_BF  = (u16*)(ws + OFF_ZS_BF);
  u16* ZT_BF  = (u16*)(ws + OFF_ZT_BF);
  u16* WT_BF  = (u16*)(ws + OFF_WT_BF);
  u16* ZSP_BF = (u16*)(ws + OFF_ZSP_BF);
  u16* GN_BF  = (u16*)(ws + OFF_GN_BF);
  u16* CT_BF  = (u16*)(ws + OFF_CT_BF);
  u16* T_BF   = (u16*)(ws + OFF_T_BF);

  hipFuncSetAttribute(reinterpret_cast<const void*>(k_sinkhorn_fused),
                      hipFuncAttributeMaxDynamicSharedMemorySize, SINK_DYN_LDS);
  hipFuncSetAttribute(reinterpret_cast<const void*>(k_rkd_angle_mfma),
                      hipFuncAttributeMaxDynamicSharedMemorySize, RKD_LDS);

  hipMemsetAsync(acc, 0, 16*sizeof(float), stream);

  // ---- Part A ----
  k_l2norm_all<<<384,256,0,stream>>>(s_q_reps, s_p_reps, t_q_reps, t_p_reps, ws);
  k_contrastive2<<<128,512,0,stream>>>(ws, acc);

  // pass-0 cvt (zs,zt) + gram packed into one launch
  k_pack_cvt<<<8320,256,0,stream>>>(s_q_states, t_q_states, ZS_BF, ZT_BF,
      ws+OFF_NS, ws+OFF_NT, ws+OFF_SQ128, ws+OFF_TQ128, ws+OFF_DS, ws+OFF_DT, acc);
  // rkd_dist + saliency(pass0) packed
  k_small0<<<256,256,0,stream>>>(ws+OFF_DS, ws+OFF_DT, ws+OFF_NS, ws+OFF_NT,
      ws+OFF_MU, ws+OFF_NU, acc);
  k_rkd_angle_mfma<<<256,256,RKD_LDS,stream>>>(ws+OFF_SQ128, ws+OFF_TQ128, acc);
  k_wt<<<dim3(HTT/32, HSS/32),dim3(32,8),0,stream>>>(proj_w, WT_BF);

  // ---- Part B phase 1 ----
  for(int pass=0; pass<2; pass++){
    size_t po  = (size_t)pass*NB*NN*NN;
    size_t pr  = (size_t)pass*ROWS;
    if(pass==1){
      k_pack_cvt<<<8192,256,0,stream>>>(s_p_states, t_p_states, ZS_BF, ZT_BF,
          ws+OFF_NS, ws+OFF_NT, ws+OFF_SQ128, ws+OFF_TQ128, ws+OFF_DS, ws+OFF_DT, acc);
      k_saliency2<<<128,256,0,stream>>>(ws+OFF_NS, ws+OFF_NT, ws+OFF_MU+pr, ws+OFF_NU+pr);
    }
    k_mfma<MODE_PROJ><<<dim3(HTT/128, ROWS/128, 1),256,0,stream>>>(
        ZS_BF, HSS, 0, WT_BF, HSS, 0, HSS,
        nullptr, ZSP_BF, HTT, 0,
        nullptr, nullptr, proj_b, nullptr, nullptr, nullptr);
    k_row_norm_bf16<<<ROWS/4,256,0,stream>>>(ZSP_BF, ws+OFF_NSP, HTT);
    // C_s (f32) — 64² tiles, 1024 blocks
    k_mfma64<MODE_COST><<<dim3(4,4,NB),256,0,stream>>>(
        ZS_BF, HSS, (long)NN*HSS, ZS_BF, HSS, (long)NN*HSS, HSS,
        ws+OFF_CS+po, nullptr, NN, (long)NN*NN,
        ws+OFF_NS, ws+OFF_NS, nullptr, nullptr, nullptr, nullptr);
    // C_t + M fused (shared B=ZT, K=1024): bit-identical to separate kernels
    k_mfma64_dual<<<dim3(4,4,NB),256,0,stream>>>(
        ZT_BF, ZSP_BF, ZT_BF, HTT, (long)NN*HTT, HTT,
        CT_BF+po, M_BF+po, (long)NN*NN,
        ws+OFF_NT, ws+OFF_NSP, ws+OFF_NT);
  }

  // ---- Part B phase 2: Sinkhorn (both passes, multiplicative, K in LDS) ----
  k_sinkhorn_fused<<<2*NB,1024,SINK_DYN_LDS,stream>>>(
      M_BF, ws+OFF_MU, ws+OFF_NU, GN_BF, acc);

  // ---- Part B phase 3: T = Gn@Ct, struct loss (batched, 64² tiles) ----
  k_mfma64<MODE_PLAIN><<<dim3(4,4,2*NB),256,0,stream>>>(
      GN_BF, NN, (long)NN*NN, CT_BF, NN, (long)NN*NN, NN,
      nullptr, T_BF, NN, (long)NN*NN,
      nullptr, nullptr, nullptr, nullptr, nullptr, nullptr);
  k_mfma64<MODE_STRUCT><<<dim3(4,4,2*NB),256,0,stream>>>(
      T_BF, NN, (long)NN*NN, GN_BF, NN, (long)NN*NN, NN,
      nullptr, nullptr, NN, (long)NN*NN,
      nullptr, nullptr, nullptr, ws+OFF_CS, ws+OFF_MU, acc);

  k_final<<<1,1,0,stream>>>(acc, (float*)d_out);
}

// Round 9
// 590.328 us; speedup vs baseline: 1.1635x; 1.0216x over previous
//
#include <hip/hip_runtime.h>
#include <math.h>

// Problem dims
#define NB   64      // batch B
#define NN   256     // tokens N
#define HSS  768     // H_S
#define HTT  1024    // H_T
#define ROWS (NB*NN) // 16384
#define C2LOG 14.426950408889634f  // 10 * log2(e)

typedef unsigned short u16;
typedef __attribute__((ext_vector_type(8))) short bf16x8;
typedef __attribute__((ext_vector_type(4))) float f32x4;

// swizzled LDS index for K[r][c] (256 cols): chunk rotation, 8-u16 granularity
#define LIDX(r,c) (((r)<<8) + (((((c)>>3) + (r)) & 31)<<3) + ((c)&7))
// swizzled LDS index for E[r][c] (128 cols, 16 chunks of 8)
#define EIDX(r,c) (((r)<<7) + (((((c)>>3) + (r)) & 15)<<3) + ((c)&7))

// async global->LDS, 16B per lane (gfx950)
__device__ __forceinline__ void gl16(const u16* g, u16* l){
  __builtin_amdgcn_global_load_lds(
      (const __attribute__((address_space(1))) unsigned int*)g,
      (__attribute__((address_space(3))) unsigned int*)l,
      16, 0, 0);
}

// ---------------- workspace layout (float offsets) ----------------
static const size_t OFF_ACC   = 0;                          // 16 floats
static const size_t OFF_SQ128 = 16;
static const size_t OFF_SP128 = OFF_SQ128 + 64*128;
static const size_t OFF_TQ128 = OFF_SP128 + 64*128;
static const size_t OFF_TP128 = OFF_TQ128 + 64*128;
static const size_t OFF_SQ768 = OFF_TP128 + 64*128;
static const size_t OFF_SP768 = OFF_SQ768 + 64*768;
static const size_t OFF_DS    = OFF_SP768 + 64*768;         // 128*128
static const size_t OFF_DT    = OFF_DS + 128*128;
static const size_t OFF_CS    = OFF_DT + 128*128;           // 2*B*N*N f32
static const size_t OFF_MBF   = OFF_CS  + (size_t)2*NB*NN*NN;     // 2*B*N*N bf16
static const size_t OFF_ZS_BF = OFF_MBF + (size_t)NB*NN*NN;       // 16384x768 bf16
static const size_t OFF_ZT_BF = OFF_ZS_BF + (size_t)ROWS*HSS/2;   // 16384x1024 bf16
static const size_t OFF_WT_BF = OFF_ZT_BF + (size_t)ROWS*HTT/2;   // 1024x768 bf16
static const size_t OFF_ZSP_BF= OFF_WT_BF + (size_t)HTT*HSS/2;    // 16384x1024 bf16
static const size_t OFF_GN_BF = OFF_ZSP_BF+ (size_t)ROWS*HTT/2;   // 2*B*N*N bf16
static const size_t OFF_CT_BF = OFF_GN_BF + (size_t)NB*NN*NN;     // 2*B*N*N bf16
static const size_t OFF_T_BF  = OFF_ZS_BF;                  // ALIAS: ZS dead after cost GEMMs
static const size_t OFF_NS    = OFF_CT_BF + (size_t)NB*NN*NN;
static const size_t OFF_NT    = OFF_NS + ROWS;
static const size_t OFF_MU    = OFF_NT + ROWS;              // 2*ROWS (linear)
static const size_t OFF_NU    = OFF_MU + 2*ROWS;            // 2*ROWS (linear)
static const size_t OFF_NSPP  = OFF_NU + 2*ROWS;            // 16*ROWS f32: ZSP row-ssq partials

// acc: 0=contrastive 1=ds_sum 2=dt_sum 3=dist_huber 4=angle_huber 5=feat 6=struct

// ---------------- helpers ----------------
__device__ __forceinline__ float wred_sum(float v){
  #pragma unroll
  for(int o=32;o>0;o>>=1) v += __shfl_xor(v,o,64);
  return v;
}
__device__ __forceinline__ float wred_max(float v){
  #pragma unroll
  for(int o=32;o>0;o>>=1) v = fmaxf(v, __shfl_xor(v,o,64));
  return v;
}
__device__ __forceinline__ u16 f2bf(float f){
  unsigned u = __float_as_uint(f);
  unsigned r = (u + 0x7fffu + ((u>>16)&1u)) >> 16;
  return (u16)r;
}
__device__ __forceinline__ float bf2f(u16 h){
  return __uint_as_float(((unsigned)h)<<16);
}

// ---------------- Part A kernels ----------------
__global__ __launch_bounds__(256) void k_l2norm_all(
    const float* __restrict__ sq, const float* __restrict__ sp,
    const float* __restrict__ tq, const float* __restrict__ tp,
    float* __restrict__ ws){
  int bid = blockIdx.x;
  int r = bid & 63;
  const float* in; float* out; int kuse;
  if(bid < 64)       { in = sq; out = ws + OFF_SQ128; kuse = 128; }
  else if(bid < 128) { in = sp; out = ws + OFF_SP128; kuse = 128; }
  else if(bid < 192) { in = tq; out = ws + OFF_TQ128; kuse = 128; }
  else if(bid < 256) { in = tp; out = ws + OFF_TP128; kuse = 128; }
  else if(bid < 320) { in = sq; out = ws + OFF_SQ768; kuse = 768; }
  else               { in = sp; out = ws + OFF_SP768; kuse = 768; }
  const float* row = in + (size_t)r*768;
  float ss = 0.f;
  for(int d=threadIdx.x; d<kuse; d+=256){ float x=row[d]; ss += x*x; }
  ss = wred_sum(ss);
  __shared__ float sm[4];
  if((threadIdx.x&63)==0) sm[threadIdx.x>>6]=ss;
  __syncthreads();
  float tot = sm[0]+sm[1]+sm[2]+sm[3];
  float inv = 1.f / fmaxf(sqrtf(tot), 1e-12f);
  for(int d=threadIdx.x; d<kuse; d+=256) out[(size_t)r*kuse + d] = row[d]*inv;
}

__global__ __launch_bounds__(512) void k_contrastive2(const float* __restrict__ ws,
    float* __restrict__ acc){
  int bid = blockIdx.x;
  int i = bid & 63;
  int big = bid >> 6;
  const float* q = ws + (big ? OFF_SQ768 : OFF_SQ128);
  const float* p = ws + (big ? OFF_SP768 : OFF_SP128);
  int dim = big ? 768 : 128;
  float weight = big ? 2.f : 1.f;
  int j = threadIdx.x & 63;
  int part = threadIdx.x >> 6;           // 0..7
  const float* qi = q + (size_t)i*dim;
  const float* pj = p + (size_t)j*dim;
  int seg = dim >> 3;
  int d0 = part*seg;
  float dot = 0.f;
  for(int d=d0; d<d0+seg; d+=4){
    float4 a = *(const float4*)(qi+d);
    float4 b = *(const float4*)(pj+d);
    dot = fmaf(a.x,b.x,dot);
    dot = fmaf(a.y,b.y,dot);
    dot = fmaf(a.z,b.z,dot);
    dot = fmaf(a.w,b.w,dot);
  }
  __shared__ float sm[8][64];
  sm[part][j] = dot;
  __syncthreads();
  if(part==0){
    float s = 0.f;
    #pragma unroll
    for(int k=0;k<8;k++) s += sm[k][j];
    s = s / 0.07f;
    float mx = wred_max(s);
    float e = expf(s - mx);
    float Z = wred_sum(e);
    float logZ = mx + logf(Z);
    float diag = __shfl(s, i, 64);
    if(j==0) atomicAdd(acc+0, weight*(logZ - diag)*(1.f/64.f));
  }
}

// ---- packed cvt+gram: blocks [0,4096) cvt zs, [4096,8192) cvt zt,
// [8192,8320) gram_ds (pass-0 only; pass-1 launches with grid 8192).
__global__ __launch_bounds__(256) void k_pack_cvt(
    const float* __restrict__ zs, const float* __restrict__ zt,
    u16* __restrict__ zsb, u16* __restrict__ ztb,
    float* __restrict__ ns, float* __restrict__ nt,
    const float* __restrict__ sb128, const float* __restrict__ tb128,
    float* __restrict__ ds, float* __restrict__ dt, float* __restrict__ acc)
{
  __shared__ float sm[2][2];
  int bid = blockIdx.x;
  if(bid < 8192){
    const float* in; u16* out; float* nrm; int K; int cb;
    if(bid < 4096){ in=zs; out=zsb; nrm=ns; K=HSS; cb=bid; }
    else          { in=zt; out=ztb; nrm=nt; K=HTT; cb=bid-4096; }
    int w = threadIdx.x >> 6, l = threadIdx.x & 63;
    int r = cb*4 + w;
    const float* row = in + (size_t)r*K;
    u16* orow = out + (size_t)r*K;
    float ss = 0.f;
    int nv = K >> 8;
    for(int i=0;i<nv;i++){
      int d = l*4 + i*256;
      float4 x = *(const float4*)(row + d);
      ushort4 o; o.x=f2bf(x.x); o.y=f2bf(x.y); o.z=f2bf(x.z); o.w=f2bf(x.w);
      *(ushort4*)(orow + d) = o;
      ss += x.x*x.x + x.y*x.y + x.z*x.z + x.w*x.w;
    }
    ss = wred_sum(ss);
    if(l==0) nrm[r] = sqrtf(ss);
    return;
  }
  // gram_ds branch
  {
    int r = bid - 8192;
    int c = threadIdx.x;
    float ms = 0.f, mt = 0.f;
    if(c < 128){
      const float* sr = sb128 + r*128; const float* sc = sb128 + c*128;
      const float* tr = tb128 + r*128; const float* tc = tb128 + c*128;
      float dot_s=0,ssr=0,ssc=0,dot_t=0,tsr=0,tsc=0;
      for(int d=0; d<128; d++){
        float a=sr[d], bb=sc[d]; dot_s += a*bb; ssr += a*a; ssc += bb*bb;
        float at=tr[d], bt=tc[d]; dot_t += at*bt; tsr += at*at; tsc += bt*bt;
      }
      float dv = ssr + ssc - 2.f*dot_s;
      float tv = tsr + tsc - 2.f*dot_t;
      ds[r*128+c] = dv; dt[r*128+c] = tv;
      ms = (c>r)? dv : 0.f;
      mt = (c>r)? tv : 0.f;
      ms = wred_sum(ms); mt = wred_sum(mt);
      if((c&63)==0){ sm[0][c>>6]=ms; sm[1][c>>6]=mt; }
    }
    __syncthreads();
    if(threadIdx.x==0){
      atomicAdd(acc+1, sm[0][0]+sm[0][1]);
      atomicAdd(acc+2, sm[1][0]+sm[1][1]);
    }
  }
}

// packed small kernels (pass 0): blocks [0,128) rkd_dist, [128,256) saliency
__global__ __launch_bounds__(256) void k_small0(
    const float* __restrict__ ds, const float* __restrict__ dt,
    const float* __restrict__ ns, const float* __restrict__ nt,
    float* __restrict__ omu, float* __restrict__ onu, float* __restrict__ acc)
{
  __shared__ float sm[4], sm2[4];
  int bid = blockIdx.x;
  if(bid < 128){
    int r = bid, c = threadIdx.x;
    float mean_s = acc[1]*(1.f/8128.f) + 1e-8f;
    float mean_t = acc[2]*(1.f/8128.f) + 1e-8f;
    float h = 0.f;
    if(c < 128){
      if(c > r){
        float diff = ds[r*128+c]/mean_s - dt[r*128+c]/mean_t;
        float a = fabsf(diff);
        h = (a<1.f)? 0.5f*a*a : a-0.5f;
      }
      h = wred_sum(h);
      if((c&63)==0) sm[c>>6]=h;
    }
    __syncthreads();
    if(threadIdx.x==0) atomicAdd(acc+3, sm[0]+sm[1]);
    return;
  }
  // saliency branch
  {
    int b0 = bid - 128, n = threadIdx.x;
    const float* nrm = (b0 < NB) ? ns : nt;
    float* out = (b0 < NB) ? omu : onu;
    int b = b0 & 63;
    float x = nrm[b*NN+n];
    float mx = wred_max(x);
    if((n&63)==0) sm[n>>6]=mx;
    __syncthreads();
    mx = fmaxf(fmaxf(sm[0],sm[1]),fmaxf(sm[2],sm[3]));
    float e = expf(x-mx);
    float s = wred_sum(e);
    if((n&63)==0) sm2[n>>6]=s;
    __syncthreads();
    s = sm2[0]+sm2[1]+sm2[2]+sm2[3];
    out[b*NN+n] = e/s;
  }
}

// ---- RKD angle via MFMA: psi = E E^T, E in bf16 LDS, huber fused ----
#define RKD_LDS 65536
__global__ __launch_bounds__(256, 1) void k_rkd_angle_mfma(
    const float* __restrict__ sb, const float* __restrict__ tb,
    float* __restrict__ accp)
{
  extern __shared__ u16 eSh[];
  u16* Es = eSh;
  u16* Et = eSh + 128*128;
  const int j    = blockIdx.x >> 1;
  const int half = blockIdx.x & 1;
  const int tid = threadIdx.x;
  {
    const int i = tid >> 1, h = tid & 1;
    #pragma unroll
    for(int which=0; which<2; which++){
      const float* xb = which ? tb : sb;
      u16* E = which ? Et : Es;
      const float* xj = xb + j*128 + h*64;
      const float* xi = xb + i*128 + h*64;
      float ss = 0.f;
      #pragma unroll
      for(int d4=0; d4<16; d4++){
        float4 a = *(const float4*)(xj + d4*4);
        float4 b = *(const float4*)(xi + d4*4);
        float d0=a.x-b.x, d1=a.y-b.y, d2=a.z-b.z, d3=a.w-b.w;
        ss += d0*d0+d1*d1+d2*d2+d3*d3;
      }
      ss += __shfl_xor(ss, 1, 64);
      float inv = (i==j) ? 0.f : 1.f/(sqrtf(ss)+1e-8f);
      #pragma unroll
      for(int d4=0; d4<16; d4++){
        float4 a = *(const float4*)(xj + d4*4);
        float4 b = *(const float4*)(xi + d4*4);
        int c = h*64 + d4*4;
        E[EIDX(i,c+0)] = f2bf((a.x-b.x)*inv);
        E[EIDX(i,c+1)] = f2bf((a.y-b.y)*inv);
        E[EIDX(i,c+2)] = f2bf((a.z-b.z)*inv);
        E[EIDX(i,c+3)] = f2bf((a.w-b.w)*inv);
      }
    }
  }
  __syncthreads();
  const int w = tid >> 6, lane = tid & 63;
  const int q = lane >> 4, loc = lane & 15;
  float hsum = 0.f;
  #pragma unroll
  for(int ni=0; ni<4; ni++){
    const int cb = half*64 + ni*16;
    #pragma unroll
    for(int mi=0; mi<2; mi++){
      const int rb = w*32 + mi*16;
      f32x4 as_ = {0.f,0.f,0.f,0.f}, at_ = {0.f,0.f,0.f,0.f};
      #pragma unroll
      for(int k0=0; k0<128; k0+=32){
        int ra = rb + loc, rbn = cb + loc;
        int ca = k0 + q*8;
        bf16x8 aS = *(const bf16x8*)(Es + EIDX(ra, ca));
        bf16x8 bS = *(const bf16x8*)(Es + EIDX(rbn, ca));
        bf16x8 aT = *(const bf16x8*)(Et + EIDX(ra, ca));
        bf16x8 bT = *(const bf16x8*)(Et + EIDX(rbn, ca));
        as_ = __builtin_amdgcn_mfma_f32_16x16x32_bf16(aS, bS, as_, 0,0,0);
        at_ = __builtin_amdgcn_mfma_f32_16x16x32_bf16(aT, bT, at_, 0,0,0);
      }
      #pragma unroll
      for(int jj=0; jj<4; jj++){
        int row = rb + q*4 + jj, col = cb + loc;
        if(row != col){
          float d = as_[jj] - at_[jj];
          float a = fabsf(d);
          hsum += (a < 1.f) ? 0.5f*a*a : a - 0.5f;
        }
      }
    }
  }
  hsum = wred_sum(hsum);
  __syncthreads();
  float* red = (float*)eSh;
  if(lane==0) red[w] = hsum;
  __syncthreads();
  if(tid==0) atomicAdd(accp+4, red[0]+red[1]+red[2]+red[3]);
}

// W (HSS x HTT) f32 -> Wt (HTT x HSS) bf16
__global__ void k_wt(const float* __restrict__ W, u16* __restrict__ Wt){
  __shared__ float t[32][33];
  int k0 = blockIdx.y*32, n0 = blockIdx.x*32;
  int tx = threadIdx.x, ty = threadIdx.y;
  for(int r=0;r<32;r+=8) t[ty+r][tx] = W[(size_t)(k0+ty+r)*HTT + n0+tx];
  __syncthreads();
  for(int r=0;r<32;r+=8) Wt[(size_t)(n0+ty+r)*HSS + k0+tx] = f2bf(t[tx][ty+r]);
}

// fused saliency: blocks 0..63 -> (ns -> mu), 64..127 -> (nt -> nu)
__global__ __launch_bounds__(256) void k_saliency2(const float* __restrict__ ns,
    const float* __restrict__ nt, float* __restrict__ omu, float* __restrict__ onu){
  int b0 = blockIdx.x, n = threadIdx.x;
  const float* nrm = (b0 < NB) ? ns : nt;
  float* out = (b0 < NB) ? omu : onu;
  int b = b0 & 63;
  float x = nrm[b*NN+n];
  float mx = wred_max(x);
  __shared__ float sm[4], sm2[4];
  if((n&63)==0) sm[n>>6]=mx;
  __syncthreads();
  mx = fmaxf(fmaxf(sm[0],sm[1]),fmaxf(sm[2],sm[3]));
  float e = expf(x-mx);
  float s = wred_sum(e);
  if((n&63)==0) sm2[n>>6]=s;
  __syncthreads();
  s = sm2[0]+sm2[1]+sm2[2]+sm2[3];
  out[b*NN+n] = e/s;
}

// ---------------- PROJ GEMM (128x128 tile) with fused row-ssq partials ----------------
// nspp layout: [16][ROWS] f32, slice = bx*2 + (w&1). dual sums 16 slices + sqrt.
__global__ __launch_bounds__(256) void k_proj(
    const u16* __restrict__ A, const u16* __restrict__ B,
    u16* __restrict__ outB, const float* __restrict__ bias,
    float* __restrict__ nspp)
{
  __shared__ u16 As[128*32];
  __shared__ u16 Bs[128*32];

  int gx = gridDim.x, gy = gridDim.y;
  int flat = blockIdx.x + gx*blockIdx.y;
  int nwg  = gx*gy;
  int cpx  = nwg >> 3;
  int lg   = (flat & 7)*cpx + (flat >> 3);
  int bx   = lg % gx;
  int by   = lg / gx;

  int tid = threadIdx.x;
  int lane = tid & 63, w = tid >> 6;
  int m0 = by*128, n0 = bx*128;
  int row_off = (w>>1)*64, col_off = (w&1)*64;
  int q = lane>>4, loc = lane&15;
  f32x4 acc[4][4] = {};

  const int srow = (lane >> 2);
  const int sslot = lane & 3;

  for(int k0=0;k0<HSS;k0+=32){
    #pragma unroll
    for(int h=0;h<2;h++){
      int row = h*64 + w*16 + srow;
      int ca  = (sslot ^ ((row>>1)&3))*8;
      u16* ldst = As + h*2048 + w*512 + lane*8;
      u16* ldstB= Bs + h*2048 + w*512 + lane*8;
      gl16(A + (size_t)(m0+row)*HSS + k0 + ca, ldst);
      gl16(B + (size_t)(n0+row)*HSS + k0 + ca, ldstB);
    }
    __syncthreads();
    bf16x8 af[4], bfr[4];
    #pragma unroll
    for(int mi=0;mi<4;mi++){
      int r = row_off + mi*16 + loc;
      int slot = q ^ ((r>>1)&3);
      af[mi] = *(const bf16x8*)(As + r*32 + slot*8);
    }
    #pragma unroll
    for(int ni=0;ni<4;ni++){
      int r = col_off + ni*16 + loc;
      int slot = q ^ ((r>>1)&3);
      bfr[ni] = *(const bf16x8*)(Bs + r*32 + slot*8);
    }
    #pragma unroll
    for(int mi=0;mi<4;mi++)
      #pragma unroll
      for(int ni=0;ni<4;ni++)
        acc[mi][ni] = __builtin_amdgcn_mfma_f32_16x16x32_bf16(af[mi], bfr[ni], acc[mi][ni], 0,0,0);
    __syncthreads();
  }

  int slice = bx*2 + (w&1);
  #pragma unroll
  for(int mi=0;mi<4;mi++){
    #pragma unroll
    for(int j=0;j<4;j++){
      int row = m0 + row_off + mi*16 + q*4 + j;
      float sq = 0.f;
      #pragma unroll
      for(int ni=0;ni<4;ni++){
        int col = n0 + col_off + ni*16 + loc;
        float v = acc[mi][ni][j] + bias[col];
        u16 h = f2bf(v);
        outB[(size_t)row*HTT + col] = h;
        float vq = bf2f(h);
        sq = fmaf(vq, vq, sq);
      }
      sq += __shfl_xor(sq, 1, 64);
      sq += __shfl_xor(sq, 2, 64);
      sq += __shfl_xor(sq, 4, 64);
      sq += __shfl_xor(sq, 8, 64);
      if(loc==0) nspp[(size_t)slice*ROWS + row] = sq;
    }
  }
}

// ---------------- 64x64 batched GEMM (COST / PLAIN / STRUCT) ----------------
enum { MODE_PROJ=0, MODE_COST=1, MODE_PLAIN=2, MODE_STRUCT=3 };

template<int MODE>
__global__ __launch_bounds__(256) void k_mfma64(
    const u16* __restrict__ A, int lda, long bA,
    const u16* __restrict__ B, int ldb, long bB,
    int K,
    float* __restrict__ outF, u16* __restrict__ outB, int ldo, long bO,
    const float* __restrict__ nx, const float* __restrict__ ny,
    const float* __restrict__ bias,
    const float* __restrict__ Cs, const float* __restrict__ mu,
    float* __restrict__ accp)
{
  __shared__ u16 As[64*32];
  __shared__ u16 Bs[64*32];
  __shared__ float red[4];

  int gx = gridDim.x, gy = gridDim.y;
  int flat = blockIdx.x + gx*(blockIdx.y + gy*blockIdx.z);
  int nwg  = gx*gy*gridDim.z;
  int cpx  = nwg >> 3;
  int lg   = (flat & 7)*cpx + (flat >> 3);
  int bx   = lg % gx;
  int rest = lg / gx;
  int by   = rest % gy;
  int b    = rest / gy;

  const u16* Ab = A + (size_t)b*bA;
  const u16* Bb = B + (size_t)b*bB;
  int tid = threadIdx.x;
  int lane = tid & 63, w = tid >> 6;
  int m0 = by*64, n0 = bx*64;
  int row_off = (w>>1)*32, col_off = (w&1)*32;
  int q = lane>>4, loc = lane&15;
  f32x4 acc[2][2] = {};

  const int srow = tid >> 2;     // 0..63
  const int sslot = tid & 3;

  for(int k0=0;k0<K;k0+=32){
    {
      int row = srow;
      int ca  = (sslot ^ ((row>>1)&3))*8;
      u16* la = As + w*512 + lane*8;
      u16* lb = Bs + w*512 + lane*8;
      gl16(Ab + (size_t)(m0+row)*lda + k0 + ca, la);
      gl16(Bb + (size_t)(n0+row)*ldb + k0 + ca, lb);
    }
    __syncthreads();
    bf16x8 af[2], bfr[2];
    #pragma unroll
    for(int mi=0;mi<2;mi++){
      int r = row_off + mi*16 + loc;
      int slot = q ^ ((r>>1)&3);
      af[mi] = *(const bf16x8*)(As + r*32 + slot*8);
    }
    #pragma unroll
    for(int ni=0;ni<2;ni++){
      int r = col_off + ni*16 + loc;
      int slot = q ^ ((r>>1)&3);
      bfr[ni] = *(const bf16x8*)(Bs + r*32 + slot*8);
    }
    #pragma unroll
    for(int mi=0;mi<2;mi++)
      #pragma unroll
      for(int ni=0;ni<2;ni++)
        acc[mi][ni] = __builtin_amdgcn_mfma_f32_16x16x32_bf16(af[mi], bfr[ni], acc[mi][ni], 0,0,0);
    __syncthreads();
  }

  float* outFb = outF ? outF + (size_t)b*bO : nullptr;
  u16*   outBb = outB ? outB + (size_t)b*bO : nullptr;
  const float* nxb = nx ? nx + (size_t)b*NN : nullptr;
  const float* nyb = ny ? ny + (size_t)b*NN : nullptr;
  const float* Cb  = (MODE==MODE_STRUCT) ? Cs + (size_t)b*bO : nullptr;
  const float* mb  = (MODE==MODE_STRUCT) ? mu + (size_t)b*NN : nullptr;
  float lsum = 0.f;
  #pragma unroll
  for(int mi=0;mi<2;mi++){
    #pragma unroll
    for(int j=0;j<4;j++){
      int row = m0 + row_off + mi*16 + q*4 + j;
      float ir = 0.f, mr = 0.f;
      if(MODE==MODE_COST)   ir = 1.f/fmaxf(nxb[row],1e-12f);
      if(MODE==MODE_STRUCT) mr = mb[row];
      #pragma unroll
      for(int ni=0;ni<2;ni++){
        int col = n0 + col_off + ni*16 + loc;
        float v = acc[mi][ni][j];
        if(MODE==MODE_COST){
          float ic = 1.f/fmaxf(nyb[col],1e-12f);
          v = 1.f - v*ir*ic;
          if(outFb) outFb[(size_t)row*ldo + col] = v;
          if(outBb) outBb[(size_t)row*ldo + col] = f2bf(v);
        } else if(MODE==MODE_PLAIN){
          outBb[(size_t)row*ldo + col] = f2bf(v);
        } else if(MODE==MODE_STRUCT){
          float d = Cb[(size_t)row*ldo + col] - v;
          lsum += d*d*mr*mb[col];
        }
      }
    }
  }
  if(MODE==MODE_STRUCT){
    lsum = wred_sum(lsum);
    if(lane==0) red[w] = lsum;
    __syncthreads();
    if(tid==0) atomicAdd(accp+6, red[0]+red[1]+red[2]+red[3]);
  }
}

// Dual-output 64x64 COST GEMM: C_t (A1=ZT) and M (A2=ZSP) share B=ZT, K=1024.
// n2 comes from nspp partials (16 slices of ROWS), summed + sqrt inline.
__global__ __launch_bounds__(256) void k_mfma64_dual(
    const u16* __restrict__ A1, const u16* __restrict__ A2,
    const u16* __restrict__ B, int ld, long bStr,
    int K,
    u16* __restrict__ out1, u16* __restrict__ out2, long bO,
    const float* __restrict__ n1, const float* __restrict__ nspp,
    const float* __restrict__ ny)
{
  __shared__ u16 A1s[64*32];
  __shared__ u16 A2s[64*32];
  __shared__ u16 Bs[64*32];

  int gx = gridDim.x, gy = gridDim.y;
  int flat = blockIdx.x + gx*(blockIdx.y + gy*blockIdx.z);
  int nwg  = gx*gy*gridDim.z;
  int cpx  = nwg >> 3;
  int lg   = (flat & 7)*cpx + (flat >> 3);
  int bx   = lg % gx;
  int rest = lg / gx;
  int by   = rest % gy;
  int b    = rest / gy;

  const u16* A1b = A1 + (size_t)b*bStr;
  const u16* A2b = A2 + (size_t)b*bStr;
  const u16* Bb  = B  + (size_t)b*bStr;
  int tid = threadIdx.x;
  int lane = tid & 63, w = tid >> 6;
  int m0 = by*64, n0 = bx*64;
  int row_off = (w>>1)*32, col_off = (w&1)*32;
  int q = lane>>4, loc = lane&15;
  f32x4 acc1[2][2] = {};
  f32x4 acc2[2][2] = {};

  const int srow = tid >> 2;     // 0..63
  const int sslot = tid & 3;

  for(int k0=0;k0<K;k0+=32){
    {
      int row = srow;
      int ca  = (sslot ^ ((row>>1)&3))*8;
      u16* l1 = A1s + w*512 + lane*8;
      u16* l2 = A2s + w*512 + lane*8;
      u16* lb = Bs  + w*512 + lane*8;
      gl16(A1b + (size_t)(m0+row)*ld + k0 + ca, l1);
      gl16(A2b + (size_t)(m0+row)*ld + k0 + ca, l2);
      gl16(Bb  + (size_t)(n0+row)*ld + k0 + ca, lb);
    }
    __syncthreads();
    bf16x8 a1f[2], a2f[2], bfr[2];
    #pragma unroll
    for(int mi=0;mi<2;mi++){
      int r = row_off + mi*16 + loc;
      int slot = q ^ ((r>>1)&3);
      a1f[mi] = *(const bf16x8*)(A1s + r*32 + slot*8);
      a2f[mi] = *(const bf16x8*)(A2s + r*32 + slot*8);
    }
    #pragma unroll
    for(int ni=0;ni<2;ni++){
      int r = col_off + ni*16 + loc;
      int slot = q ^ ((r>>1)&3);
      bfr[ni] = *(const bf16x8*)(Bs + r*32 + slot*8);
    }
    #pragma unroll
    for(int mi=0;mi<2;mi++)
      #pragma unroll
      for(int ni=0;ni<2;ni++){
        acc1[mi][ni] = __builtin_amdgcn_mfma_f32_16x16x32_bf16(a1f[mi], bfr[ni], acc1[mi][ni], 0,0,0);
        acc2[mi][ni] = __builtin_amdgcn_mfma_f32_16x16x32_bf16(a2f[mi], bfr[ni], acc2[mi][ni], 0,0,0);
      }
    __syncthreads();
  }

  u16* o1 = out1 + (size_t)b*bO;
  u16* o2 = out2 + (size_t)b*bO;
  const float* n1b = n1 + (size_t)b*NN;
  const float* nyb = ny + (size_t)b*NN;
  #pragma unroll
  for(int mi=0;mi<2;mi++){
    #pragma unroll
    for(int j=0;j<4;j++){
      int row = m0 + row_off + mi*16 + q*4 + j;
      float ir1 = 1.f/fmaxf(n1b[row],1e-12f);
      // ZSP row norm from 16 partial slices
      size_t gr = (size_t)b*NN + row;
      float ssq = 0.f;
      #pragma unroll
      for(int s=0;s<16;s++) ssq += nspp[(size_t)s*ROWS + gr];
      float ir2 = 1.f/fmaxf(sqrtf(ssq),1e-12f);
      #pragma unroll
      for(int ni=0;ni<2;ni++){
        int col = n0 + col_off + ni*16 + loc;
        float ic = 1.f/fmaxf(nyb[col],1e-12f);
        float v1 = 1.f - acc1[mi][ni][j]*ir1*ic;
        float v2 = 1.f - acc2[mi][ni][j]*ir2*ic;
        o1[(size_t)row*NN + col] = f2bf(v1);
        o2[(size_t)row*NN + col] = f2bf(v2);
      }
    }
  }
}

// ---------------- mega dispatch: Sinkhorn (blocks 0..127) + C_s pass-1 packs ----------------
// Sinkhorn: measured-best 4-phase structure (DO NOT restructure — 2-phase/reg-K/3-phase all worse).
// Blocks [128,384): 4x 64x64 C_s tiles (pass 1) per block, 256-thread sub-groups,
// hidden on the 128 CUs sinkhorn leaves idle. ZS_BF holds pass-1 data at this point.
#define SINK_DYN_LDS 131072
__global__ __launch_bounds__(1024, 1) void k_sink_cs(
    const u16* __restrict__ Mbf, const float* __restrict__ muL,
    const float* __restrict__ nuL, u16* __restrict__ Gn, float* __restrict__ accp,
    const u16* __restrict__ ZS, const float* __restrict__ ns,
    float* __restrict__ CsOut)
{
  extern __shared__ u16 dynLds[];
  __shared__ __align__(16) float part[4096];
  __shared__ __align__(16) float su[NN], sv[NN], smu[NN], snu[NN];
  __shared__ float red[16];

  const int bid = blockIdx.x;
  const int t = threadIdx.x;

  if(bid >= 128){
    // ---- C_s pack path: 4 jobs of 256 threads, pass-1 tiles ----
    const int sub = t >> 8;            // 0..3
    const int st  = t & 255;
    int job = (bid - 128)*4 + sub;     // 0..1023
    int bx = job & 3, by = (job >> 2) & 3, b = job >> 4;
    const u16* Ab = ZS + (size_t)b*NN*HSS;
    u16* As = dynLds + (size_t)sub*4096;
    u16* Bs = As + 2048;
    int lane = st & 63, w = st >> 6;
    int m0 = by*64, n0 = bx*64;
    int row_off = (w>>1)*32, col_off = (w&1)*32;
    int q = lane>>4, loc = lane&15;
    f32x4 acc[2][2] = {};
    const int srow = st >> 2;
    const int sslot = st & 3;

    for(int k0=0;k0<HSS;k0+=32){
      {
        int row = srow;
        int ca  = (sslot ^ ((row>>1)&3))*8;
        gl16(Ab + (size_t)(m0+row)*HSS + k0 + ca, As + w*512 + lane*8);
        gl16(Ab + (size_t)(n0+row)*HSS + k0 + ca, Bs + w*512 + lane*8);
      }
      __syncthreads();
      bf16x8 af[2], bfr[2];
      #pragma unroll
      for(int mi=0;mi<2;mi++){
        int r = row_off + mi*16 + loc;
        int slot = q ^ ((r>>1)&3);
        af[mi] = *(const bf16x8*)(As + r*32 + slot*8);
      }
      #pragma unroll
      for(int ni=0;ni<2;ni++){
        int r = col_off + ni*16 + loc;
        int slot = q ^ ((r>>1)&3);
        bfr[ni] = *(const bf16x8*)(Bs + r*32 + slot*8);
      }
      #pragma unroll
      for(int mi=0;mi<2;mi++)
        #pragma unroll
        for(int ni=0;ni<2;ni++)
          acc[mi][ni] = __builtin_amdgcn_mfma_f32_16x16x32_bf16(af[mi], bfr[ni], acc[mi][ni], 0,0,0);
      __syncthreads();
    }

    float* outFb = CsOut + (size_t)b*NN*NN;
    const float* nb = ns + (size_t)b*NN;
    #pragma unroll
    for(int mi=0;mi<2;mi++){
      #pragma unroll
      for(int j=0;j<4;j++){
        int row = m0 + row_off + mi*16 + q*4 + j;
        float ir = 1.f/fmaxf(nb[row],1e-12f);
        #pragma unroll
        for(int ni=0;ni<2;ni++){
          int col = n0 + col_off + ni*16 + loc;
          float ic = 1.f/fmaxf(nb[col],1e-12f);
          float v = 1.f - acc[mi][ni][j]*ir*ic;
          outFb[(size_t)row*NN + col] = v;
        }
      }
    }
    return;
  }

  // ---- sinkhorn path (verbatim R5 structure) ----
  u16* Ks = dynLds;
  const int b = bid;
  const u16* Mb = Mbf + (size_t)b*NN*NN;

  #pragma unroll
  for(int i=0;i<16;i++){
    int e = (i*1024 + t)*4;
    int r = e>>8, c = e&255;
    ushort4 mv = *(const ushort4*)(Mb + e);
    ushort4 o;
    o.x = f2bf(exp2f(-C2LOG*bf2f(mv.x)));
    o.y = f2bf(exp2f(-C2LOG*bf2f(mv.y)));
    o.z = f2bf(exp2f(-C2LOG*bf2f(mv.z)));
    o.w = f2bf(exp2f(-C2LOG*bf2f(mv.w)));
    *(ushort4*)(Ks + LIDX(r,c)) = o;
  }
  if(t < NN){
    smu[t] = muL[(size_t)b*NN+t] + 1e-8f;
    snu[t] = nuL[(size_t)b*NN+t] + 1e-8f;
    sv[t] = 1.f;
  }
  __syncthreads();

  const int r_ = t & 255, p_ = t >> 8;
  const int w = t>>6, l = t&63;

  for(int it=0; it<20; it++){
    {
      float s0=0.f, s1=0.f, s2=0.f, s3=0.f;
      #pragma unroll
      for(int jj=0;jj<8;jj++){
        int c0 = p_*64 + jj*8;
        uint4 kv = *(const uint4*)(Ks + LIDX(r_, c0));
        float4 va = *(const float4*)(sv + c0);
        float4 vb = *(const float4*)(sv + c0 + 4);
        s0 = fmaf(__uint_as_float(kv.x<<16),           va.x, s0);
        s1 = fmaf(__uint_as_float(kv.x & 0xffff0000u), va.y, s1);
        s2 = fmaf(__uint_as_float(kv.y<<16),           va.z, s2);
        s3 = fmaf(__uint_as_float(kv.y & 0xffff0000u), va.w, s3);
        s0 = fmaf(__uint_as_float(kv.z<<16),           vb.x, s0);
        s1 = fmaf(__uint_as_float(kv.z & 0xffff0000u), vb.y, s1);
        s2 = fmaf(__uint_as_float(kv.w<<16),           vb.z, s2);
        s3 = fmaf(__uint_as_float(kv.w & 0xffff0000u), vb.w, s3);
      }
      part[t] = (s0+s1)+(s2+s3);
    }
    __syncthreads();
    if(t < NN){
      float S = part[t] + part[256+t] + part[512+t] + part[768+t];
      su[t] = smu[t] / S;
    }
    __syncthreads();
    {
      float cs0=0.f,cs1=0.f,cs2=0.f,cs3=0.f;
      #pragma unroll
      for(int rr=0;rr<16;rr++){
        int r = w*16 + rr;
        ushort4 kv = *(const ushort4*)(Ks + LIDX(r, l*4));
        float ur = su[r];
        cs0 = fmaf(bf2f(kv.x), ur, cs0);
        cs1 = fmaf(bf2f(kv.y), ur, cs1);
        cs2 = fmaf(bf2f(kv.z), ur, cs2);
        cs3 = fmaf(bf2f(kv.w), ur, cs3);
      }
      float4 o; o.x=cs0; o.y=cs1; o.z=cs2; o.w=cs3;
      *(float4*)(part + w*256 + l*4) = o;
    }
    __syncthreads();
    if(t < NN){
      float S = 0.f;
      #pragma unroll
      for(int ww=0;ww<16;ww++) S += part[ww*256 + t];
      sv[t] = snu[t] / S;
    }
    __syncthreads();
  }

  {
    float s0=0.f, s1=0.f, s2=0.f, s3=0.f;
    #pragma unroll
    for(int jj=0;jj<8;jj++){
      int c0 = p_*64 + jj*8;
      uint4 kv = *(const uint4*)(Ks + LIDX(r_, c0));
      float4 va = *(const float4*)(sv + c0);
      float4 vb = *(const float4*)(sv + c0 + 4);
      s0 = fmaf(__uint_as_float(kv.x<<16),           va.x, s0);
      s1 = fmaf(__uint_as_float(kv.x & 0xffff0000u), va.y, s1);
      s2 = fmaf(__uint_as_float(kv.y<<16),           va.z, s2);
      s3 = fmaf(__uint_as_float(kv.y & 0xffff0000u), va.w, s3);
      s0 = fmaf(__uint_as_float(kv.z<<16),           vb.x, s0);
      s1 = fmaf(__uint_as_float(kv.z & 0xffff0000u), vb.y, s1);
      s2 = fmaf(__uint_as_float(kv.w<<16),           vb.z, s2);
      s3 = fmaf(__uint_as_float(kv.w & 0xffff0000u), vb.w, s3);
    }
    part[t] = (s0+s1)+(s2+s3);
  }
  __syncthreads();
  if(t < NN){
    float S = part[t] + part[256+t] + part[512+t] + part[768+t];
    smu[t] = 1.f / (su[t]*S + 1e-8f);
  }
  __syncthreads();

  u16* Gb = Gn + (size_t)b*NN*NN;
  const float IC = -1.f/C2LOG;
  float v0 = sv[l*4+0], v1 = sv[l*4+1], v2 = sv[l*4+2], v3 = sv[l*4+3];
  float fl = 0.f;
  for(int rr=0;rr<16;rr++){
    int r = w*16 + rr;
    ushort4 kv = *(const ushort4*)(Ks + LIDX(r, l*4));
    float k0=bf2f(kv.x), k1=bf2f(kv.y), k2=bf2f(kv.z), k3=bf2f(kv.w);
    float ur = su[r], inv = smu[r];
    float g0=ur*k0*v0, g1=ur*k1*v1, g2=ur*k2*v2, g3=ur*k3*v3;
    fl += g0*(__log2f(k0)*IC) + g1*(__log2f(k1)*IC)
        + g2*(__log2f(k2)*IC) + g3*(__log2f(k3)*IC);
    ushort4 o;
    o.x=f2bf(g0*inv); o.y=f2bf(g1*inv); o.z=f2bf(g2*inv); o.w=f2bf(g3*inv);
    *(ushort4*)(Gb + (size_t)r*NN + l*4) = o;
  }
  fl = wred_sum(fl);
  if(l==0) red[w] = fl;
  __syncthreads();
  if(t==0){
    float s=0.f;
    #pragma unroll
    for(int i=0;i<16;i++) s+=red[i];
    atomicAdd(accp+5, s);
  }
}

__global__ void k_final(const float* __restrict__ acc, float* __restrict__ out){
  out[0] = acc[0]
         + 20.f*acc[3]*(1.f/8128.f)
         + 40.f*acc[4]*(1.f/2048256.f)
         + 0.25f*(acc[5]+acc[6])*(1.f/64.f);
}

// ---------------- host ----------------
extern "C" void kernel_launch(void* const* d_in, const int* in_sizes, int n_in,
                              void* d_out, int out_size, void* d_ws, size_t ws_size,
                              hipStream_t stream) {
  const float* s_q_reps   = (const float*)d_in[0];
  const float* s_p_reps   = (const float*)d_in[1];
  const float* t_q_reps   = (const float*)d_in[2];
  const float* t_p_reps   = (const float*)d_in[3];
  const float* s_q_states = (const float*)d_in[4];
  const float* s_p_states = (const float*)d_in[5];
  const float* t_q_states = (const float*)d_in[6];
  const float* t_p_states = (const float*)d_in[7];
  const float* proj_w     = (const float*)d_in[8];
  const float* proj_b     = (const float*)d_in[9];
  float* ws = (float*)d_ws;
  float* acc = ws + OFF_ACC;
  u16* M_BF   = (u16*)(ws + OFF_MBF);
  u16* ZS_BF  = (u16*)(ws + OFF_ZS_BF);
  u16* ZT_BF  = (u16*)(ws + OFF_ZT_BF);
  u16* WT_BF  = (u16*)(ws + OFF_WT_BF);
  u16* ZSP_BF = (u16*)(ws + OFF_ZSP_BF);
  u16* GN_BF  = (u16*)(ws + OFF_GN_BF);
  u16* CT_BF  = (u16*)(ws + OFF_CT_BF);
  u16* T_BF   = (u16*)(ws + OFF_T_BF);

  hipFuncSetAttribute(reinterpret_cast<const void*>(k_sink_cs),
                      hipFuncAttributeMaxDynamicSharedMemorySize, SINK_DYN_LDS);
  hipFuncSetAttribute(reinterpret_cast<const void*>(k_rkd_angle_mfma),
                      hipFuncAttributeMaxDynamicSharedMemorySize, RKD_LDS);

  hipMemsetAsync(acc, 0, 16*sizeof(float), stream);

  // ---- Part A ----
  k_l2norm_all<<<384,256,0,stream>>>(s_q_reps, s_p_reps, t_q_reps, t_p_reps, ws);
  k_contrastive2<<<128,512,0,stream>>>(ws, acc);

  // pass-0 cvt (zs,zt) + gram packed into one launch
  k_pack_cvt<<<8320,256,0,stream>>>(s_q_states, t_q_states, ZS_BF, ZT_BF,
      ws+OFF_NS, ws+OFF_NT, ws+OFF_SQ128, ws+OFF_TQ128, ws+OFF_DS, ws+OFF_DT, acc);
  // rkd_dist + saliency(pass0) packed
  k_small0<<<256,256,0,stream>>>(ws+OFF_DS, ws+OFF_DT, ws+OFF_NS, ws+OFF_NT,
      ws+OFF_MU, ws+OFF_NU, acc);
  k_rkd_angle_mfma<<<256,256,RKD_LDS,stream>>>(ws+OFF_SQ128, ws+OFF_TQ128, acc);
  k_wt<<<dim3(HTT/32, HSS/32),dim3(32,8),0,stream>>>(proj_w, WT_BF);

  // ---- Part B phase 1 ----
  for(int pass=0; pass<2; pass++){
    size_t po  = (size_t)pass*NB*NN*NN;
    size_t pr  = (size_t)pass*ROWS;
    if(pass==1){
      k_pack_cvt<<<8192,256,0,stream>>>(s_p_states, t_p_states, ZS_BF, ZT_BF,
          ws+OFF_NS, ws+OFF_NT, ws+OFF_SQ128, ws+OFF_TQ128, ws+OFF_DS, ws+OFF_DT, acc);
      k_saliency2<<<128,256,0,stream>>>(ws+OFF_NS, ws+OFF_NT, ws+OFF_MU+pr, ws+OFF_NU+pr);
    }
    // PROJ with fused ZSP row-ssq partials (replaces k_row_norm_bf16)
    k_proj<<<dim3(HTT/128, ROWS/128),256,0,stream>>>(
        ZS_BF, WT_BF, ZSP_BF, proj_b, ws+OFF_NSPP);
    if(pass==0){
      // C_s pass 0 (pass 1 is hidden inside the sinkhorn mega-dispatch)
      k_mfma64<MODE_COST><<<dim3(4,4,NB),256,0,stream>>>(
          ZS_BF, HSS, (long)NN*HSS, ZS_BF, HSS, (long)NN*HSS, HSS,
          ws+OFF_CS+po, nullptr, NN, (long)NN*NN,
          ws+OFF_NS, ws+OFF_NS, nullptr, nullptr, nullptr, nullptr);
    }
    // C_t + M fused (shared B=ZT, K=1024); ZSP norm from nspp partials
    k_mfma64_dual<<<dim3(4,4,NB),256,0,stream>>>(
        ZT_BF, ZSP_BF, ZT_BF, HTT, (long)NN*HTT, HTT,
        CT_BF+po, M_BF+po, (long)NN*NN,
        ws+OFF_NT, ws+OFF_NSPP, ws+OFF_NT);
  }

  // ---- Part B phase 2: Sinkhorn (128 blocks) + hidden C_s pass-1 (256 pack blocks) ----
  k_sink_cs<<<384,1024,SINK_DYN_LDS,stream>>>(
      M_BF, ws+OFF_MU, ws+OFF_NU, GN_BF, acc,
      ZS_BF, ws+OFF_NS, ws+OFF_CS + (size_t)NB*NN*NN);

  // ---- Part B phase 3: T = Gn@Ct, struct loss (batched, 64² tiles) ----
  k_mfma64<MODE_PLAIN><<<dim3(4,4,2*NB),256,0,stream>>>(
      GN_BF, NN, (long)NN*NN, CT_BF, NN, (long)NN*NN, NN,
      nullptr, T_BF, NN, (long)NN*NN,
      nullptr, nullptr, nullptr, nullptr, nullptr, nullptr);
  k_mfma64<MODE_STRUCT><<<dim3(4,4,2*NB),256,0,stream>>>(
      T_BF, NN, (long)NN*NN, GN_BF, NN, (long)NN*NN, NN,
      nullptr, nullptr, NN, (long)NN*NN,
      nullptr, nullptr, nullptr, ws+OFF_CS, ws+OFF_MU, acc);

  k_final<<<1,1,0,stream>>>(acc, (float*)d_out);
}

// Round 11
// 547.205 us; speedup vs baseline: 1.2552x; 1.0788x over previous
//
#include <hip/hip_runtime.h>
#include <math.h>

// Problem dims
#define NB   64      // batch B
#define NN   256     // tokens N
#define HSS  768     // H_S
#define HTT  1024    // H_T
#define ROWS (NB*NN) // 16384
#define C2LOG 14.426950408889634f  // 10 * log2(e)

typedef unsigned short u16;
typedef __attribute__((ext_vector_type(8))) short bf16x8;
typedef __attribute__((ext_vector_type(4))) float f32x4;

// swizzled LDS index for [r][c] tiles with 256 cols: chunk rotation, 8-u16 granularity
#define LIDX(r,c) (((r)<<8) + (((((c)>>3) + (r)) & 31)<<3) + ((c)&7))
// swizzled LDS index for E[r][c] (128 cols, 16 chunks of 8)
#define EIDX(r,c) (((r)<<7) + (((((c)>>3) + (r)) & 15)<<3) + ((c)&7))

// async global->LDS, 16B per lane (gfx950)
__device__ __forceinline__ void gl16(const u16* g, u16* l){
  __builtin_amdgcn_global_load_lds(
      (const __attribute__((address_space(1))) unsigned int*)g,
      (__attribute__((address_space(3))) unsigned int*)l,
      16, 0, 0);
}

// ---------------- workspace layout (float offsets) ----------------
static const size_t OFF_ACC   = 0;                          // 16 floats
static const size_t OFF_SQ128 = 16;
static const size_t OFF_SP128 = OFF_SQ128 + 64*128;
static const size_t OFF_TQ128 = OFF_SP128 + 64*128;
static const size_t OFF_TP128 = OFF_TQ128 + 64*128;
static const size_t OFF_SQ768 = OFF_TP128 + 64*128;
static const size_t OFF_SP768 = OFF_SQ768 + 64*768;
static const size_t OFF_DS    = OFF_SP768 + 64*768;         // 128*128
static const size_t OFF_DT    = OFF_DS + 128*128;
static const size_t OFF_CS    = OFF_DT + 128*128;           // 2*B*N*N f32
static const size_t OFF_MBF   = OFF_CS  + (size_t)2*NB*NN*NN;     // 2*B*N*N bf16
static const size_t OFF_ZS_BF = OFF_MBF + (size_t)NB*NN*NN;       // 16384x768 bf16
static const size_t OFF_ZT_BF = OFF_ZS_BF + (size_t)ROWS*HSS/2;   // 16384x1024 bf16
static const size_t OFF_WT_BF = OFF_ZT_BF + (size_t)ROWS*HTT/2;   // 1024x768 bf16
static const size_t OFF_ZSP_BF= OFF_WT_BF + (size_t)HTT*HSS/2;    // 16384x1024 bf16
static const size_t OFF_GN_BF = OFF_ZSP_BF+ (size_t)ROWS*HTT/2;   // 2*B*N*N bf16
static const size_t OFF_CT_BF = OFF_GN_BF + (size_t)NB*NN*NN;     // 2*B*N*N bf16
static const size_t OFF_NS    = OFF_CT_BF + (size_t)NB*NN*NN;
static const size_t OFF_NT    = OFF_NS + ROWS;
static const size_t OFF_MU    = OFF_NT + ROWS;              // 2*ROWS (linear)
static const size_t OFF_NU    = OFF_MU + 2*ROWS;            // 2*ROWS (linear)
static const size_t OFF_NSPP  = OFF_NU + 2*ROWS;            // 16*ROWS f32: ZSP row-ssq partials

// acc: 0=contrastive 1=ds_sum 2=dt_sum 3=dist_huber 4=angle_huber 5=feat 6=struct

// ---------------- helpers ----------------
__device__ __forceinline__ float wred_sum(float v){
  #pragma unroll
  for(int o=32;o>0;o>>=1) v += __shfl_xor(v,o,64);
  return v;
}
__device__ __forceinline__ float wred_max(float v){
  #pragma unroll
  for(int o=32;o>0;o>>=1) v = fmaxf(v, __shfl_xor(v,o,64));
  return v;
}
__device__ __forceinline__ u16 f2bf(float f){
  unsigned u = __float_as_uint(f);
  unsigned r = (u + 0x7fffu + ((u>>16)&1u)) >> 16;
  return (u16)r;
}
__device__ __forceinline__ float bf2f(u16 h){
  return __uint_as_float(((unsigned)h)<<16);
}

// ---------------- Part A kernels ----------------
__global__ __launch_bounds__(256) void k_l2norm_all(
    const float* __restrict__ sq, const float* __restrict__ sp,
    const float* __restrict__ tq, const float* __restrict__ tp,
    float* __restrict__ ws){
  int bid = blockIdx.x;
  int r = bid & 63;
  const float* in; float* out; int kuse;
  if(bid < 64)       { in = sq; out = ws + OFF_SQ128; kuse = 128; }
  else if(bid < 128) { in = sp; out = ws + OFF_SP128; kuse = 128; }
  else if(bid < 192) { in = tq; out = ws + OFF_TQ128; kuse = 128; }
  else if(bid < 256) { in = tp; out = ws + OFF_TP128; kuse = 128; }
  else if(bid < 320) { in = sq; out = ws + OFF_SQ768; kuse = 768; }
  else               { in = sp; out = ws + OFF_SP768; kuse = 768; }
  const float* row = in + (size_t)r*768;
  float ss = 0.f;
  for(int d=threadIdx.x; d<kuse; d+=256){ float x=row[d]; ss += x*x; }
  ss = wred_sum(ss);
  __shared__ float sm[4];
  if((threadIdx.x&63)==0) sm[threadIdx.x>>6]=ss;
  __syncthreads();
  float tot = sm[0]+sm[1]+sm[2]+sm[3];
  float inv = 1.f / fmaxf(sqrtf(tot), 1e-12f);
  for(int d=threadIdx.x; d<kuse; d+=256) out[(size_t)r*kuse + d] = row[d]*inv;
}

__global__ __launch_bounds__(512) void k_contrastive2(const float* __restrict__ ws,
    float* __restrict__ acc){
  int bid = blockIdx.x;
  int i = bid & 63;
  int big = bid >> 6;
  const float* q = ws + (big ? OFF_SQ768 : OFF_SQ128);
  const float* p = ws + (big ? OFF_SP768 : OFF_SP128);
  int dim = big ? 768 : 128;
  float weight = big ? 2.f : 1.f;
  int j = threadIdx.x & 63;
  int part = threadIdx.x >> 6;           // 0..7
  const float* qi = q + (size_t)i*dim;
  const float* pj = p + (size_t)j*dim;
  int seg = dim >> 3;
  int d0 = part*seg;
  float dot = 0.f;
  for(int d=d0; d<d0+seg; d+=4){
    float4 a = *(const float4*)(qi+d);
    float4 b = *(const float4*)(pj+d);
    dot = fmaf(a.x,b.x,dot);
    dot = fmaf(a.y,b.y,dot);
    dot = fmaf(a.z,b.z,dot);
    dot = fmaf(a.w,b.w,dot);
  }
  __shared__ float sm[8][64];
  sm[part][j] = dot;
  __syncthreads();
  if(part==0){
    float s = 0.f;
    #pragma unroll
    for(int k=0;k<8;k++) s += sm[k][j];
    s = s / 0.07f;
    float mx = wred_max(s);
    float e = expf(s - mx);
    float Z = wred_sum(e);
    float logZ = mx + logf(Z);
    float diag = __shfl(s, i, 64);
    if(j==0) atomicAdd(acc+0, weight*(logZ - diag)*(1.f/64.f));
  }
}

// ---- packed cvt+gram: blocks [0,4096) cvt zs, [4096,8192) cvt zt,
// [8192,8320) gram_ds (pass-0 only; pass-1 launches with grid 8192).
__global__ __launch_bounds__(256) void k_pack_cvt(
    const float* __restrict__ zs, const float* __restrict__ zt,
    u16* __restrict__ zsb, u16* __restrict__ ztb,
    float* __restrict__ ns, float* __restrict__ nt,
    const float* __restrict__ sb128, const float* __restrict__ tb128,
    float* __restrict__ ds, float* __restrict__ dt, float* __restrict__ acc)
{
  __shared__ float sm[2][2];
  int bid = blockIdx.x;
  if(bid < 8192){
    const float* in; u16* out; float* nrm; int K; int cb;
    if(bid < 4096){ in=zs; out=zsb; nrm=ns; K=HSS; cb=bid; }
    else          { in=zt; out=ztb; nrm=nt; K=HTT; cb=bid-4096; }
    int w = threadIdx.x >> 6, l = threadIdx.x & 63;
    int r = cb*4 + w;
    const float* row = in + (size_t)r*K;
    u16* orow = out + (size_t)r*K;
    float ss = 0.f;
    int nv = K >> 8;
    for(int i=0;i<nv;i++){
      int d = l*4 + i*256;
      float4 x = *(const float4*)(row + d);
      ushort4 o; o.x=f2bf(x.x); o.y=f2bf(x.y); o.z=f2bf(x.z); o.w=f2bf(x.w);
      *(ushort4*)(orow + d) = o;
      ss += x.x*x.x + x.y*x.y + x.z*x.z + x.w*x.w;
    }
    ss = wred_sum(ss);
    if(l==0) nrm[r] = sqrtf(ss);
    return;
  }
  // gram_ds branch
  {
    int r = bid - 8192;
    int c = threadIdx.x;
    float ms = 0.f, mt = 0.f;
    if(c < 128){
      const float* sr = sb128 + r*128; const float* sc = sb128 + c*128;
      const float* tr = tb128 + r*128; const float* tc = tb128 + c*128;
      float dot_s=0,ssr=0,ssc=0,dot_t=0,tsr=0,tsc=0;
      for(int d=0; d<128; d++){
        float a=sr[d], bb=sc[d]; dot_s += a*bb; ssr += a*a; ssc += bb*bb;
        float at=tr[d], bt=tc[d]; dot_t += at*bt; tsr += at*at; tsc += bt*bt;
      }
      float dv = ssr + ssc - 2.f*dot_s;
      float tv = tsr + tsc - 2.f*dot_t;
      ds[r*128+c] = dv; dt[r*128+c] = tv;
      ms = (c>r)? dv : 0.f;
      mt = (c>r)? tv : 0.f;
      ms = wred_sum(ms); mt = wred_sum(mt);
      if((c&63)==0){ sm[0][c>>6]=ms; sm[1][c>>6]=mt; }
    }
    __syncthreads();
    if(threadIdx.x==0){
      atomicAdd(acc+1, sm[0][0]+sm[0][1]);
      atomicAdd(acc+2, sm[1][0]+sm[1][1]);
    }
  }
}

// packed small kernels (pass 0): blocks [0,128) rkd_dist, [128,256) saliency
__global__ __launch_bounds__(256) void k_small0(
    const float* __restrict__ ds, const float* __restrict__ dt,
    const float* __restrict__ ns, const float* __restrict__ nt,
    float* __restrict__ omu, float* __restrict__ onu, float* __restrict__ acc)
{
  __shared__ float sm[4], sm2[4];
  int bid = blockIdx.x;
  if(bid < 128){
    int r = bid, c = threadIdx.x;
    float mean_s = acc[1]*(1.f/8128.f) + 1e-8f;
    float mean_t = acc[2]*(1.f/8128.f) + 1e-8f;
    float h = 0.f;
    if(c < 128){
      if(c > r){
        float diff = ds[r*128+c]/mean_s - dt[r*128+c]/mean_t;
        float a = fabsf(diff);
        h = (a<1.f)? 0.5f*a*a : a-0.5f;
      }
      h = wred_sum(h);
      if((c&63)==0) sm[c>>6]=h;
    }
    __syncthreads();
    if(threadIdx.x==0) atomicAdd(acc+3, sm[0]+sm[1]);
    return;
  }
  // saliency branch
  {
    int b0 = bid - 128, n = threadIdx.x;
    const float* nrm = (b0 < NB) ? ns : nt;
    float* out = (b0 < NB) ? omu : onu;
    int b = b0 & 63;
    float x = nrm[b*NN+n];
    float mx = wred_max(x);
    if((n&63)==0) sm[n>>6]=mx;
    __syncthreads();
    mx = fmaxf(fmaxf(sm[0],sm[1]),fmaxf(sm[2],sm[3]));
    float e = expf(x-mx);
    float s = wred_sum(e);
    if((n&63)==0) sm2[n>>6]=s;
    __syncthreads();
    s = sm2[0]+sm2[1]+sm2[2]+sm2[3];
    out[b*NN+n] = e/s;
  }
}

// ---- RKD angle via MFMA: psi = E E^T, E in bf16 LDS, huber fused ----
#define RKD_LDS 65536
__global__ __launch_bounds__(256, 1) void k_rkd_angle_mfma(
    const float* __restrict__ sb, const float* __restrict__ tb,
    float* __restrict__ accp)
{
  extern __shared__ u16 eSh[];
  u16* Es = eSh;
  u16* Et = eSh + 128*128;
  const int j    = blockIdx.x >> 1;
  const int half = blockIdx.x & 1;
  const int tid = threadIdx.x;
  {
    const int i = tid >> 1, h = tid & 1;
    #pragma unroll
    for(int which=0; which<2; which++){
      const float* xb = which ? tb : sb;
      u16* E = which ? Et : Es;
      const float* xj = xb + j*128 + h*64;
      const float* xi = xb + i*128 + h*64;
      float ss = 0.f;
      #pragma unroll
      for(int d4=0; d4<16; d4++){
        float4 a = *(const float4*)(xj + d4*4);
        float4 b = *(const float4*)(xi + d4*4);
        float d0=a.x-b.x, d1=a.y-b.y, d2=a.z-b.z, d3=a.w-b.w;
        ss += d0*d0+d1*d1+d2*d2+d3*d3;
      }
      ss += __shfl_xor(ss, 1, 64);
      float inv = (i==j) ? 0.f : 1.f/(sqrtf(ss)+1e-8f);
      #pragma unroll
      for(int d4=0; d4<16; d4++){
        float4 a = *(const float4*)(xj + d4*4);
        float4 b = *(const float4*)(xi + d4*4);
        int c = h*64 + d4*4;
        E[EIDX(i,c+0)] = f2bf((a.x-b.x)*inv);
        E[EIDX(i,c+1)] = f2bf((a.y-b.y)*inv);
        E[EIDX(i,c+2)] = f2bf((a.z-b.z)*inv);
        E[EIDX(i,c+3)] = f2bf((a.w-b.w)*inv);
      }
    }
  }
  __syncthreads();
  const int w = tid >> 6, lane = tid & 63;
  const int q = lane >> 4, loc = lane & 15;
  float hsum = 0.f;
  #pragma unroll
  for(int ni=0; ni<4; ni++){
    const int cb = half*64 + ni*16;
    #pragma unroll
    for(int mi=0; mi<2; mi++){
      const int rb = w*32 + mi*16;
      f32x4 as_ = {0.f,0.f,0.f,0.f}, at_ = {0.f,0.f,0.f,0.f};
      #pragma unroll
      for(int k0=0; k0<128; k0+=32){
        int ra = rb + loc, rbn = cb + loc;
        int ca = k0 + q*8;
        bf16x8 aS = *(const bf16x8*)(Es + EIDX(ra, ca));
        bf16x8 bS = *(const bf16x8*)(Es + EIDX(rbn, ca));
        bf16x8 aT = *(const bf16x8*)(Et + EIDX(ra, ca));
        bf16x8 bT = *(const bf16x8*)(Et + EIDX(rbn, ca));
        as_ = __builtin_amdgcn_mfma_f32_16x16x32_bf16(aS, bS, as_, 0,0,0);
        at_ = __builtin_amdgcn_mfma_f32_16x16x32_bf16(aT, bT, at_, 0,0,0);
      }
      #pragma unroll
      for(int jj=0; jj<4; jj++){
        int row = rb + q*4 + jj, col = cb + loc;
        if(row != col){
          float d = as_[jj] - at_[jj];
          float a = fabsf(d);
          hsum += (a < 1.f) ? 0.5f*a*a : a - 0.5f;
        }
      }
    }
  }
  hsum = wred_sum(hsum);
  __syncthreads();
  float* red = (float*)eSh;
  if(lane==0) red[w] = hsum;
  __syncthreads();
  if(tid==0) atomicAdd(accp+4, red[0]+red[1]+red[2]+red[3]);
}

// W (HSS x HTT) f32 -> Wt (HTT x HSS) bf16
__global__ void k_wt(const float* __restrict__ W, u16* __restrict__ Wt){
  __shared__ float t[32][33];
  int k0 = blockIdx.y*32, n0 = blockIdx.x*32;
  int tx = threadIdx.x, ty = threadIdx.y;
  for(int r=0;r<32;r+=8) t[ty+r][tx] = W[(size_t)(k0+ty+r)*HTT + n0+tx];
  __syncthreads();
  for(int r=0;r<32;r+=8) Wt[(size_t)(n0+ty+r)*HSS + k0+tx] = f2bf(t[tx][ty+r]);
}

// fused saliency: blocks 0..63 -> (ns -> mu), 64..127 -> (nt -> nu)
__global__ __launch_bounds__(256) void k_saliency2(const float* __restrict__ ns,
    const float* __restrict__ nt, float* __restrict__ omu, float* __restrict__ onu){
  int b0 = blockIdx.x, n = threadIdx.x;
  const float* nrm = (b0 < NB) ? ns : nt;
  float* out = (b0 < NB) ? omu : onu;
  int b = b0 & 63;
  float x = nrm[b*NN+n];
  float mx = wred_max(x);
  __shared__ float sm[4], sm2[4];
  if((n&63)==0) sm[n>>6]=mx;
  __syncthreads();
  mx = fmaxf(fmaxf(sm[0],sm[1]),fmaxf(sm[2],sm[3]));
  float e = expf(x-mx);
  float s = wred_sum(e);
  if((n&63)==0) sm2[n>>6]=s;
  __syncthreads();
  s = sm2[0]+sm2[1]+sm2[2]+sm2[3];
  out[b*NN+n] = e/s;
}

// ---------------- PROJ GEMM (128x128 tile) with fused row-ssq partials ----------------
// nspp layout: [16][ROWS] f32, slice = bx*2 + (w&1). dual sums 16 slices + sqrt.
__global__ __launch_bounds__(256) void k_proj(
    const u16* __restrict__ A, const u16* __restrict__ B,
    u16* __restrict__ outB, const float* __restrict__ bias,
    float* __restrict__ nspp)
{
  __shared__ u16 As[128*32];
  __shared__ u16 Bs[128*32];

  int gx = gridDim.x, gy = gridDim.y;
  int flat = blockIdx.x + gx*blockIdx.y;
  int nwg  = gx*gy;
  int cpx  = nwg >> 3;
  int lg   = (flat & 7)*cpx + (flat >> 3);
  int bx   = lg % gx;
  int by   = lg / gx;

  int tid = threadIdx.x;
  int lane = tid & 63, w = tid >> 6;
  int m0 = by*128, n0 = bx*128;
  int row_off = (w>>1)*64, col_off = (w&1)*64;
  int q = lane>>4, loc = lane&15;
  f32x4 acc[4][4] = {};

  const int srow = (lane >> 2);
  const int sslot = lane & 3;

  for(int k0=0;k0<HSS;k0+=32){
    #pragma unroll
    for(int h=0;h<2;h++){
      int row = h*64 + w*16 + srow;
      int ca  = (sslot ^ ((row>>1)&3))*8;
      u16* ldst = As + h*2048 + w*512 + lane*8;
      u16* ldstB= Bs + h*2048 + w*512 + lane*8;
      gl16(A + (size_t)(m0+row)*HSS + k0 + ca, ldst);
      gl16(B + (size_t)(n0+row)*HSS + k0 + ca, ldstB);
    }
    __syncthreads();
    bf16x8 af[4], bfr[4];
    #pragma unroll
    for(int mi=0;mi<4;mi++){
      int r = row_off + mi*16 + loc;
      int slot = q ^ ((r>>1)&3);
      af[mi] = *(const bf16x8*)(As + r*32 + slot*8);
    }
    #pragma unroll
    for(int ni=0;ni<4;ni++){
      int r = col_off + ni*16 + loc;
      int slot = q ^ ((r>>1)&3);
      bfr[ni] = *(const bf16x8*)(Bs + r*32 + slot*8);
    }
    #pragma unroll
    for(int mi=0;mi<4;mi++)
      #pragma unroll
      for(int ni=0;ni<4;ni++)
        acc[mi][ni] = __builtin_amdgcn_mfma_f32_16x16x32_bf16(af[mi], bfr[ni], acc[mi][ni], 0,0,0);
    __syncthreads();
  }

  int slice = bx*2 + (w&1);
  #pragma unroll
  for(int mi=0;mi<4;mi++){
    #pragma unroll
    for(int j=0;j<4;j++){
      int row = m0 + row_off + mi*16 + q*4 + j;
      float sq = 0.f;
      #pragma unroll
      for(int ni=0;ni<4;ni++){
        int col = n0 + col_off + ni*16 + loc;
        float v = acc[mi][ni][j] + bias[col];
        u16 h = f2bf(v);
        outB[(size_t)row*HTT + col] = h;
        float vq = bf2f(h);
        sq = fmaf(vq, vq, sq);
      }
      sq += __shfl_xor(sq, 1, 64);
      sq += __shfl_xor(sq, 2, 64);
      sq += __shfl_xor(sq, 4, 64);
      sq += __shfl_xor(sq, 8, 64);
      if(loc==0) nspp[(size_t)slice*ROWS + row] = sq;
    }
  }
}

// ---------------- packed PROJ + C_s (pass 0): blocks [0,1024) PROJ, [1024,2048) C_s ----------------
__global__ __launch_bounds__(256) void k_proj_cs(
    const u16* __restrict__ ZS, const u16* __restrict__ WT,
    u16* __restrict__ ZSP, const float* __restrict__ bias,
    float* __restrict__ nspp,
    const float* __restrict__ ns, float* __restrict__ CsOut)
{
  __shared__ u16 sh[8192];   // 16KB: PROJ uses all; C_s uses 8KB
  int bid = blockIdx.x;
  int tid = threadIdx.x;
  int lane = tid & 63, w = tid >> 6;
  int q = lane>>4, loc = lane&15;

  if(bid < 1024){
    // ---- PROJ branch (verbatim k_proj body, segment swizzle gx=8,gy=128) ----
    u16* As = sh;
    u16* Bs = sh + 4096;
    int f = bid;
    int lg = (f & 7)*128 + (f >> 3);
    int bx = lg % 8;
    int by = lg / 8;
    int m0 = by*128, n0 = bx*128;
    int row_off = (w>>1)*64, col_off = (w&1)*64;
    f32x4 acc[4][4] = {};
    const int srow = (lane >> 2);
    const int sslot = lane & 3;

    for(int k0=0;k0<HSS;k0+=32){
      #pragma unroll
      for(int h=0;h<2;h++){
        int row = h*64 + w*16 + srow;
        int ca  = (sslot ^ ((row>>1)&3))*8;
        gl16(ZS + (size_t)(m0+row)*HSS + k0 + ca, As + h*2048 + w*512 + lane*8);
        gl16(WT + (size_t)(n0+row)*HSS + k0 + ca, Bs + h*2048 + w*512 + lane*8);
      }
      __syncthreads();
      bf16x8 af[4], bfr[4];
      #pragma unroll
      for(int mi=0;mi<4;mi++){
        int r = row_off + mi*16 + loc;
        int slot = q ^ ((r>>1)&3);
        af[mi] = *(const bf16x8*)(As + r*32 + slot*8);
      }
      #pragma unroll
      for(int ni=0;ni<4;ni++){
        int r = col_off + ni*16 + loc;
        int slot = q ^ ((r>>1)&3);
        bfr[ni] = *(const bf16x8*)(Bs + r*32 + slot*8);
      }
      #pragma unroll
      for(int mi=0;mi<4;mi++)
        #pragma unroll
        for(int ni=0;ni<4;ni++)
          acc[mi][ni] = __builtin_amdgcn_mfma_f32_16x16x32_bf16(af[mi], bfr[ni], acc[mi][ni], 0,0,0);
      __syncthreads();
    }

    int slice = bx*2 + (w&1);
    #pragma unroll
    for(int mi=0;mi<4;mi++){
      #pragma unroll
      for(int j=0;j<4;j++){
        int row = m0 + row_off + mi*16 + q*4 + j;
        float sq = 0.f;
        #pragma unroll
        for(int ni=0;ni<4;ni++){
          int col = n0 + col_off + ni*16 + loc;
          float v = acc[mi][ni][j] + bias[col];
          u16 h = f2bf(v);
          ZSP[(size_t)row*HTT + col] = h;
          float vq = bf2f(h);
          sq = fmaf(vq, vq, sq);
        }
        sq += __shfl_xor(sq, 1, 64);
        sq += __shfl_xor(sq, 2, 64);
        sq += __shfl_xor(sq, 4, 64);
        sq += __shfl_xor(sq, 8, 64);
        if(loc==0) nspp[(size_t)slice*ROWS + row] = sq;
      }
    }
    return;
  }

  // ---- C_s branch (verbatim 64x64 COST body, A=B=ZS, f32 out) ----
  {
    u16* As = sh;
    u16* Bs = sh + 2048;
    int f = bid - 1024;
    int lg = (f & 7)*128 + (f >> 3);
    int bx = lg & 3, by = (lg >> 2) & 3, b = lg >> 4;
    const u16* Ab = ZS + (size_t)b*NN*HSS;
    int m0 = by*64, n0 = bx*64;
    int row_off = (w>>1)*32, col_off = (w&1)*32;
    f32x4 acc[2][2] = {};
    const int srow = tid >> 2;
    const int sslot = tid & 3;

    for(int k0=0;k0<HSS;k0+=32){
      {
        int row = srow;
        int ca  = (sslot ^ ((row>>1)&3))*8;
        gl16(Ab + (size_t)(m0+row)*HSS + k0 + ca, As + w*512 + lane*8);
        gl16(Ab + (size_t)(n0+row)*HSS + k0 + ca, Bs + w*512 + lane*8);
      }
      __syncthreads();
      bf16x8 af[2], bfr[2];
      #pragma unroll
      for(int mi=0;mi<2;mi++){
        int r = row_off + mi*16 + loc;
        int slot = q ^ ((r>>1)&3);
        af[mi] = *(const bf16x8*)(As + r*32 + slot*8);
      }
      #pragma unroll
      for(int ni=0;ni<2;ni++){
        int r = col_off + ni*16 + loc;
        int slot = q ^ ((r>>1)&3);
        bfr[ni] = *(const bf16x8*)(Bs + r*32 + slot*8);
      }
      #pragma unroll
      for(int mi=0;mi<2;mi++)
        #pragma unroll
        for(int ni=0;ni<2;ni++)
          acc[mi][ni] = __builtin_amdgcn_mfma_f32_16x16x32_bf16(af[mi], bfr[ni], acc[mi][ni], 0,0,0);
      __syncthreads();
    }

    float* outFb = CsOut + (size_t)b*NN*NN;
    const float* nb = ns + (size_t)b*NN;
    #pragma unroll
    for(int mi=0;mi<2;mi++){
      #pragma unroll
      for(int j=0;j<4;j++){
        int row = m0 + row_off + mi*16 + q*4 + j;
        float ir = 1.f/fmaxf(nb[row],1e-12f);
        #pragma unroll
        for(int ni=0;ni<2;ni++){
          int col = n0 + col_off + ni*16 + loc;
          float ic = 1.f/fmaxf(nb[col],1e-12f);
          float v = 1.f - acc[mi][ni][j]*ir*ic;
          outFb[(size_t)row*NN + col] = v;
        }
      }
    }
  }
}

// Dual-output 64x64 COST GEMM: C_t (A1=ZT) and M (A2=ZSP) share B=ZT, K=1024.
// n2 comes from nspp partials (16 slices of ROWS), summed + sqrt inline.
__global__ __launch_bounds__(256) void k_mfma64_dual(
    const u16* __restrict__ A1, const u16* __restrict__ A2,
    const u16* __restrict__ B, int ld, long bStr,
    int K,
    u16* __restrict__ out1, u16* __restrict__ out2, long bO,
    const float* __restrict__ n1, const float* __restrict__ nspp,
    const float* __restrict__ ny)
{
  __shared__ u16 A1s[64*32];
  __shared__ u16 A2s[64*32];
  __shared__ u16 Bs[64*32];

  int gx = gridDim.x, gy = gridDim.y;
  int flat = blockIdx.x + gx*(blockIdx.y + gy*blockIdx.z);
  int nwg  = gx*gy*gridDim.z;
  int cpx  = nwg >> 3;
  int lg   = (flat & 7)*cpx + (flat >> 3);
  int bx   = lg % gx;
  int rest = lg / gx;
  int by   = rest % gy;
  int b    = rest / gy;

  const u16* A1b = A1 + (size_t)b*bStr;
  const u16* A2b = A2 + (size_t)b*bStr;
  const u16* Bb  = B  + (size_t)b*bStr;
  int tid = threadIdx.x;
  int lane = tid & 63, w = tid >> 6;
  int m0 = by*64, n0 = bx*64;
  int row_off = (w>>1)*32, col_off = (w&1)*32;
  int q = lane>>4, loc = lane&15;
  f32x4 acc1[2][2] = {};
  f32x4 acc2[2][2] = {};

  const int srow = tid >> 2;     // 0..63
  const int sslot = tid & 3;

  for(int k0=0;k0<K;k0+=32){
    {
      int row = srow;
      int ca  = (sslot ^ ((row>>1)&3))*8;
      gl16(A1b + (size_t)(m0+row)*ld + k0 + ca, A1s + w*512 + lane*8);
      gl16(A2b + (size_t)(m0+row)*ld + k0 + ca, A2s + w*512 + lane*8);
      gl16(Bb  + (size_t)(n0+row)*ld + k0 + ca, Bs  + w*512 + lane*8);
    }
    __syncthreads();
    bf16x8 a1f[2], a2f[2], bfr[2];
    #pragma unroll
    for(int mi=0;mi<2;mi++){
      int r = row_off + mi*16 + loc;
      int slot = q ^ ((r>>1)&3);
      a1f[mi] = *(const bf16x8*)(A1s + r*32 + slot*8);
      a2f[mi] = *(const bf16x8*)(A2s + r*32 + slot*8);
    }
    #pragma unroll
    for(int ni=0;ni<2;ni++){
      int r = col_off + ni*16 + loc;
      int slot = q ^ ((r>>1)&3);
      bfr[ni] = *(const bf16x8*)(Bs + r*32 + slot*8);
    }
    #pragma unroll
    for(int mi=0;mi<2;mi++)
      #pragma unroll
      for(int ni=0;ni<2;ni++){
        acc1[mi][ni] = __builtin_amdgcn_mfma_f32_16x16x32_bf16(a1f[mi], bfr[ni], acc1[mi][ni], 0,0,0);
        acc2[mi][ni] = __builtin_amdgcn_mfma_f32_16x16x32_bf16(a2f[mi], bfr[ni], acc2[mi][ni], 0,0,0);
      }
    __syncthreads();
  }

  u16* o1 = out1 + (size_t)b*bO;
  u16* o2 = out2 + (size_t)b*bO;
  const float* n1b = n1 + (size_t)b*NN;
  const float* nyb = ny + (size_t)b*NN;
  #pragma unroll
  for(int mi=0;mi<2;mi++){
    #pragma unroll
    for(int j=0;j<4;j++){
      int row = m0 + row_off + mi*16 + q*4 + j;
      float ir1 = 1.f/fmaxf(n1b[row],1e-12f);
      size_t gr = (size_t)b*NN + row;
      float ssq = 0.f;
      #pragma unroll
      for(int s=0;s<16;s++) ssq += nspp[(size_t)s*ROWS + gr];
      float ir2 = 1.f/fmaxf(sqrtf(ssq),1e-12f);
      #pragma unroll
      for(int ni=0;ni<2;ni++){
        int col = n0 + col_off + ni*16 + loc;
        float ic = 1.f/fmaxf(nyb[col],1e-12f);
        float v1 = 1.f - acc1[mi][ni][j]*ir1*ic;
        float v2 = 1.f - acc2[mi][ni][j]*ir2*ic;
        o1[(size_t)row*NN + col] = f2bf(v1);
        o2[(size_t)row*NN + col] = f2bf(v2);
      }
    }
  }
}

// ---------------- fused GW struct: T_strip in LDS, no global T ----------------
// Per block: 64-row strip of batch b. Phase 1: T = Gn_strip @ Ct (Ct symmetric, NT).
// Phase 2: Tmap_strip = T @ Gn^T; struct loss vs Cs inline. T K-order and bf16
// quantization identical to the old PLAIN->STRUCT pair.
__global__ __launch_bounds__(256) void k_gw_struct(
    const u16* __restrict__ Gn, const u16* __restrict__ Ct,
    const float* __restrict__ Cs, const float* __restrict__ mu,
    float* __restrict__ accp)
{
  __shared__ u16 As[64*32];       // Gn strip slice (phase 1)
  __shared__ u16 Bs[256*32];      // Ct rows (ph1) / Gn rows (ph2)
  __shared__ u16 Tl[64*256];      // T strip bf16, LIDX-swizzled
  __shared__ float red[4];

  int flat = blockIdx.x;                 // nwg = 512
  int lg = (flat & 7)*64 + (flat >> 3);  // XCD swizzle, cpx=64
  int strip = lg & 3;
  int b = lg >> 2;

  const u16* Gnb = Gn + (size_t)b*NN*NN;
  const u16* Ctb = Ct + (size_t)b*NN*NN;
  int tid = threadIdx.x;
  int lane = tid & 63, w = tid >> 6;
  int m0 = strip*64;
  int q = lane>>4, loc = lane&15;
  f32x4 acc[4][4] = {};
  const int srow = tid >> 2;
  const int sslot = tid & 3;

  // ---- phase 1: T_strip(64x256) = Gn[m0..m0+64) @ Ct ----
  for(int k0=0;k0<NN;k0+=32){
    {
      int rowA = srow;
      int caA = (sslot ^ ((rowA>>1)&3))*8;
      gl16(Gnb + (size_t)(m0+rowA)*NN + k0 + caA, As + tid*8);
      #pragma unroll
      for(int h=0;h<4;h++){
        int rowB = h*64 + srow;
        int caB = (sslot ^ ((rowB>>1)&3))*8;
        gl16(Ctb + (size_t)rowB*NN + k0 + caB, Bs + h*2048 + tid*8);
      }
    }
    __syncthreads();
    bf16x8 af[4], bfr[4];
    #pragma unroll
    for(int mi=0;mi<4;mi++){
      int r = mi*16 + loc;
      int slot = q ^ ((r>>1)&3);
      af[mi] = *(const bf16x8*)(As + r*32 + slot*8);
    }
    #pragma unroll
    for(int ni=0;ni<4;ni++){
      int r = w*64 + ni*16 + loc;
      int slot = q ^ ((r>>1)&3);
      bfr[ni] = *(const bf16x8*)(Bs + r*32 + slot*8);
    }
    #pragma unroll
    for(int mi=0;mi<4;mi++)
      #pragma unroll
      for(int ni=0;ni<4;ni++)
        acc[mi][ni] = __builtin_amdgcn_mfma_f32_16x16x32_bf16(af[mi], bfr[ni], acc[mi][ni], 0,0,0);
    __syncthreads();
  }

  // write T_strip to LDS (bf16, same quantization as old T_BF), THEN clear acc.
  // (R9 bug: clearing inside the j loop zeroed rows j=1..3 before writing.)
  #pragma unroll
  for(int mi=0;mi<4;mi++){
    #pragma unroll
    for(int j=0;j<4;j++){
      int row = mi*16 + q*4 + j;
      #pragma unroll
      for(int ni=0;ni<4;ni++){
        int col = w*64 + ni*16 + loc;
        Tl[LIDX(row,col)] = f2bf(acc[mi][ni][j]);
      }
    }
    #pragma unroll
    for(int ni=0;ni<4;ni++)
      acc[mi][ni] = (f32x4){0.f,0.f,0.f,0.f};
  }
  __syncthreads();

  // ---- phase 2: Tmap_strip = T_strip @ Gn^T ----
  for(int k0=0;k0<NN;k0+=32){
    {
      #pragma unroll
      for(int h=0;h<4;h++){
        int rowB = h*64 + srow;
        int caB = (sslot ^ ((rowB>>1)&3))*8;
        gl16(Gnb + (size_t)rowB*NN + k0 + caB, Bs + h*2048 + tid*8);
      }
    }
    __syncthreads();
    bf16x8 af[4], bfr[4];
    #pragma unroll
    for(int mi=0;mi<4;mi++){
      int r = mi*16 + loc;
      af[mi] = *(const bf16x8*)(Tl + LIDX(r, k0 + q*8));
    }
    #pragma unroll
    for(int ni=0;ni<4;ni++){
      int r = w*64 + ni*16 + loc;
      int slot = q ^ ((r>>1)&3);
      bfr[ni] = *(const bf16x8*)(Bs + r*32 + slot*8);
    }
    #pragma unroll
    for(int mi=0;mi<4;mi++)
      #pragma unroll
      for(int ni=0;ni<4;ni++)
        acc[mi][ni] = __builtin_amdgcn_mfma_f32_16x16x32_bf16(af[mi], bfr[ni], acc[mi][ni], 0,0,0);
    __syncthreads();
  }

  // ---- epilogue: weighted squared diff vs Cs ----
  const float* Csb = Cs + (size_t)b*NN*NN;
  const float* mb  = mu + (size_t)b*NN;
  float lsum = 0.f;
  #pragma unroll
  for(int mi=0;mi<4;mi++){
    #pragma unroll
    for(int j=0;j<4;j++){
      int row = m0 + mi*16 + q*4 + j;
      float mr = mb[row];
      #pragma unroll
      for(int ni=0;ni<4;ni++){
        int col = w*64 + ni*16 + loc;
        float d = Csb[(size_t)row*NN + col] - acc[mi][ni][j];
        lsum += d*d*mr*mb[col];
      }
    }
  }
  lsum = wred_sum(lsum);
  if(lane==0) red[w] = lsum;
  __syncthreads();
  if(tid==0) atomicAdd(accp+6, red[0]+red[1]+red[2]+red[3]);
}

// ---------------- mega dispatch: Sinkhorn (blocks 0..127) + C_s pass-1 packs ----------------
// Sinkhorn: measured-best 4-phase structure (DO NOT restructure).
#define SINK_DYN_LDS 131072
__global__ __launch_bounds__(1024, 1) void k_sink_cs(
    const u16* __restrict__ Mbf, const float* __restrict__ muL,
    const float* __restrict__ nuL, u16* __restrict__ Gn, float* __restrict__ accp,
    const u16* __restrict__ ZS, const float* __restrict__ ns,
    float* __restrict__ CsOut)
{
  extern __shared__ u16 dynLds[];
  __shared__ __align__(16) float part[4096];
  __shared__ __align__(16) float su[NN], sv[NN], smu[NN], snu[NN];
  __shared__ float red[16];

  const int bid = blockIdx.x;
  const int t = threadIdx.x;

  if(bid >= 128){
    const int sub = t >> 8;            // 0..3
    const int st  = t & 255;
    int job = (bid - 128)*4 + sub;     // 0..1023
    int bx = job & 3, by = (job >> 2) & 3, b = job >> 4;
    const u16* Ab = ZS + (size_t)b*NN*HSS;
    u16* As = dynLds + (size_t)sub*4096;
    u16* Bs = As + 2048;
    int lane = st & 63, w = st >> 6;
    int m0 = by*64, n0 = bx*64;
    int row_off = (w>>1)*32, col_off = (w&1)*32;
    int q = lane>>4, loc = lane&15;
    f32x4 acc[2][2] = {};
    const int srow = st >> 2;
    const int sslot = st & 3;

    for(int k0=0;k0<HSS;k0+=32){
      {
        int row = srow;
        int ca  = (sslot ^ ((row>>1)&3))*8;
        gl16(Ab + (size_t)(m0+row)*HSS + k0 + ca, As + w*512 + lane*8);
        gl16(Ab + (size_t)(n0+row)*HSS + k0 + ca, Bs + w*512 + lane*8);
      }
      __syncthreads();
      bf16x8 af[2], bfr[2];
      #pragma unroll
      for(int mi=0;mi<2;mi++){
        int r = row_off + mi*16 + loc;
        int slot = q ^ ((r>>1)&3);
        af[mi] = *(const bf16x8*)(As + r*32 + slot*8);
      }
      #pragma unroll
      for(int ni=0;ni<2;ni++){
        int r = col_off + ni*16 + loc;
        int slot = q ^ ((r>>1)&3);
        bfr[ni] = *(const bf16x8*)(Bs + r*32 + slot*8);
      }
      #pragma unroll
      for(int mi=0;mi<2;mi++)
        #pragma unroll
        for(int ni=0;ni<2;ni++)
          acc[mi][ni] = __builtin_amdgcn_mfma_f32_16x16x32_bf16(af[mi], bfr[ni], acc[mi][ni], 0,0,0);
      __syncthreads();
    }

    float* outFb = CsOut + (size_t)b*NN*NN;
    const float* nb = ns + (size_t)b*NN;
    #pragma unroll
    for(int mi=0;mi<2;mi++){
      #pragma unroll
      for(int j=0;j<4;j++){
        int row = m0 + row_off + mi*16 + q*4 + j;
        float ir = 1.f/fmaxf(nb[row],1e-12f);
        #pragma unroll
        for(int ni=0;ni<2;ni++){
          int col = n0 + col_off + ni*16 + loc;
          float ic = 1.f/fmaxf(nb[col],1e-12f);
          float v = 1.f - acc[mi][ni][j]*ir*ic;
          outFb[(size_t)row*NN + col] = v;
        }
      }
    }
    return;
  }

  // ---- sinkhorn path (verbatim R5 structure) ----
  u16* Ks = dynLds;
  const int b = bid;
  const u16* Mb = Mbf + (size_t)b*NN*NN;

  #pragma unroll
  for(int i=0;i<16;i++){
    int e = (i*1024 + t)*4;
    int r = e>>8, c = e&255;
    ushort4 mv = *(const ushort4*)(Mb + e);
    ushort4 o;
    o.x = f2bf(exp2f(-C2LOG*bf2f(mv.x)));
    o.y = f2bf(exp2f(-C2LOG*bf2f(mv.y)));
    o.z = f2bf(exp2f(-C2LOG*bf2f(mv.z)));
    o.w = f2bf(exp2f(-C2LOG*bf2f(mv.w)));
    *(ushort4*)(Ks + LIDX(r,c)) = o;
  }
  if(t < NN){
    smu[t] = muL[(size_t)b*NN+t] + 1e-8f;
    snu[t] = nuL[(size_t)b*NN+t] + 1e-8f;
    sv[t] = 1.f;
  }
  __syncthreads();

  const int r_ = t & 255, p_ = t >> 8;
  const int w = t>>6, l = t&63;

  for(int it=0; it<20; it++){
    {
      float s0=0.f, s1=0.f, s2=0.f, s3=0.f;
      #pragma unroll
      for(int jj=0;jj<8;jj++){
        int c0 = p_*64 + jj*8;
        uint4 kv = *(const uint4*)(Ks + LIDX(r_, c0));
        float4 va = *(const float4*)(sv + c0);
        float4 vb = *(const float4*)(sv + c0 + 4);
        s0 = fmaf(__uint_as_float(kv.x<<16),           va.x, s0);
        s1 = fmaf(__uint_as_float(kv.x & 0xffff0000u), va.y, s1);
        s2 = fmaf(__uint_as_float(kv.y<<16),           va.z, s2);
        s3 = fmaf(__uint_as_float(kv.y & 0xffff0000u), va.w, s3);
        s0 = fmaf(__uint_as_float(kv.z<<16),           vb.x, s0);
        s1 = fmaf(__uint_as_float(kv.z & 0xffff0000u), vb.y, s1);
        s2 = fmaf(__uint_as_float(kv.w<<16),           vb.z, s2);
        s3 = fmaf(__uint_as_float(kv.w & 0xffff0000u), vb.w, s3);
      }
      part[t] = (s0+s1)+(s2+s3);
    }
    __syncthreads();
    if(t < NN){
      float S = part[t] + part[256+t] + part[512+t] + part[768+t];
      su[t] = smu[t] / S;
    }
    __syncthreads();
    {
      float cs0=0.f,cs1=0.f,cs2=0.f,cs3=0.f;
      #pragma unroll
      for(int rr=0;rr<16;rr++){
        int r = w*16 + rr;
        ushort4 kv = *(const ushort4*)(Ks + LIDX(r, l*4));
        float ur = su[r];
        cs0 = fmaf(bf2f(kv.x), ur, cs0);
        cs1 = fmaf(bf2f(kv.y), ur, cs1);
        cs2 = fmaf(bf2f(kv.z), ur, cs2);
        cs3 = fmaf(bf2f(kv.w), ur, cs3);
      }
      float4 o; o.x=cs0; o.y=cs1; o.z=cs2; o.w=cs3;
      *(float4*)(part + w*256 + l*4) = o;
    }
    __syncthreads();
    if(t < NN){
      float S = 0.f;
      #pragma unroll
      for(int ww=0;ww<16;ww++) S += part[ww*256 + t];
      sv[t] = snu[t] / S;
    }
    __syncthreads();
  }

  {
    float s0=0.f, s1=0.f, s2=0.f, s3=0.f;
    #pragma unroll
    for(int jj=0;jj<8;jj++){
      int c0 = p_*64 + jj*8;
      uint4 kv = *(const uint4*)(Ks + LIDX(r_, c0));
      float4 va = *(const float4*)(sv + c0);
      float4 vb = *(const float4*)(sv + c0 + 4);
      s0 = fmaf(__uint_as_float(kv.x<<16),           va.x, s0);
      s1 = fmaf(__uint_as_float(kv.x & 0xffff0000u), va.y, s1);
      s2 = fmaf(__uint_as_float(kv.y<<16),           va.z, s2);
      s3 = fmaf(__uint_as_float(kv.y & 0xffff0000u), va.w, s3);
      s0 = fmaf(__uint_as_float(kv.z<<16),           vb.x, s0);
      s1 = fmaf(__uint_as_float(kv.z & 0xffff0000u), vb.y, s1);
      s2 = fmaf(__uint_as_float(kv.w<<16),           vb.z, s2);
      s3 = fmaf(__uint_as_float(kv.w & 0xffff0000u), vb.w, s3);
    }
    part[t] = (s0+s1)+(s2+s3);
  }
  __syncthreads();
  if(t < NN){
    float S = part[t] + part[256+t] + part[512+t] + part[768+t];
    smu[t] = 1.f / (su[t]*S + 1e-8f);
  }
  __syncthreads();

  u16* Gb = Gn + (size_t)b*NN*NN;
  const float IC = -1.f/C2LOG;
  float v0 = sv[l*4+0], v1 = sv[l*4+1], v2 = sv[l*4+2], v3 = sv[l*4+3];
  float fl = 0.f;
  for(int rr=0;rr<16;rr++){
    int r = w*16 + rr;
    ushort4 kv = *(const ushort4*)(Ks + LIDX(r, l*4));
    float k0=bf2f(kv.x), k1=bf2f(kv.y), k2=bf2f(kv.z), k3=bf2f(kv.w);
    float ur = su[r], inv = smu[r];
    float g0=ur*k0*v0, g1=ur*k1*v1, g2=ur*k2*v2, g3=ur*k3*v3;
    fl += g0*(__log2f(k0)*IC) + g1*(__log2f(k1)*IC)
        + g2*(__log2f(k2)*IC) + g3*(__log2f(k3)*IC);
    ushort4 o;
    o.x=f2bf(g0*inv); o.y=f2bf(g1*inv); o.z=f2bf(g2*inv); o.w=f2bf(g3*inv);
    *(ushort4*)(Gb + (size_t)r*NN + l*4) = o;
  }
  fl = wred_sum(fl);
  if(l==0) red[w] = fl;
  __syncthreads();
  if(t==0){
    float s=0.f;
    #pragma unroll
    for(int i=0;i<16;i++) s+=red[i];
    atomicAdd(accp+5, s);
  }
}

__global__ void k_final(const float* __restrict__ acc, float* __restrict__ out){
  out[0] = acc[0]
         + 20.f*acc[3]*(1.f/8128.f)
         + 40.f*acc[4]*(1.f/2048256.f)
         + 0.25f*(acc[5]+acc[6])*(1.f/64.f);
}

// ---------------- host ----------------
extern "C" void kernel_launch(void* const* d_in, const int* in_sizes, int n_in,
                              void* d_out, int out_size, void* d_ws, size_t ws_size,
                              hipStream_t stream) {
  const float* s_q_reps   = (const float*)d_in[0];
  const float* s_p_reps   = (const float*)d_in[1];
  const float* t_q_reps   = (const float*)d_in[2];
  const float* t_p_reps   = (const float*)d_in[3];
  const float* s_q_states = (const float*)d_in[4];
  const float* s_p_states = (const float*)d_in[5];
  const float* t_q_states = (const float*)d_in[6];
  const float* t_p_states = (const float*)d_in[7];
  const float* proj_w     = (const float*)d_in[8];
  const float* proj_b     = (const float*)d_in[9];
  float* ws = (float*)d_ws;
  float* acc = ws + OFF_ACC;
  u16* M_BF   = (u16*)(ws + OFF_MBF);
  u16* ZS_BF  = (u16*)(ws + OFF_ZS_BF);
  u16* ZT_BF  = (u16*)(ws + OFF_ZT_BF);
  u16* WT_BF  = (u16*)(ws + OFF_WT_BF);
  u16* ZSP_BF = (u16*)(ws + OFF_ZSP_BF);
  u16* GN_BF  = (u16*)(ws + OFF_GN_BF);
  u16* CT_BF  = (u16*)(ws + OFF_CT_BF);

  hipFuncSetAttribute(reinterpret_cast<const void*>(k_sink_cs),
                      hipFuncAttributeMaxDynamicSharedMemorySize, SINK_DYN_LDS);
  hipFuncSetAttribute(reinterpret_cast<const void*>(k_rkd_angle_mfma),
                      hipFuncAttributeMaxDynamicSharedMemorySize, RKD_LDS);

  hipMemsetAsync(acc, 0, 16*sizeof(float), stream);

  // ---- Part A ----
  k_l2norm_all<<<384,256,0,stream>>>(s_q_reps, s_p_reps, t_q_reps, t_p_reps, ws);
  k_contrastive2<<<128,512,0,stream>>>(ws, acc);

  // pass-0 cvt (zs,zt) + gram packed into one launch
  k_pack_cvt<<<8320,256,0,stream>>>(s_q_states, t_q_states, ZS_BF, ZT_BF,
      ws+OFF_NS, ws+OFF_NT, ws+OFF_SQ128, ws+OFF_TQ128, ws+OFF_DS, ws+OFF_DT, acc);
  // rkd_dist + saliency(pass0) packed
  k_small0<<<256,256,0,stream>>>(ws+OFF_DS, ws+OFF_DT, ws+OFF_NS, ws+OFF_NT,
      ws+OFF_MU, ws+OFF_NU, acc);
  k_rkd_angle_mfma<<<256,256,RKD_LDS,stream>>>(ws+OFF_SQ128, ws+OFF_TQ128, acc);
  k_wt<<<dim3(HTT/32, HSS/32),dim3(32,8),0,stream>>>(proj_w, WT_BF);

  // ---- Part B phase 1 ----
  // pass 0: PROJ + C_s packed into one dispatch (C_s latency-bound rides under PROJ)
  k_proj_cs<<<2048,256,0,stream>>>(
      ZS_BF, WT_BF, ZSP_BF, proj_b, ws+OFF_NSPP,
      ws+OFF_NS, ws+OFF_CS);
  k_mfma64_dual<<<dim3(4,4,NB),256,0,stream>>>(
      ZT_BF, ZSP_BF, ZT_BF, HTT, (long)NN*HTT, HTT,
      CT_BF, M_BF, (long)NN*NN,
      ws+OFF_NT, ws+OFF_NSPP, ws+OFF_NT);

  // pass 1
  {
    size_t po  = (size_t)1*NB*NN*NN;
    size_t pr  = (size_t)1*ROWS;
    k_pack_cvt<<<8192,256,0,stream>>>(s_p_states, t_p_states, ZS_BF, ZT_BF,
        ws+OFF_NS, ws+OFF_NT, ws+OFF_SQ128, ws+OFF_TQ128, ws+OFF_DS, ws+OFF_DT, acc);
    k_saliency2<<<128,256,0,stream>>>(ws+OFF_NS, ws+OFF_NT, ws+OFF_MU+pr, ws+OFF_NU+pr);
    k_proj<<<dim3(HTT/128, ROWS/128),256,0,stream>>>(
        ZS_BF, WT_BF, ZSP_BF, proj_b, ws+OFF_NSPP);
    k_mfma64_dual<<<dim3(4,4,NB),256,0,stream>>>(
        ZT_BF, ZSP_BF, ZT_BF, HTT, (long)NN*HTT, HTT,
        CT_BF+po, M_BF+po, (long)NN*NN,
        ws+OFF_NT, ws+OFF_NSPP, ws+OFF_NT);
  }

  // ---- Part B phase 2: Sinkhorn (128 blocks) + hidden C_s pass-1 (256 pack blocks) ----
  k_sink_cs<<<384,1024,SINK_DYN_LDS,stream>>>(
      M_BF, ws+OFF_MU, ws+OFF_NU, GN_BF, acc,
      ZS_BF, ws+OFF_NS, ws+OFF_CS + (size_t)NB*NN*NN);

  // ---- Part B phase 3: fused Gn@Ct@Gn^T + struct loss (no global T) ----
  k_gw_struct<<<512,256,0,stream>>>(
      GN_BF, CT_BF, ws+OFF_CS, ws+OFF_MU, acc);

  k_final<<<1,1,0,stream>>>(acc, (float*)d_out);
}